// Round 1
// baseline (1398.379 us; speedup 1.0000x reference)
//
#include <hip/hip_runtime.h>
#include <hip/hip_bf16.h>
#include <cstdint>
#include <cstddef>

// Problem constants
#define B_    8
#define SEQ_  1024
#define C_    768
#define H_    12
#define D_    64
#define TC_   2304          // 3*C
#define M_    8192          // B*SEQ
#define EPS_  1e-7f
#define SCALE_ 0.036084391824351615f  // 768^-0.5

typedef __attribute__((ext_vector_type(8))) short bf16x8;
typedef __attribute__((ext_vector_type(4))) float f32x4;

__device__ __forceinline__ int sdot4_(int a, int b, int c) {
#if __has_builtin(__builtin_amdgcn_sdot4)
  return __builtin_amdgcn_sdot4(a, b, c, false);
#else
  c += (int)(signed char)(a)       * (int)(signed char)(b);
  c += (int)(signed char)(a >> 8)  * (int)(signed char)(b >> 8);
  c += (int)(signed char)(a >> 16) * (int)(signed char)(b >> 16);
  c += (int)(signed char)(a >> 24) * (int)(signed char)(b >> 24);
  return c;
#endif
}

__device__ __forceinline__ int dot16_(const int4& a0, const int4& a1, const int4& a2, const int4& a3,
                                      const int4& b0, const int4& b1, const int4& b2, const int4& b3) {
  int d = 0;
  d = sdot4_(a0.x, b0.x, d); d = sdot4_(a0.y, b0.y, d); d = sdot4_(a0.z, b0.z, d); d = sdot4_(a0.w, b0.w, d);
  d = sdot4_(a1.x, b1.x, d); d = sdot4_(a1.y, b1.y, d); d = sdot4_(a1.z, b1.z, d); d = sdot4_(a1.w, b1.w, d);
  d = sdot4_(a2.x, b2.x, d); d = sdot4_(a2.y, b2.y, d); d = sdot4_(a2.z, b2.z, d); d = sdot4_(a2.w, b2.w, d);
  d = sdot4_(a3.x, b3.x, d); d = sdot4_(a3.y, b3.y, d); d = sdot4_(a3.z, b3.z, d); d = sdot4_(a3.w, b3.w, d);
  return d;
}

// ---------------- init global stats ----------------
// g[0]=max|x| g[1]=max|qkv_w| g[2]=max|proj_w| g[3]=max|q| g[4]=max|k| g[5]=max|v|
// g[6]=min softmax-denom  g[7]=max|attn_out|
__global__ void k_init(float* g) {
  if (threadIdx.x == 0) {
    g[0]=0.f; g[1]=0.f; g[2]=0.f; g[3]=0.f; g[4]=0.f; g[5]=0.f;
    g[6]=3.402823466e+38f;
    g[7]=0.f;
  }
}

// ---------------- abs-max reduction (float4) ----------------
__global__ __launch_bounds__(256) void k_absmax4(const float4* __restrict__ p, unsigned n4, float* gout) {
  float m = 0.f;
  for (unsigned i = blockIdx.x * blockDim.x + threadIdx.x; i < n4; i += gridDim.x * blockDim.x) {
    float4 v = p[i];
    m = fmaxf(m, fmaxf(fmaxf(fabsf(v.x), fabsf(v.y)), fmaxf(fabsf(v.z), fabsf(v.w))));
  }
  #pragma unroll
  for (int off = 32; off; off >>= 1) m = fmaxf(m, __shfl_down(m, off));
  if ((threadIdx.x & 63) == 0) atomicMax((unsigned int*)gout, __float_as_uint(m));
}

// ---------------- signed fake-quant -> bf16 integer levels ----------------
__global__ __launch_bounds__(256) void k_quant_bf16(const float* __restrict__ in, unsigned n,
                                                    const float* __restrict__ gmax,
                                                    unsigned short* __restrict__ out) {
  const float s = *gmax + EPS_;
  for (unsigned i = blockIdx.x * blockDim.x + threadIdx.x; i < n; i += gridDim.x * blockDim.x) {
    float v = in[i];
    float y = fminf(fabsf(v) / s, 1.0f);
    float q = rintf(y * 127.0f);          // half-to-even, matches jnp.round
    if (v < 0.f) q = -q;
    out[i] = (unsigned short)(__float_as_uint(q) >> 16);  // exact: integer <= 127
  }
}

// ---------------- bf16-integer MFMA GEMM: C = alpha * (A . Bt^T) + bias ----------------
// A: [Mn][Kn] bf16 int-levels, Bt: [Nn][Kn] bf16 int-levels (K-contiguous), C: [Mn][Nn] f32
__global__ __launch_bounds__(256) void k_gemm(const unsigned short* __restrict__ A,
                                              const unsigned short* __restrict__ Bt,
                                              const float* __restrict__ bias,
                                              float* __restrict__ C,
                                              int Mn, int Nn, int Kn,
                                              const float* __restrict__ sA, const float* __restrict__ sB) {
  __shared__ unsigned short As[128 * 64];
  __shared__ unsigned short Bs[128 * 64];
  const int tid = threadIdx.x;
  const int n0 = blockIdx.x * 128, m0 = blockIdx.y * 128;
  const int wid = tid >> 6, lane = tid & 63;
  const int wr = wid >> 1, wc = wid & 1;            // 2x2 waves -> 64x64 each
  const int lrow = lane & 15;
  const int lko = (lane >> 4) << 3;                 // k offset 0/8/16/24
  f32x4 acc[4][4] = {};
  const int srow = tid >> 1, scol = (tid & 1) << 5; // each thread stages 64B of A and B
  const unsigned short* ga = A  + (size_t)(m0 + srow) * Kn + scol;
  const unsigned short* gb = Bt + (size_t)(n0 + srow) * Kn + scol;
  int4* lA = (int4*)&As[srow * 64 + scol];
  int4* lB = (int4*)&Bs[srow * 64 + scol];
  for (int k0 = 0; k0 < Kn; k0 += 64) {
    const int4* gav = (const int4*)(ga + k0);
    const int4* gbv = (const int4*)(gb + k0);
    int4 a0 = gav[0], a1 = gav[1], a2 = gav[2], a3 = gav[3];
    int4 b0 = gbv[0], b1 = gbv[1], b2 = gbv[2], b3 = gbv[3];
    lA[0] = a0; lA[1] = a1; lA[2] = a2; lA[3] = a3;
    lB[0] = b0; lB[1] = b1; lB[2] = b2; lB[3] = b3;
    __syncthreads();
    #pragma unroll
    for (int kk = 0; kk < 64; kk += 32) {
      bf16x8 af[4], bfr[4];
      #pragma unroll
      for (int i = 0; i < 4; ++i) af[i]  = *(const bf16x8*)&As[(wr * 64 + i * 16 + lrow) * 64 + kk + lko];
      #pragma unroll
      for (int j = 0; j < 4; ++j) bfr[j] = *(const bf16x8*)&Bs[(wc * 64 + j * 16 + lrow) * 64 + kk + lko];
      #pragma unroll
      for (int i = 0; i < 4; ++i)
        #pragma unroll
        for (int j = 0; j < 4; ++j)
          acc[i][j] = __builtin_amdgcn_mfma_f32_16x16x32_bf16(af[i], bfr[j], acc[i][j], 0, 0, 0);
    }
    __syncthreads();
  }
  const float alpha = (sA[0] + EPS_) * (sB[0] + EPS_) * (1.0f / 16129.0f);
  const int orow = (lane >> 4) << 2;
  #pragma unroll
  for (int i = 0; i < 4; ++i) {
    #pragma unroll
    for (int j = 0; j < 4; ++j) {
      int col = n0 + wc * 64 + j * 16 + lrow;
      float bc = bias[col];
      #pragma unroll
      for (int rr = 0; rr < 4; ++rr) {
        int row = m0 + wr * 64 + i * 16 + orow + rr;
        C[(size_t)row * Nn + col] = acc[i][j][rr] * alpha + bc;
      }
    }
  }
}

// ---------------- per-part abs-max over qkv (q/k/v) ----------------
__global__ __launch_bounds__(256) void k_max3(const float4* __restrict__ qkvf4, float* g) {
  float m0 = 0.f, m1 = 0.f, m2 = 0.f;
  const unsigned total4 = (unsigned)M_ * TC_ / 4;
  for (unsigned i = blockIdx.x * blockDim.x + threadIdx.x; i < total4; i += gridDim.x * blockDim.x) {
    float4 v = qkvf4[i];
    float am = fmaxf(fmaxf(fabsf(v.x), fabsf(v.y)), fmaxf(fabsf(v.z), fabsf(v.w)));
    unsigned o = (i * 4u) % 2304u;
    unsigned part = o / 768u;                 // float4 never crosses a part boundary (768%4==0)
    if (part == 0) m0 = fmaxf(m0, am);
    else if (part == 1) m1 = fmaxf(m1, am);
    else m2 = fmaxf(m2, am);
  }
  #pragma unroll
  for (int off = 32; off; off >>= 1) {
    m0 = fmaxf(m0, __shfl_down(m0, off));
    m1 = fmaxf(m1, __shfl_down(m1, off));
    m2 = fmaxf(m2, __shfl_down(m2, off));
  }
  if ((threadIdx.x & 63) == 0) {
    atomicMax((unsigned int*)&g[3], __float_as_uint(m0));
    atomicMax((unsigned int*)&g[4], __float_as_uint(m1));
    atomicMax((unsigned int*)&g[5], __float_as_uint(m2));
  }
}

// ---------------- quantize qkv into int8 head-layouts ----------------
// q,k: [bh][n][d]; v stored transposed: vT [bh][d][n]
__global__ __launch_bounds__(256) void k_quant_heads(const float* __restrict__ qkvf, const float* __restrict__ g,
                                                     int8_t* __restrict__ qo, int8_t* __restrict__ ko,
                                                     int8_t* __restrict__ vT) {
  const unsigned total = (unsigned)M_ * TC_;
  const float s0 = g[3] + EPS_, s1 = g[4] + EPS_, s2 = g[5] + EPS_;
  for (unsigned i = blockIdx.x * blockDim.x + threadIdx.x; i < total; i += gridDim.x * blockDim.x) {
    unsigned m = i / 2304u, o = i % 2304u;
    unsigned part = o / 768u, c = o % 768u;
    unsigned h = c >> 6, d = c & 63;
    unsigned b = m >> 10, n = m & 1023;
    float s = (part == 0) ? s0 : (part == 1) ? s1 : s2;
    float v = qkvf[i];
    float y = fminf(fabsf(v) / s, 1.0f);
    int q = (int)rintf(y * 127.0f);
    if (v < 0.f) q = -q;
    unsigned bh = b * 12 + h;
    if (part == 0)      qo[((size_t)bh * 1024 + n) * 64 + d] = (int8_t)q;
    else if (part == 1) ko[((size_t)bh * 1024 + n) * 64 + d] = (int8_t)q;
    else                vT[((size_t)bh * 64 + d) * 1024 + n] = (int8_t)q;
  }
}

// ---------------- per-(bh,d) column sums of v (for the a-128 trick) ----------------
__global__ __launch_bounds__(256) void k_vsum(const int8_t* __restrict__ vT, int* __restrict__ vsum) {
  int idx = blockIdx.x * 256 + threadIdx.x;     // 0..6143 = bh*64+d
  const int4* p = (const int4*)(vT + (size_t)idx * 1024);
  int s = 0;
  for (int i = 0; i < 64; ++i) {
    int4 v = p[i];
    s = sdot4_(v.x, 0x01010101, s); s = sdot4_(v.y, 0x01010101, s);
    s = sdot4_(v.z, 0x01010101, s); s = sdot4_(v.w, 0x01010101, s);
  }
  vsum[idx] = s;
}

// ---------------- attention pass 1: per-row max + softmax denom; global min denom ----------------
__global__ __launch_bounds__(256) void k_attn_stats(const int8_t* __restrict__ qq, const int8_t* __restrict__ kk,
                                                    const float* __restrict__ g,
                                                    float* __restrict__ rowmax, float* __restrict__ denom,
                                                    unsigned int* __restrict__ gminden) {
  const int bh = blockIdx.x >> 2;
  const int r  = ((blockIdx.x & 3) << 8) + threadIdx.x;
  const size_t rowg = (size_t)bh * 1024 + r;
  const int4* qp = (const int4*)(qq + rowg * 64);
  int4 q0 = qp[0], q1 = qp[1], q2 = qp[2], q3 = qp[3];
  const int4* kb = (const int4*)(kk + (size_t)bh * 65536);
  const float qkScale = (g[3] + EPS_) * (g[4] + EPS_) * (1.0f / 16129.0f) * SCALE_;
  float m = -1e30f, den = 0.f;
  for (int n = 0; n < 1024; ++n) {
    int4 k0 = kb[n * 4 + 0], k1 = kb[n * 4 + 1], k2 = kb[n * 4 + 2], k3 = kb[n * 4 + 3];
    int dp = dot16_(q0, q1, q2, q3, k0, k1, k2, k3);
    float s = (float)dp * qkScale;
    if (s > m) { den = den * expf(m - s) + 1.0f; m = s; }
    else       { den += expf(s - m); }
  }
  rowmax[rowg] = m;
  denom[rowg]  = den;
  atomicMin(gminden, __float_as_uint(den));   // positive floats: uint order == float order
}

// ---------------- attention pass 2: quantized P @ quantized V ----------------
__global__ __launch_bounds__(256) void k_attn_pv(const int8_t* __restrict__ qq, const int8_t* __restrict__ kk,
                                                 const int8_t* __restrict__ vT, const int* __restrict__ vsum,
                                                 const float* __restrict__ g, const unsigned int* __restrict__ gminden,
                                                 const float* __restrict__ rowmax, const float* __restrict__ denom,
                                                 float* __restrict__ aof) {
  const int bh = blockIdx.x >> 2;
  const int b = bh / 12, h = bh % 12;
  const int r = ((blockIdx.x & 3) << 8) + threadIdx.x;
  const size_t rowg = (size_t)bh * 1024 + r;
  const int4* qp = (const int4*)(qq + rowg * 64);
  int4 q0 = qp[0], q1 = qp[1], q2 = qp[2], q3 = qp[3];
  const int4* kb = (const int4*)(kk + (size_t)bh * 65536);
  const int8_t* vtb = vT + (size_t)bh * 65536;
  const float qkScale = (g[3] + EPS_) * (g[4] + EPS_) * (1.0f / 16129.0f) * SCALE_;
  const float minden = __uint_as_float(*gminden);
  const float sa = 1.0f / minden + EPS_;       // scaling of unsigned quant = max(softmax)+EPS
  const float invSa = 1.0f / sa;
  const float rm = rowmax[rowg];
  const float invden = 1.0f / denom[rowg];
  const float sv = g[5] + EPS_;
  const float pvScale = sa * sv * (1.0f / 32385.0f);   // /(255*127)
  int acc[64];
  #pragma unroll
  for (int d = 0; d < 64; ++d) acc[d] = 0;
  for (int n0 = 0; n0 < 1024; n0 += 16) {
    int a[16];
    #pragma unroll
    for (int c = 0; c < 16; ++c) {
      const int4* kr = kb + (size_t)(n0 + c) * 4;
      int4 k0 = kr[0], k1 = kr[1], k2 = kr[2], k3 = kr[3];
      int dp = dot16_(q0, q1, q2, q3, k0, k1, k2, k3);
      float s = (float)dp * qkScale;
      float p = expf(s - rm) * invden;
      a[c] = (int)rintf(fminf(p * invSa, 1.0f) * 255.0f);
    }
    int ap[4];
    #pragma unroll
    for (int gi = 0; gi < 4; ++gi)
      ap[gi] = ((a[4 * gi] - 128) & 255) | (((a[4 * gi + 1] - 128) & 255) << 8) |
               (((a[4 * gi + 2] - 128) & 255) << 16) | (((a[4 * gi + 3] - 128) & 255) << 24);
    #pragma unroll
    for (int d = 0; d < 64; ++d) {
      int4 vv = *(const int4*)(vtb + (size_t)d * 1024 + n0);
      int t = acc[d];
      t = sdot4_(ap[0], vv.x, t); t = sdot4_(ap[1], vv.y, t);
      t = sdot4_(ap[2], vv.z, t); t = sdot4_(ap[3], vv.w, t);
      acc[d] = t;
    }
  }
  float* outp = aof + ((size_t)(b * 1024 + r)) * 768 + h * 64;
  const int* vs = vsum + bh * 64;
  #pragma unroll
  for (int d = 0; d < 64; ++d)
    outp[d] = (float)(acc[d] + 128 * vs[d]) * pvScale;   // undo the a-128 shift
}

extern "C" void kernel_launch(void* const* d_in, const int* in_sizes, int n_in,
                              void* d_out, int out_size, void* d_ws, size_t ws_size,
                              hipStream_t stream) {
  const float* x      = (const float*)d_in[0];   // [8,1024,768]
  const float* qkv_w  = (const float*)d_in[1];   // [2304,768]
  const float* qkv_b  = (const float*)d_in[2];   // [2304]
  const float* proj_w = (const float*)d_in[3];   // [768,768]
  const float* proj_b = (const float*)d_in[4];   // [768]
  float* out = (float*)d_out;

  char* w = (char*)d_ws;
  float*          g      = (float*)(w + 0);                 // 8 stats
  float*          rowmax = (float*)(w + 256);               // 98304 f32
  float*          denomv = (float*)(w + 786688 - 393216);   // = w+393472
  unsigned short* xq     = (unsigned short*)(w + 786688);   // 12582912 B
  unsigned short* wq     = (unsigned short*)(w + 13369600); //  3538944 B
  unsigned short* pw     = (unsigned short*)(w + 16908544); //  1179648 B
  int8_t*         qi8    = (int8_t*)(w + 18088192);         //  6291456 B
  int8_t*         ki8    = (int8_t*)(w + 24379648);         //  6291456 B
  int8_t*         vT     = (int8_t*)(w + 30671104);         //  6291456 B
  int*            vsum   = (int*)(w + 36962560);            //    24576 B
  float*          qkvf   = (float*)(w + 36987136);          // 75497472 B
  float*          aof    = (float*)(w + 36987136);          // aliases qkvf (dead after quant_heads)
  unsigned short* aobf   = (unsigned short*)(w + 62152960); // inside qkvf region, after aof

  hipLaunchKernelGGL(k_init, dim3(1), dim3(64), 0, stream, g);

  hipLaunchKernelGGL(k_absmax4, dim3(1024), dim3(256), 0, stream, (const float4*)x,      6291456u / 4, &g[0]);
  hipLaunchKernelGGL(k_absmax4, dim3(512),  dim3(256), 0, stream, (const float4*)qkv_w,  1769472u / 4, &g[1]);
  hipLaunchKernelGGL(k_absmax4, dim3(256),  dim3(256), 0, stream, (const float4*)proj_w,  589824u / 4, &g[2]);

  hipLaunchKernelGGL(k_quant_bf16, dim3(2048), dim3(256), 0, stream, x,      6291456u, &g[0], xq);
  hipLaunchKernelGGL(k_quant_bf16, dim3(1024), dim3(256), 0, stream, qkv_w,  1769472u, &g[1], wq);
  hipLaunchKernelGGL(k_quant_bf16, dim3(512),  dim3(256), 0, stream, proj_w,  589824u, &g[2], pw);

  // qkv = xq @ wq^T * (sx*sw/127^2) + b   -> f32 [8192][2304]
  hipLaunchKernelGGL(k_gemm, dim3(TC_ / 128, M_ / 128), dim3(256), 0, stream,
                     xq, wq, qkv_b, qkvf, M_, TC_, C_, &g[0], &g[1]);

  hipLaunchKernelGGL(k_max3, dim3(2048), dim3(256), 0, stream, (const float4*)qkvf, g);
  hipLaunchKernelGGL(k_quant_heads, dim3(2048), dim3(256), 0, stream, qkvf, g, qi8, ki8, vT);
  hipLaunchKernelGGL(k_vsum, dim3(24), dim3(256), 0, stream, vT, vsum);

  hipLaunchKernelGGL(k_attn_stats, dim3(384), dim3(256), 0, stream,
                     qi8, ki8, g, rowmax, denomv, (unsigned int*)&g[6]);
  hipLaunchKernelGGL(k_attn_pv, dim3(384), dim3(256), 0, stream,
                     qi8, ki8, vT, vsum, g, (const unsigned int*)&g[6], rowmax, denomv, aof);

  hipLaunchKernelGGL(k_absmax4, dim3(1024), dim3(256), 0, stream, (const float4*)aof, 6291456u / 4, &g[7]);
  hipLaunchKernelGGL(k_quant_bf16, dim3(2048), dim3(256), 0, stream, aof, 6291456u, &g[7], aobf);

  // out = aobf @ pw^T * (sao*spw/127^2) + proj_b -> d_out f32 [8192][768]
  hipLaunchKernelGGL(k_gemm, dim3(C_ / 128, M_ / 128), dim3(256), 0, stream,
                     aobf, pw, proj_b, out, M_, C_, C_, &g[7], &g[2]);

  (void)in_sizes; (void)n_in; (void)out_size; (void)ws_size;
}

// Round 2
// 729.578 us; speedup vs baseline: 1.9167x; 1.9167x over previous
//
#include <hip/hip_runtime.h>
#include <hip/hip_bf16.h>
#include <cstdint>
#include <cstddef>

// Problem constants
#define B_    8
#define SEQ_  1024
#define C_    768
#define H_    12
#define D_    64
#define TC_   2304          // 3*C
#define M_    8192          // B*SEQ
#define EPS_  1e-7f
#define SCALE_ 0.036084391824351615f  // 768^-0.5

typedef __attribute__((ext_vector_type(8))) short bf16x8;
typedef __attribute__((ext_vector_type(4))) float f32x4;

// int8 -> bf16 integer levels (exact for |v|<=255)
__device__ __forceinline__ bf16x8 expand8(int2 raw) {
  union { int2 v; signed char c[8]; } u; u.v = raw;
  bf16x8 r;
  #pragma unroll
  for (int j = 0; j < 8; ++j) {
    float f = (float)(int)u.c[j];
    r[j] = (short)(__float_as_uint(f) >> 16);
  }
  return r;
}
__device__ __forceinline__ void expand16(int4 raw, int4& lo, int4& hi) {
  union { int4 v; signed char c[16]; } u; u.v = raw;
  unsigned short s[16];
  #pragma unroll
  for (int j = 0; j < 16; ++j) {
    float f = (float)(int)u.c[j];
    s[j] = (unsigned short)(__float_as_uint(f) >> 16);
  }
  lo = *(const int4*)&s[0]; hi = *(const int4*)&s[8];
}

// ---------------- init global stats ----------------
// g[0]=max|x| g[1]=max|qkv_w| g[2]=max|proj_w| g[3]=max|q| g[4]=max|k| g[5]=max|v|
// g[6]=min softmax-denom  g[7]=max|attn_out|
__global__ void k_init(float* g) {
  if (threadIdx.x == 0) {
    g[0]=0.f; g[1]=0.f; g[2]=0.f; g[3]=0.f; g[4]=0.f; g[5]=0.f;
    g[6]=3.402823466e+38f;
    g[7]=0.f;
  }
}

// ---------------- abs-max reduction (float4) ----------------
__global__ __launch_bounds__(256) void k_absmax4(const float4* __restrict__ p, unsigned n4, float* gout) {
  float m = 0.f;
  for (unsigned i = blockIdx.x * blockDim.x + threadIdx.x; i < n4; i += gridDim.x * blockDim.x) {
    float4 v = p[i];
    m = fmaxf(m, fmaxf(fmaxf(fabsf(v.x), fabsf(v.y)), fmaxf(fabsf(v.z), fabsf(v.w))));
  }
  #pragma unroll
  for (int off = 32; off; off >>= 1) m = fmaxf(m, __shfl_down(m, off));
  if ((threadIdx.x & 63) == 0) atomicMax((unsigned int*)gout, __float_as_uint(m));
}

// ---------------- signed fake-quant -> bf16 integer levels ----------------
__global__ __launch_bounds__(256) void k_quant_bf16(const float* __restrict__ in, unsigned n,
                                                    const float* __restrict__ gmax,
                                                    unsigned short* __restrict__ out) {
  const float s = *gmax + EPS_;
  for (unsigned i = blockIdx.x * blockDim.x + threadIdx.x; i < n; i += gridDim.x * blockDim.x) {
    float v = in[i];
    float y = fminf(fabsf(v) / s, 1.0f);
    float q = rintf(y * 127.0f);          // half-to-even, matches jnp.round
    if (v < 0.f) q = -q;
    out[i] = (unsigned short)(__float_as_uint(q) >> 16);  // exact: integer <= 127
  }
}

// ---------------- bf16-integer MFMA GEMM: C = alpha * (A . Bt^T) + bias ----------------
// A: [Mn][Kn], Bt: [Nn][Kn] bf16 int-levels, C: [Mn][Nn] f32
// If pmax != nullptr: also atomicMax per-part |C| maxima into pmax[col/partDiv]
// (requires 128-col blocks to not straddle part boundaries: partDiv % 128 == 0).
__global__ __launch_bounds__(256) void k_gemm(const unsigned short* __restrict__ A,
                                              const unsigned short* __restrict__ Bt,
                                              const float* __restrict__ bias,
                                              float* __restrict__ C,
                                              int Mn, int Nn, int Kn,
                                              const float* __restrict__ sA, const float* __restrict__ sB,
                                              float* pmax, int partDiv) {
  __shared__ unsigned short As[128 * 64];
  __shared__ unsigned short Bs[128 * 64];
  const int tid = threadIdx.x;
  const int n0 = blockIdx.x * 128, m0 = blockIdx.y * 128;
  const int wid = tid >> 6, lane = tid & 63;
  const int wr = wid >> 1, wc = wid & 1;            // 2x2 waves -> 64x64 each
  const int lrow = lane & 15;
  const int lko = (lane >> 4) << 3;                 // k offset 0/8/16/24
  f32x4 acc[4][4] = {};
  const int srow = tid >> 1;
  const int scolb = (tid & 1) << 6;                 // byte col offset 0/64
  const int sx = (srow & 7) << 4;                   // LDS XOR swizzle
  const unsigned short* ga = A  + (size_t)(m0 + srow) * Kn + ((tid & 1) << 5);
  const unsigned short* gb = Bt + (size_t)(n0 + srow) * Kn + ((tid & 1) << 5);
  char* lAc = (char*)As + srow * 128;
  char* lBc = (char*)Bs + srow * 128;
  for (int k0 = 0; k0 < Kn; k0 += 64) {
    const int4* gav = (const int4*)(ga + k0);
    const int4* gbv = (const int4*)(gb + k0);
    int4 a0 = gav[0], a1 = gav[1], a2 = gav[2], a3 = gav[3];
    int4 b0 = gbv[0], b1 = gbv[1], b2 = gbv[2], b3 = gbv[3];
    *(int4*)(lAc + ((scolb +  0) ^ sx)) = a0;
    *(int4*)(lAc + ((scolb + 16) ^ sx)) = a1;
    *(int4*)(lAc + ((scolb + 32) ^ sx)) = a2;
    *(int4*)(lAc + ((scolb + 48) ^ sx)) = a3;
    *(int4*)(lBc + ((scolb +  0) ^ sx)) = b0;
    *(int4*)(lBc + ((scolb + 16) ^ sx)) = b1;
    *(int4*)(lBc + ((scolb + 32) ^ sx)) = b2;
    *(int4*)(lBc + ((scolb + 48) ^ sx)) = b3;
    __syncthreads();
    #pragma unroll
    for (int kk = 0; kk < 64; kk += 32) {
      bf16x8 af[4], bfr[4];
      #pragma unroll
      for (int i = 0; i < 4; ++i) {
        int row = wr * 64 + i * 16 + lrow;
        af[i] = *(const bf16x8*)((const char*)As + ((row * 128 + (kk + lko) * 2) ^ ((row & 7) << 4)));
      }
      #pragma unroll
      for (int j = 0; j < 4; ++j) {
        int row = wc * 64 + j * 16 + lrow;
        bfr[j] = *(const bf16x8*)((const char*)Bs + ((row * 128 + (kk + lko) * 2) ^ ((row & 7) << 4)));
      }
      #pragma unroll
      for (int i = 0; i < 4; ++i)
        #pragma unroll
        for (int j = 0; j < 4; ++j)
          acc[i][j] = __builtin_amdgcn_mfma_f32_16x16x32_bf16(af[i], bfr[j], acc[i][j], 0, 0, 0);
    }
    __syncthreads();
  }
  const float alpha = (sA[0] + EPS_) * (sB[0] + EPS_) * (1.0f / 16129.0f);
  const int orow = (lane >> 4) << 2;
  float amax = 0.f;
  #pragma unroll
  for (int i = 0; i < 4; ++i) {
    #pragma unroll
    for (int j = 0; j < 4; ++j) {
      int col = n0 + wc * 64 + j * 16 + lrow;
      float bc = bias[col];
      #pragma unroll
      for (int rr = 0; rr < 4; ++rr) {
        int row = m0 + wr * 64 + i * 16 + orow + rr;
        float val = acc[i][j][rr] * alpha + bc;
        C[(size_t)row * Nn + col] = val;
        amax = fmaxf(amax, fabsf(val));
      }
    }
  }
  if (pmax) {
    #pragma unroll
    for (int off = 32; off; off >>= 1) amax = fmaxf(amax, __shfl_down(amax, off));
    if (lane == 0) atomicMax((unsigned int*)&pmax[n0 / partDiv], __float_as_uint(amax));
  }
}

// ---------------- quantize qkv into int8 head-layouts ----------------
// q,k: [bh][n][d]; v stored transposed: vT [bh][d][n]
__global__ __launch_bounds__(256) void k_quant_heads(const float* __restrict__ qkvf, const float* __restrict__ g,
                                                     int8_t* __restrict__ qo, int8_t* __restrict__ ko,
                                                     int8_t* __restrict__ vT) {
  const unsigned total = (unsigned)M_ * TC_;
  const float s0 = g[3] + EPS_, s1 = g[4] + EPS_, s2 = g[5] + EPS_;
  for (unsigned i = blockIdx.x * blockDim.x + threadIdx.x; i < total; i += gridDim.x * blockDim.x) {
    unsigned m = i / 2304u, o = i % 2304u;
    unsigned part = o / 768u, c = o % 768u;
    unsigned h = c >> 6, d = c & 63;
    unsigned b = m >> 10, n = m & 1023;
    float s = (part == 0) ? s0 : (part == 1) ? s1 : s2;
    float v = qkvf[i];
    float y = fminf(fabsf(v) / s, 1.0f);
    int q = (int)rintf(y * 127.0f);
    if (v < 0.f) q = -q;
    unsigned bh = b * 12 + h;
    if (part == 0)      qo[((size_t)bh * 1024 + n) * 64 + d] = (int8_t)q;
    else if (part == 1) ko[((size_t)bh * 1024 + n) * 64 + d] = (int8_t)q;
    else                vT[((size_t)bh * 64 + d) * 1024 + n] = (int8_t)q;
  }
}

// ---------------- attention pass 1 (MFMA): per-row max + softmax denom ----------------
// grid: 768 blocks = bh(96) x row-tile(8); 256 threads = 4 waves, each wave 32 rows.
__global__ __launch_bounds__(256) void k_attn_stats_mfma(
    const int8_t* __restrict__ qi8, const int8_t* __restrict__ ki8,
    const float* __restrict__ g, float* __restrict__ rowmax, float* __restrict__ denomv,
    unsigned int* __restrict__ gminden) {
  __shared__ unsigned short Ks[64 * 64];
  const int bh = blockIdx.x >> 3, rt = blockIdx.x & 7;
  const int tid = threadIdx.x, w = tid >> 6, lane = tid & 63;
  const int lrow = lane & 15, lko = (lane >> 4) << 3;
  const int8_t* qbase = qi8 + (size_t)bh * 65536;
  const int8_t* kbase = ki8 + (size_t)bh * 65536;
  bf16x8 qf[2][2];
  #pragma unroll
  for (int i = 0; i < 2; ++i)
    #pragma unroll
    for (int ks = 0; ks < 2; ++ks)
      qf[i][ks] = expand8(*(const int2*)(qbase + (size_t)(rt*128 + w*32 + i*16 + lrow) * 64 + ks*32 + lko));
  const float qkScale = (g[3] + EPS_) * (g[4] + EPS_) * (1.0f / 16129.0f) * SCALE_;
  float m[8], den[8];
  #pragma unroll
  for (int r = 0; r < 8; ++r) { m[r] = -3.0e38f; den[r] = 0.f; }
  const int srow = tid >> 2, sc = tid & 3;
  const int sx = (srow & 7) << 4;
  for (int t = 0; t < 16; ++t) {
    __syncthreads();
    {
      int4 raw = *(const int4*)(kbase + (size_t)(t*64 + srow) * 64 + sc * 16);
      int4 lo, hi; expand16(raw, lo, hi);
      int bb = srow * 128 + sc * 32;
      *(int4*)((char*)Ks + ( bb       ^ sx)) = lo;
      *(int4*)((char*)Ks + ((bb + 16) ^ sx)) = hi;
    }
    __syncthreads();
    f32x4 acc[2][4] = {};
    #pragma unroll
    for (int ks = 0; ks < 2; ++ks) {
      bf16x8 kf[4];
      #pragma unroll
      for (int j = 0; j < 4; ++j) {
        int row = j * 16 + lrow;
        kf[j] = *(const bf16x8*)((const char*)Ks + ((row * 128 + (ks*32 + lko) * 2) ^ ((row & 7) << 4)));
      }
      #pragma unroll
      for (int i = 0; i < 2; ++i)
        #pragma unroll
        for (int j = 0; j < 4; ++j)
          acc[i][j] = __builtin_amdgcn_mfma_f32_16x16x32_bf16(qf[i][ks], kf[j], acc[i][j], 0, 0, 0);
    }
    #pragma unroll
    for (int i = 0; i < 2; ++i)
      #pragma unroll
      for (int rr = 0; rr < 4; ++rr) {
        float s0 = acc[i][0][rr] * qkScale, s1 = acc[i][1][rr] * qkScale;
        float s2 = acc[i][2][rr] * qkScale, s3 = acc[i][3][rr] * qkScale;
        float mx = fmaxf(fmaxf(s0, s1), fmaxf(s2, s3));
        #pragma unroll
        for (int off = 1; off < 16; off <<= 1) mx = fmaxf(mx, __shfl_xor(mx, off));
        const int r = i * 4 + rr;
        float mnew = fmaxf(m[r], mx);
        float sum = expf(s0 - mnew) + expf(s1 - mnew) + expf(s2 - mnew) + expf(s3 - mnew);
        #pragma unroll
        for (int off = 1; off < 16; off <<= 1) sum += __shfl_xor(sum, off);
        den[r] = den[r] * expf(m[r] - mnew) + sum;
        m[r] = mnew;
      }
  }
  if (lrow == 0) {
    #pragma unroll
    for (int i = 0; i < 2; ++i)
      #pragma unroll
      for (int rr = 0; rr < 4; ++rr) {
        const int r = i * 4 + rr;
        size_t rg = (size_t)bh * 1024 + rt * 128 + w * 32 + i * 16 + (lane >> 4) * 4 + rr;
        rowmax[rg] = m[r];
        denomv[rg] = den[r];
        atomicMin(gminden, __float_as_uint(den[r]));
      }
  }
}

// ---------------- attention pass 2 (MFMA): quantized P @ quantized V ----------------
__global__ __launch_bounds__(256) void k_attn_pv_mfma(
    const int8_t* __restrict__ qi8, const int8_t* __restrict__ ki8, const int8_t* __restrict__ vti8,
    const float* __restrict__ g, const unsigned int* __restrict__ gminden,
    const float* __restrict__ rowmax, const float* __restrict__ denomv,
    float* __restrict__ aof, float* __restrict__ gamax) {
  __shared__ unsigned short Ks[64 * 64];
  __shared__ unsigned short Vs[64 * 64];
  __shared__ unsigned short Ps[128 * 64];
  const int bh = blockIdx.x >> 3, rt = blockIdx.x & 7;
  const int b = bh / 12, h = bh % 12;
  const int tid = threadIdx.x, w = tid >> 6, lane = tid & 63;
  const int lrow = lane & 15, lko = (lane >> 4) << 3;
  const int8_t* qbase = qi8 + (size_t)bh * 65536;
  const int8_t* kbase = ki8 + (size_t)bh * 65536;
  const int8_t* vbase = vti8 + (size_t)bh * 65536;
  bf16x8 qf[2][2];
  #pragma unroll
  for (int i = 0; i < 2; ++i)
    #pragma unroll
    for (int ks = 0; ks < 2; ++ks)
      qf[i][ks] = expand8(*(const int2*)(qbase + (size_t)(rt*128 + w*32 + i*16 + lrow) * 64 + ks*32 + lko));
  const float qkScale = (g[3] + EPS_) * (g[4] + EPS_) * (1.0f / 16129.0f) * SCALE_;
  const float minden = __uint_as_float(*gminden);
  const float sa = 1.0f / minden + EPS_;
  const float invSa = 1.0f / sa;
  const float sv = g[5] + EPS_;
  const float pvScale = sa * sv * (1.0f / 32385.0f);   // /(255*127)
  float rm[8], ivd[8];
  {
    const size_t rowb = (size_t)bh * 1024 + rt * 128 + w * 32;
    #pragma unroll
    for (int i = 0; i < 2; ++i)
      #pragma unroll
      for (int rr = 0; rr < 4; ++rr) {
        size_t rg = rowb + i * 16 + (lane >> 4) * 4 + rr;
        rm[i * 4 + rr] = rowmax[rg];
        ivd[i * 4 + rr] = 1.0f / denomv[rg];
      }
  }
  f32x4 accO[2][4] = {};
  const int srow = tid >> 2, sc = tid & 3;
  const int sx = (srow & 7) << 4;
  for (int t = 0; t < 16; ++t) {
    __syncthreads();
    {
      int4 kraw = *(const int4*)(kbase + (size_t)(t*64 + srow) * 64 + sc * 16);
      int4 vraw = *(const int4*)(vbase + (size_t)srow * 1024 + t * 64 + sc * 16);
      int4 lo, hi;
      int bb = srow * 128 + sc * 32;
      expand16(kraw, lo, hi);
      *(int4*)((char*)Ks + ( bb       ^ sx)) = lo;
      *(int4*)((char*)Ks + ((bb + 16) ^ sx)) = hi;
      expand16(vraw, lo, hi);
      *(int4*)((char*)Vs + ( bb       ^ sx)) = lo;
      *(int4*)((char*)Vs + ((bb + 16) ^ sx)) = hi;
    }
    __syncthreads();
    f32x4 acc[2][4] = {};
    #pragma unroll
    for (int ks = 0; ks < 2; ++ks) {
      bf16x8 kf[4];
      #pragma unroll
      for (int j = 0; j < 4; ++j) {
        int row = j * 16 + lrow;
        kf[j] = *(const bf16x8*)((const char*)Ks + ((row * 128 + (ks*32 + lko) * 2) ^ ((row & 7) << 4)));
      }
      #pragma unroll
      for (int i = 0; i < 2; ++i)
        #pragma unroll
        for (int j = 0; j < 4; ++j)
          acc[i][j] = __builtin_amdgcn_mfma_f32_16x16x32_bf16(qf[i][ks], kf[j], acc[i][j], 0, 0, 0);
    }
    // softmax -> unsigned 8-bit quant levels (0..255, exact bf16) -> Ps
    #pragma unroll
    for (int i = 0; i < 2; ++i)
      #pragma unroll
      for (int rr = 0; rr < 4; ++rr) {
        const int r = i * 4 + rr;
        const int prow = w * 32 + i * 16 + (lane >> 4) * 4 + rr;
        #pragma unroll
        for (int j = 0; j < 4; ++j) {
          float s = acc[i][j][rr] * qkScale;
          float p = expf(s - rm[r]) * ivd[r];
          float av = rintf(fminf(p * invSa, 1.0f) * 255.0f);
          int col = j * 16 + lrow;
          *(unsigned short*)((char*)Ps + ((prow * 128 + col * 2) ^ ((prow & 7) << 4))) =
              (unsigned short)(__float_as_uint(av) >> 16);
        }
      }
    // O += P @ V  (A = Ps rows, Bt = Vs = vT[d][n])
    #pragma unroll
    for (int ks = 0; ks < 2; ++ks) {
      bf16x8 pf[2], vf[4];
      #pragma unroll
      for (int i = 0; i < 2; ++i) {
        int row = w * 32 + i * 16 + lrow;
        pf[i] = *(const bf16x8*)((const char*)Ps + ((row * 128 + (ks*32 + lko) * 2) ^ ((row & 7) << 4)));
      }
      #pragma unroll
      for (int j = 0; j < 4; ++j) {
        int row = j * 16 + lrow;
        vf[j] = *(const bf16x8*)((const char*)Vs + ((row * 128 + (ks*32 + lko) * 2) ^ ((row & 7) << 4)));
      }
      #pragma unroll
      for (int i = 0; i < 2; ++i)
        #pragma unroll
        for (int j = 0; j < 4; ++j)
          accO[i][j] = __builtin_amdgcn_mfma_f32_16x16x32_bf16(pf[i], vf[j], accO[i][j], 0, 0, 0);
    }
  }
  float amax = 0.f;
  #pragma unroll
  for (int i = 0; i < 2; ++i)
    #pragma unroll
    for (int j = 0; j < 4; ++j) {
      int d = j * 16 + lrow;
      #pragma unroll
      for (int rr = 0; rr < 4; ++rr) {
        int row = rt * 128 + w * 32 + i * 16 + (lane >> 4) * 4 + rr;
        float val = accO[i][j][rr] * pvScale;
        aof[((size_t)(b * 1024 + row)) * 768 + h * 64 + d] = val;
        amax = fmaxf(amax, fabsf(val));
      }
    }
  #pragma unroll
  for (int off = 32; off; off >>= 1) amax = fmaxf(amax, __shfl_down(amax, off));
  if (lane == 0) atomicMax((unsigned int*)gamax, __float_as_uint(amax));
}

extern "C" void kernel_launch(void* const* d_in, const int* in_sizes, int n_in,
                              void* d_out, int out_size, void* d_ws, size_t ws_size,
                              hipStream_t stream) {
  const float* x      = (const float*)d_in[0];   // [8,1024,768]
  const float* qkv_w  = (const float*)d_in[1];   // [2304,768]
  const float* qkv_b  = (const float*)d_in[2];   // [2304]
  const float* proj_w = (const float*)d_in[3];   // [768,768]
  const float* proj_b = (const float*)d_in[4];   // [768]
  float* out = (float*)d_out;

  char* w = (char*)d_ws;
  float*          g      = (float*)(w + 0);                 // 8 stats
  float*          rowmax = (float*)(w + 256);               // 393216 B
  float*          denomv = (float*)(w + 393472);            // 393216 B
  int8_t*         qi8    = (int8_t*)(w + 786688);           // 6291456 B
  int8_t*         ki8    = (int8_t*)(w + 7078144);          // 6291456 B
  int8_t*         vT     = (int8_t*)(w + 13369600);         // 6291456 B
  unsigned short* pw     = (unsigned short*)(w + 19661056); // 1179648 B (live to end)
  unsigned short* xq     = (unsigned short*)(w + 20840704); // 12582912 B (dead after GEMM1)
  unsigned short* wq     = (unsigned short*)(w + 33423616); //  3538944 B (dead after GEMM1)
  float*          qkvf   = (float*)(w + 36962560);          // 75497472 B (dead after quant_heads)
  float*          aof    = (float*)(w + 36962560);          // 25165824 B (aliases dead qkvf)
  unsigned short* aobf   = (unsigned short*)(w + 62128384); // 12582912 B (inside qkvf region)

  hipLaunchKernelGGL(k_init, dim3(1), dim3(64), 0, stream, g);

  hipLaunchKernelGGL(k_absmax4, dim3(1024), dim3(256), 0, stream, (const float4*)x,      6291456u / 4, &g[0]);
  hipLaunchKernelGGL(k_absmax4, dim3(512),  dim3(256), 0, stream, (const float4*)qkv_w,  1769472u / 4, &g[1]);
  hipLaunchKernelGGL(k_absmax4, dim3(256),  dim3(256), 0, stream, (const float4*)proj_w,  589824u / 4, &g[2]);

  hipLaunchKernelGGL(k_quant_bf16, dim3(2048), dim3(256), 0, stream, x,      6291456u, &g[0], xq);
  hipLaunchKernelGGL(k_quant_bf16, dim3(1024), dim3(256), 0, stream, qkv_w,  1769472u, &g[1], wq);
  hipLaunchKernelGGL(k_quant_bf16, dim3(512),  dim3(256), 0, stream, proj_w,  589824u, &g[2], pw);

  // qkv = xq @ wq^T * (sx*sw/127^2) + b -> f32 [8192][2304]; also per-part |max| -> g[3..5]
  hipLaunchKernelGGL(k_gemm, dim3(TC_ / 128, M_ / 128), dim3(256), 0, stream,
                     xq, wq, qkv_b, qkvf, M_, TC_, C_, &g[0], &g[1], &g[3], 768);

  hipLaunchKernelGGL(k_quant_heads, dim3(2048), dim3(256), 0, stream, qkvf, g, qi8, ki8, vT);

  hipLaunchKernelGGL(k_attn_stats_mfma, dim3(768), dim3(256), 0, stream,
                     qi8, ki8, g, rowmax, denomv, (unsigned int*)&g[6]);
  hipLaunchKernelGGL(k_attn_pv_mfma, dim3(768), dim3(256), 0, stream,
                     qi8, ki8, vT, g, (const unsigned int*)&g[6], rowmax, denomv, aof, &g[7]);

  hipLaunchKernelGGL(k_quant_bf16, dim3(2048), dim3(256), 0, stream, aof, 6291456u, &g[7], aobf);

  // out = aobf @ pw^T * (sao*spw/127^2) + proj_b -> d_out f32 [8192][768]
  hipLaunchKernelGGL(k_gemm, dim3(C_ / 128, M_ / 128), dim3(256), 0, stream,
                     aobf, pw, proj_b, out, M_, C_, C_, &g[7], &g[2], (float*)nullptr, 1);

  (void)in_sizes; (void)n_in; (void)out_size; (void)ws_size;
}

// Round 3
// 442.726 us; speedup vs baseline: 3.1586x; 1.6479x over previous
//
#include <hip/hip_runtime.h>
#include <hip/hip_bf16.h>
#include <cstdint>
#include <cstddef>

// Problem constants
#define B_    8
#define SEQ_  1024
#define C_    768
#define H_    12
#define D_    64
#define TC_   2304          // 3*C
#define M_    8192          // B*SEQ
#define EPS_  1e-7f
#define SCALE_ 0.036084391824351615f  // 768^-0.5

typedef __attribute__((ext_vector_type(8))) short bf16x8;
typedef __attribute__((ext_vector_type(4))) float f32x4;

// int8 -> bf16 integer levels (exact for |v|<=255)
__device__ __forceinline__ bf16x8 expand8(int2 raw) {
  union { int2 v; signed char c[8]; } u; u.v = raw;
  bf16x8 r;
  #pragma unroll
  for (int j = 0; j < 8; ++j) {
    float f = (float)(int)u.c[j];
    r[j] = (short)(__float_as_uint(f) >> 16);
  }
  return r;
}
__device__ __forceinline__ void expand16(int4 raw, int4& lo, int4& hi) {
  union { int4 v; signed char c[16]; } u; u.v = raw;
  unsigned short s[16];
  #pragma unroll
  for (int j = 0; j < 16; ++j) {
    float f = (float)(int)u.c[j];
    s[j] = (unsigned short)(__float_as_uint(f) >> 16);
  }
  lo = *(const int4*)&s[0]; hi = *(const int4*)&s[8];
}

// ---------------- init global stats ----------------
// g[0]=max|x| g[1]=max|qkv_w| g[2]=max|proj_w| g[3]=max|q| g[4]=max|k| g[5]=max|v|
// g[6]=min softmax-denom  g[7]=max|attn_out|
__global__ void k_init(float* g) {
  if (threadIdx.x == 0) {
    g[0]=0.f; g[1]=0.f; g[2]=0.f; g[3]=0.f; g[4]=0.f; g[5]=0.f;
    g[6]=3.402823466e+38f;
    g[7]=0.f;
  }
}

// ---------------- abs-max reduction (float4) ----------------
__global__ __launch_bounds__(256) void k_absmax4(const float4* __restrict__ p, unsigned n4, float* gout) {
  float m = 0.f;
  for (unsigned i = blockIdx.x * blockDim.x + threadIdx.x; i < n4; i += gridDim.x * blockDim.x) {
    float4 v = p[i];
    m = fmaxf(m, fmaxf(fmaxf(fabsf(v.x), fabsf(v.y)), fmaxf(fabsf(v.z), fabsf(v.w))));
  }
  #pragma unroll
  for (int off = 32; off; off >>= 1) m = fmaxf(m, __shfl_down(m, off));
  if ((threadIdx.x & 63) == 0) atomicMax((unsigned int*)gout, __float_as_uint(m));
}

// ---------------- signed fake-quant -> bf16 integer levels ----------------
__global__ __launch_bounds__(256) void k_quant_bf16(const float* __restrict__ in, unsigned n,
                                                    const float* __restrict__ gmax,
                                                    unsigned short* __restrict__ out) {
  const float s = *gmax + EPS_;
  for (unsigned i = blockIdx.x * blockDim.x + threadIdx.x; i < n; i += gridDim.x * blockDim.x) {
    float v = in[i];
    float y = fminf(fabsf(v) / s, 1.0f);
    float q = rintf(y * 127.0f);          // half-to-even, matches jnp.round
    if (v < 0.f) q = -q;
    out[i] = (unsigned short)(__float_as_uint(q) >> 16);  // exact: integer <= 127
  }
}

// ---------------- bf16-integer MFMA GEMM: C = alpha * (A . Bt^T) + bias ----------------
__global__ __launch_bounds__(256) void k_gemm(const unsigned short* __restrict__ A,
                                              const unsigned short* __restrict__ Bt,
                                              const float* __restrict__ bias,
                                              float* __restrict__ C,
                                              int Mn, int Nn, int Kn,
                                              const float* __restrict__ sA, const float* __restrict__ sB,
                                              float* pmax, int partDiv) {
  __shared__ unsigned short As[128 * 64];
  __shared__ unsigned short Bs[128 * 64];
  const int tid = threadIdx.x;
  const int n0 = blockIdx.x * 128, m0 = blockIdx.y * 128;
  const int wid = tid >> 6, lane = tid & 63;
  const int wr = wid >> 1, wc = wid & 1;            // 2x2 waves -> 64x64 each
  const int lrow = lane & 15;
  const int lko = (lane >> 4) << 3;                 // k offset 0/8/16/24
  f32x4 acc[4][4] = {};
  const int srow = tid >> 1;
  const int scolb = (tid & 1) << 6;                 // byte col offset 0/64
  const int sx = (srow & 7) << 4;                   // LDS XOR swizzle
  const unsigned short* ga = A  + (size_t)(m0 + srow) * Kn + ((tid & 1) << 5);
  const unsigned short* gb = Bt + (size_t)(n0 + srow) * Kn + ((tid & 1) << 5);
  char* lAc = (char*)As + srow * 128;
  char* lBc = (char*)Bs + srow * 128;
  for (int k0 = 0; k0 < Kn; k0 += 64) {
    const int4* gav = (const int4*)(ga + k0);
    const int4* gbv = (const int4*)(gb + k0);
    int4 a0 = gav[0], a1 = gav[1], a2 = gav[2], a3 = gav[3];
    int4 b0 = gbv[0], b1 = gbv[1], b2 = gbv[2], b3 = gbv[3];
    *(int4*)(lAc + ((scolb +  0) ^ sx)) = a0;
    *(int4*)(lAc + ((scolb + 16) ^ sx)) = a1;
    *(int4*)(lAc + ((scolb + 32) ^ sx)) = a2;
    *(int4*)(lAc + ((scolb + 48) ^ sx)) = a3;
    *(int4*)(lBc + ((scolb +  0) ^ sx)) = b0;
    *(int4*)(lBc + ((scolb + 16) ^ sx)) = b1;
    *(int4*)(lBc + ((scolb + 32) ^ sx)) = b2;
    *(int4*)(lBc + ((scolb + 48) ^ sx)) = b3;
    __syncthreads();
    #pragma unroll
    for (int kk = 0; kk < 64; kk += 32) {
      bf16x8 af[4], bfr[4];
      #pragma unroll
      for (int i = 0; i < 4; ++i) {
        int row = wr * 64 + i * 16 + lrow;
        af[i] = *(const bf16x8*)((const char*)As + ((row * 128 + (kk + lko) * 2) ^ ((row & 7) << 4)));
      }
      #pragma unroll
      for (int j = 0; j < 4; ++j) {
        int row = wc * 64 + j * 16 + lrow;
        bfr[j] = *(const bf16x8*)((const char*)Bs + ((row * 128 + (kk + lko) * 2) ^ ((row & 7) << 4)));
      }
      #pragma unroll
      for (int i = 0; i < 4; ++i)
        #pragma unroll
        for (int j = 0; j < 4; ++j)
          acc[i][j] = __builtin_amdgcn_mfma_f32_16x16x32_bf16(af[i], bfr[j], acc[i][j], 0, 0, 0);
    }
    __syncthreads();
  }
  const float alpha = (sA[0] + EPS_) * (sB[0] + EPS_) * (1.0f / 16129.0f);
  const int orow = (lane >> 4) << 2;
  float amax = 0.f;
  #pragma unroll
  for (int i = 0; i < 4; ++i) {
    #pragma unroll
    for (int j = 0; j < 4; ++j) {
      int col = n0 + wc * 64 + j * 16 + lrow;
      float bc = bias[col];
      #pragma unroll
      for (int rr = 0; rr < 4; ++rr) {
        int row = m0 + wr * 64 + i * 16 + orow + rr;
        float val = acc[i][j][rr] * alpha + bc;
        C[(size_t)row * Nn + col] = val;
        amax = fmaxf(amax, fabsf(val));
      }
    }
  }
  if (pmax) {
    #pragma unroll
    for (int off = 32; off; off >>= 1) amax = fmaxf(amax, __shfl_down(amax, off));
    if (lane == 0) atomicMax((unsigned int*)&pmax[n0 / partDiv], __float_as_uint(amax));
  }
}

// ---------------- quantize qkv into int8 head-layouts ----------------
__global__ __launch_bounds__(256) void k_quant_heads(const float* __restrict__ qkvf, const float* __restrict__ g,
                                                     int8_t* __restrict__ qo, int8_t* __restrict__ ko,
                                                     int8_t* __restrict__ vT) {
  const unsigned total = (unsigned)M_ * TC_;
  const float s0 = g[3] + EPS_, s1 = g[4] + EPS_, s2 = g[5] + EPS_;
  for (unsigned i = blockIdx.x * blockDim.x + threadIdx.x; i < total; i += gridDim.x * blockDim.x) {
    unsigned m = i / 2304u, o = i % 2304u;
    unsigned part = o / 768u, c = o % 768u;
    unsigned h = c >> 6, d = c & 63;
    unsigned b = m >> 10, n = m & 1023;
    float s = (part == 0) ? s0 : (part == 1) ? s1 : s2;
    float v = qkvf[i];
    float y = fminf(fabsf(v) / s, 1.0f);
    int q = (int)rintf(y * 127.0f);
    if (v < 0.f) q = -q;
    unsigned bh = b * 12 + h;
    if (part == 0)      qo[((size_t)bh * 1024 + n) * 64 + d] = (int8_t)q;
    else if (part == 1) ko[((size_t)bh * 1024 + n) * 64 + d] = (int8_t)q;
    else                vT[((size_t)bh * 64 + d) * 1024 + n] = (int8_t)q;
  }
}

// ---------------- attention pass 1 (MFMA, swapped operands): per-row max + denom ----------------
// grid: 768 = bh(96) x rt(8); 256 thr = 4 waves, each wave 32 q-rows (2 blocks of 16).
// acc = mfma(K_frag, Q_frag): col = q-row, row = k-index -> in-lane online softmax.
__global__ __launch_bounds__(256) void k_attn_stats_mfma(
    const int8_t* __restrict__ qi8, const int8_t* __restrict__ ki8,
    const float* __restrict__ g, float* __restrict__ rowmax, float* __restrict__ denomv,
    unsigned int* __restrict__ gminden) {
  __shared__ unsigned short Ks[64 * 64];
  const int bh = blockIdx.x >> 3, rt = blockIdx.x & 7;
  const int tid = threadIdx.x, w = tid >> 6, lane = tid & 63;
  const int lrow = lane & 15, lko = (lane >> 4) << 3;
  const int8_t* qbase = qi8 + (size_t)bh * 65536;
  const int8_t* kbase = ki8 + (size_t)bh * 65536;
  bf16x8 qf[2][2];
  #pragma unroll
  for (int i = 0; i < 2; ++i)
    #pragma unroll
    for (int ks = 0; ks < 2; ++ks)
      qf[i][ks] = expand8(*(const int2*)(qbase + (size_t)(rt*128 + w*32 + i*16 + lrow) * 64 + ks*32 + lko));
  const float qkScale = (g[3] + EPS_) * (g[4] + EPS_) * (1.0f / 16129.0f) * SCALE_;
  float m[2] = {-3.0e38f, -3.0e38f}, den[2] = {0.f, 0.f};
  const int srow = tid >> 2, sc = tid & 3;
  const int sx = (srow & 7) << 4;
  for (int t = 0; t < 16; ++t) {
    __syncthreads();
    {
      int4 raw = *(const int4*)(kbase + (size_t)(t*64 + srow) * 64 + sc * 16);
      int4 lo, hi; expand16(raw, lo, hi);
      int bb = srow * 128 + sc * 32;
      *(int4*)((char*)Ks + ( bb       ^ sx)) = lo;
      *(int4*)((char*)Ks + ((bb + 16) ^ sx)) = hi;
    }
    __syncthreads();
    f32x4 acc[2][4] = {};
    #pragma unroll
    for (int ks = 0; ks < 2; ++ks) {
      bf16x8 kf[4];
      #pragma unroll
      for (int j = 0; j < 4; ++j) {
        int row = j * 16 + lrow;
        kf[j] = *(const bf16x8*)((const char*)Ks + ((row * 128 + (ks*32 + lko) * 2) ^ ((row & 7) << 4)));
      }
      #pragma unroll
      for (int i = 0; i < 2; ++i)
        #pragma unroll
        for (int j = 0; j < 4; ++j)
          acc[i][j] = __builtin_amdgcn_mfma_f32_16x16x32_bf16(kf[j], qf[i][ks], acc[i][j], 0, 0, 0);
    }
    // in-lane online softmax update (no cross-lane ops)
    #pragma unroll
    for (int i = 0; i < 2; ++i) {
      float mnew = m[i];
      #pragma unroll
      for (int j = 0; j < 4; ++j)
        #pragma unroll
        for (int rr = 0; rr < 4; ++rr)
          mnew = fmaxf(mnew, acc[i][j][rr] * qkScale);
      float d = den[i] * __expf(m[i] - mnew);
      #pragma unroll
      for (int j = 0; j < 4; ++j)
        #pragma unroll
        for (int rr = 0; rr < 4; ++rr)
          d += __expf(acc[i][j][rr] * qkScale - mnew);
      den[i] = d; m[i] = mnew;
    }
  }
  // merge the 4 hi-lane partitions of k, once
  #pragma unroll
  for (int i = 0; i < 2; ++i) {
    #pragma unroll
    for (int off = 16; off <= 32; off <<= 1) {
      float mo = __shfl_xor(m[i], off);
      float dо = __shfl_xor(den[i], off);
      float mg = fmaxf(m[i], mo);
      den[i] = den[i] * __expf(m[i] - mg) + dо * __expf(mo - mg);
      m[i] = mg;
    }
  }
  if (lane < 16) {
    #pragma unroll
    for (int i = 0; i < 2; ++i) {
      size_t rg = (size_t)bh * 1024 + rt * 128 + w * 32 + i * 16 + lane;
      rowmax[rg] = m[i];
      denomv[rg] = den[i];
      atomicMin(gminden, __float_as_uint(den[i]));
    }
  }
}

// ---------------- attention pass 2 (MFMA, swapped QK^T): quantized P @ quantized V ----------------
__global__ __launch_bounds__(256) void k_attn_pv_mfma(
    const int8_t* __restrict__ qi8, const int8_t* __restrict__ ki8, const int8_t* __restrict__ vti8,
    const float* __restrict__ g, const unsigned int* __restrict__ gminden,
    const float* __restrict__ rowmax, const float* __restrict__ denomv,
    float* __restrict__ aof, float* __restrict__ gamax) {
  __shared__ unsigned short Ks[64 * 64];
  __shared__ unsigned short Vs[64 * 64];
  __shared__ unsigned short Ps[128 * 64];
  const int bh = blockIdx.x >> 3, rt = blockIdx.x & 7;
  const int b = bh / 12, h = bh % 12;
  const int tid = threadIdx.x, w = tid >> 6, lane = tid & 63;
  const int lrow = lane & 15, lko = (lane >> 4) << 3;
  const int8_t* qbase = qi8 + (size_t)bh * 65536;
  const int8_t* kbase = ki8 + (size_t)bh * 65536;
  const int8_t* vbase = vti8 + (size_t)bh * 65536;
  bf16x8 qf[2][2];
  #pragma unroll
  for (int i = 0; i < 2; ++i)
    #pragma unroll
    for (int ks = 0; ks < 2; ++ks)
      qf[i][ks] = expand8(*(const int2*)(qbase + (size_t)(rt*128 + w*32 + i*16 + lrow) * 64 + ks*32 + lko));
  const float qkScale = (g[3] + EPS_) * (g[4] + EPS_) * (1.0f / 16129.0f) * SCALE_;
  const float minden = __uint_as_float(*gminden);
  const float sa = 1.0f / minden + EPS_;
  const float invSa = 1.0f / sa;
  const float sv = g[5] + EPS_;
  const float pvScale = sa * sv * (1.0f / 32385.0f);   // /(255*127)
  float rm2[2], ivd2[2];
  {
    const size_t rowb = (size_t)bh * 1024 + rt * 128 + w * 32;
    #pragma unroll
    for (int i = 0; i < 2; ++i) {
      rm2[i]  = rowmax[rowb + i * 16 + lrow];
      ivd2[i] = 1.0f / denomv[rowb + i * 16 + lrow];
    }
  }
  f32x4 accO[2][4] = {};
  const int srow = tid >> 2, sc = tid & 3;
  const int sx = (srow & 7) << 4;
  for (int t = 0; t < 16; ++t) {
    __syncthreads();
    {
      int4 kraw = *(const int4*)(kbase + (size_t)(t*64 + srow) * 64 + sc * 16);
      int4 vraw = *(const int4*)(vbase + (size_t)srow * 1024 + t * 64 + sc * 16);
      int4 lo, hi;
      int bb = srow * 128 + sc * 32;
      expand16(kraw, lo, hi);
      *(int4*)((char*)Ks + ( bb       ^ sx)) = lo;
      *(int4*)((char*)Ks + ((bb + 16) ^ sx)) = hi;
      expand16(vraw, lo, hi);
      *(int4*)((char*)Vs + ( bb       ^ sx)) = lo;
      *(int4*)((char*)Vs + ((bb + 16) ^ sx)) = hi;
    }
    __syncthreads();
    f32x4 acc[2][4] = {};
    #pragma unroll
    for (int ks = 0; ks < 2; ++ks) {
      bf16x8 kf[4];
      #pragma unroll
      for (int j = 0; j < 4; ++j) {
        int row = j * 16 + lrow;
        kf[j] = *(const bf16x8*)((const char*)Ks + ((row * 128 + (ks*32 + lko) * 2) ^ ((row & 7) << 4)));
      }
      #pragma unroll
      for (int i = 0; i < 2; ++i)
        #pragma unroll
        for (int j = 0; j < 4; ++j)
          acc[i][j] = __builtin_amdgcn_mfma_f32_16x16x32_bf16(kf[j], qf[i][ks], acc[i][j], 0, 0, 0);
    }
    // softmax -> unsigned 8-bit quant levels (0..255, exact bf16) -> Ps (in-lane)
    #pragma unroll
    for (int i = 0; i < 2; ++i) {
      const int q = w * 32 + i * 16 + lrow;
      const int kb = (lane >> 4) << 2;           // 0,4,8,12
      #pragma unroll
      for (int j = 0; j < 4; ++j) {
        unsigned int u01, u23;
        {
          float s0 = acc[i][j][0] * qkScale;
          float s1 = acc[i][j][1] * qkScale;
          float s2 = acc[i][j][2] * qkScale;
          float s3 = acc[i][j][3] * qkScale;
          float p0 = __expf(s0 - rm2[i]) * ivd2[i];
          float p1 = __expf(s1 - rm2[i]) * ivd2[i];
          float p2 = __expf(s2 - rm2[i]) * ivd2[i];
          float p3 = __expf(s3 - rm2[i]) * ivd2[i];
          float a0 = rintf(fminf(p0 * invSa, 1.0f) * 255.0f);
          float a1 = rintf(fminf(p1 * invSa, 1.0f) * 255.0f);
          float a2 = rintf(fminf(p2 * invSa, 1.0f) * 255.0f);
          float a3 = rintf(fminf(p3 * invSa, 1.0f) * 255.0f);
          u01 = (__float_as_uint(a0) >> 16) | ((__float_as_uint(a1) >> 16) << 16);
          u23 = (__float_as_uint(a2) >> 16) | ((__float_as_uint(a3) >> 16) << 16);
        }
        int byteoff = (q * 128 + (j * 16 + kb) * 2) ^ ((q & 7) << 4);
        uint2 pk; pk.x = u01; pk.y = u23;
        *(uint2*)((char*)Ps + byteoff) = pk;
      }
    }
    // O += P @ V  (A = Ps rows = q, Bt = Vs = vT[d][k])
    #pragma unroll
    for (int ks = 0; ks < 2; ++ks) {
      bf16x8 pf[2], vf[4];
      #pragma unroll
      for (int i = 0; i < 2; ++i) {
        int row = w * 32 + i * 16 + lrow;
        pf[i] = *(const bf16x8*)((const char*)Ps + ((row * 128 + (ks*32 + lko) * 2) ^ ((row & 7) << 4)));
      }
      #pragma unroll
      for (int j = 0; j < 4; ++j) {
        int row = j * 16 + lrow;
        vf[j] = *(const bf16x8*)((const char*)Vs + ((row * 128 + (ks*32 + lko) * 2) ^ ((row & 7) << 4)));
      }
      #pragma unroll
      for (int i = 0; i < 2; ++i)
        #pragma unroll
        for (int j = 0; j < 4; ++j)
          accO[i][j] = __builtin_amdgcn_mfma_f32_16x16x32_bf16(pf[i], vf[j], accO[i][j], 0, 0, 0);
    }
  }
  float amax = 0.f;
  #pragma unroll
  for (int i = 0; i < 2; ++i)
    #pragma unroll
    for (int j = 0; j < 4; ++j) {
      int d = j * 16 + lrow;
      #pragma unroll
      for (int rr = 0; rr < 4; ++rr) {
        int row = rt * 128 + w * 32 + i * 16 + (lane >> 4) * 4 + rr;
        float val = accO[i][j][rr] * pvScale;
        aof[((size_t)(b * 1024 + row)) * 768 + h * 64 + d] = val;
        amax = fmaxf(amax, fabsf(val));
      }
    }
  #pragma unroll
  for (int off = 32; off; off >>= 1) amax = fmaxf(amax, __shfl_down(amax, off));
  if (lane == 0) atomicMax((unsigned int*)gamax, __float_as_uint(amax));
}

extern "C" void kernel_launch(void* const* d_in, const int* in_sizes, int n_in,
                              void* d_out, int out_size, void* d_ws, size_t ws_size,
                              hipStream_t stream) {
  const float* x      = (const float*)d_in[0];   // [8,1024,768]
  const float* qkv_w  = (const float*)d_in[1];   // [2304,768]
  const float* qkv_b  = (const float*)d_in[2];   // [2304]
  const float* proj_w = (const float*)d_in[3];   // [768,768]
  const float* proj_b = (const float*)d_in[4];   // [768]
  float* out = (float*)d_out;

  char* w = (char*)d_ws;
  float*          g      = (float*)(w + 0);                 // 8 stats
  float*          rowmax = (float*)(w + 256);               // 393216 B
  float*          denomv = (float*)(w + 393472);            // 393216 B
  int8_t*         qi8    = (int8_t*)(w + 786688);           // 6291456 B
  int8_t*         ki8    = (int8_t*)(w + 7078144);          // 6291456 B
  int8_t*         vT     = (int8_t*)(w + 13369600);         // 6291456 B
  unsigned short* pw     = (unsigned short*)(w + 19661056); // 1179648 B (live to end)
  unsigned short* xq     = (unsigned short*)(w + 20840704); // 12582912 B (dead after GEMM1)
  unsigned short* wq     = (unsigned short*)(w + 33423616); //  3538944 B (dead after GEMM1)
  float*          qkvf   = (float*)(w + 36962560);          // 75497472 B (dead after quant_heads)
  float*          aof    = (float*)(w + 36962560);          // 25165824 B (aliases dead qkvf)
  unsigned short* aobf   = (unsigned short*)(w + 62128384); // 12582912 B (inside qkvf region)

  hipLaunchKernelGGL(k_init, dim3(1), dim3(64), 0, stream, g);

  hipLaunchKernelGGL(k_absmax4, dim3(1024), dim3(256), 0, stream, (const float4*)x,      6291456u / 4, &g[0]);
  hipLaunchKernelGGL(k_absmax4, dim3(512),  dim3(256), 0, stream, (const float4*)qkv_w,  1769472u / 4, &g[1]);
  hipLaunchKernelGGL(k_absmax4, dim3(256),  dim3(256), 0, stream, (const float4*)proj_w,  589824u / 4, &g[2]);

  hipLaunchKernelGGL(k_quant_bf16, dim3(2048), dim3(256), 0, stream, x,      6291456u, &g[0], xq);
  hipLaunchKernelGGL(k_quant_bf16, dim3(1024), dim3(256), 0, stream, qkv_w,  1769472u, &g[1], wq);
  hipLaunchKernelGGL(k_quant_bf16, dim3(512),  dim3(256), 0, stream, proj_w,  589824u, &g[2], pw);

  // qkv = xq @ wq^T * (sx*sw/127^2) + b -> f32 [8192][2304]; also per-part |max| -> g[3..5]
  hipLaunchKernelGGL(k_gemm, dim3(TC_ / 128, M_ / 128), dim3(256), 0, stream,
                     xq, wq, qkv_b, qkvf, M_, TC_, C_, &g[0], &g[1], &g[3], 768);

  hipLaunchKernelGGL(k_quant_heads, dim3(2048), dim3(256), 0, stream, qkvf, g, qi8, ki8, vT);

  hipLaunchKernelGGL(k_attn_stats_mfma, dim3(768), dim3(256), 0, stream,
                     qi8, ki8, g, rowmax, denomv, (unsigned int*)&g[6]);
  hipLaunchKernelGGL(k_attn_pv_mfma, dim3(768), dim3(256), 0, stream,
                     qi8, ki8, vT, g, (const unsigned int*)&g[6], rowmax, denomv, aof, &g[7]);

  hipLaunchKernelGGL(k_quant_bf16, dim3(2048), dim3(256), 0, stream, aof, 6291456u, &g[7], aobf);

  // out = aobf @ pw^T * (sao*spw/127^2) + proj_b -> d_out f32 [8192][768]
  hipLaunchKernelGGL(k_gemm, dim3(C_ / 128, M_ / 128), dim3(256), 0, stream,
                     aobf, pw, proj_b, out, M_, C_, C_, &g[7], &g[2], (float*)nullptr, 1);

  (void)in_sizes; (void)n_in; (void)out_size; (void)ws_size;
}

// Round 4
// 304.516 us; speedup vs baseline: 4.5921x; 1.4539x over previous
//
#include <hip/hip_runtime.h>
#include <hip/hip_bf16.h>
#include <cstdint>
#include <cstddef>

// Problem constants
#define B_    8
#define SEQ_  1024
#define C_    768
#define H_    12
#define D_    64
#define TC_   2304          // 3*C
#define M_    8192          // B*SEQ
#define EPS_  1e-7f
#define SCALE_ 0.036084391824351615f  // 768^-0.5

typedef __attribute__((ext_vector_type(8))) short bf16x8;
typedef __attribute__((ext_vector_type(4))) float f32x4;

#define GLOAD_LDS16(gsrc, ldst) \
  __builtin_amdgcn_global_load_lds((const __attribute__((address_space(1))) unsigned int*)(gsrc), \
                                   (__attribute__((address_space(3))) unsigned int*)(ldst), 16, 0, 0)

// int8 -> bf16 integer levels (exact for |v|<=255)
__device__ __forceinline__ bf16x8 expand8(int2 raw) {
  union { int2 v; signed char c[8]; } u; u.v = raw;
  bf16x8 r;
  #pragma unroll
  for (int j = 0; j < 8; ++j) {
    float f = (float)(int)u.c[j];
    r[j] = (short)(__float_as_uint(f) >> 16);
  }
  return r;
}
__device__ __forceinline__ void expand16(int4 raw, int4& lo, int4& hi) {
  union { int4 v; signed char c[16]; } u; u.v = raw;
  unsigned short s[16];
  #pragma unroll
  for (int j = 0; j < 16; ++j) {
    float f = (float)(int)u.c[j];
    s[j] = (unsigned short)(__float_as_uint(f) >> 16);
  }
  lo = *(const int4*)&s[0]; hi = *(const int4*)&s[8];
}

// ---------------- init global stats ----------------
// g[0]=max|x| g[1]=max|qkv_w| g[2]=max|proj_w| g[3]=max|q| g[4]=max|k| g[5]=max|v|
// g[6]=min softmax-denom  g[7]=max|attn_out|
__global__ void k_init(float* g) {
  if (threadIdx.x == 0) {
    g[0]=0.f; g[1]=0.f; g[2]=0.f; g[3]=0.f; g[4]=0.f; g[5]=0.f;
    g[6]=3.402823466e+38f;
    g[7]=0.f;
  }
}

// ---------------- abs-max reduction (float4), 1 atomic per block ----------------
__global__ __launch_bounds__(256) void k_absmax4(const float4* __restrict__ p, unsigned n4, float* gout) {
  __shared__ float red[4];
  float m = 0.f;
  for (unsigned i = blockIdx.x * blockDim.x + threadIdx.x; i < n4; i += gridDim.x * blockDim.x) {
    float4 v = p[i];
    m = fmaxf(m, fmaxf(fmaxf(fabsf(v.x), fabsf(v.y)), fmaxf(fabsf(v.z), fabsf(v.w))));
  }
  #pragma unroll
  for (int off = 32; off; off >>= 1) m = fmaxf(m, __shfl_xor(m, off));
  if ((threadIdx.x & 63) == 0) red[threadIdx.x >> 6] = m;
  __syncthreads();
  if (threadIdx.x == 0) {
    m = fmaxf(fmaxf(red[0], red[1]), fmaxf(red[2], red[3]));
    atomicMax((unsigned int*)gout, __float_as_uint(m));
  }
}

// ---------------- signed fake-quant -> bf16 integer levels ----------------
__global__ __launch_bounds__(256) void k_quant_bf16(const float* __restrict__ in, unsigned n,
                                                    const float* __restrict__ gmax,
                                                    unsigned short* __restrict__ out) {
  const float s = *gmax + EPS_;
  for (unsigned i = blockIdx.x * blockDim.x + threadIdx.x; i < n; i += gridDim.x * blockDim.x) {
    float v = in[i];
    float y = fminf(fabsf(v) / s, 1.0f);
    float q = rintf(y * 127.0f);          // half-to-even, matches jnp.round
    if (v < 0.f) q = -q;
    out[i] = (unsigned short)(__float_as_uint(q) >> 16);  // exact: integer <= 127
  }
}

// ---------------- bf16-integer MFMA GEMM (m97 structure): C = alpha*(A.Bt^T) + bias ----------------
// A: [Mn][Kn], Bt: [Nn][Kn] bf16 int-levels; linear LDS + global_load_lds w16; XCD swizzle.
__global__ __launch_bounds__(256) void k_gemm(const unsigned short* __restrict__ A,
                                              const unsigned short* __restrict__ Bt,
                                              const float* __restrict__ bias,
                                              float* __restrict__ C,
                                              int Mn, int Nn, int Kn,
                                              const float* __restrict__ sA, const float* __restrict__ sB,
                                              float* pmax, int partDiv) {
  __shared__ unsigned short As[128 * 64];
  __shared__ unsigned short Bs[128 * 64];
  const int tid = threadIdx.x;
  // bijective XCD swizzle (nwg % 8 == 0 for both GEMMs)
  int flat = blockIdx.y * gridDim.x + blockIdx.x;
  int chunk = (gridDim.x * gridDim.y) >> 3;
  int nf = (flat & 7) * chunk + (flat >> 3);
  const int n0 = (nf % gridDim.x) * 128, m0 = (nf / gridDim.x) * 128;
  const int wid = tid >> 6, lane = tid & 63;
  const int wr = wid >> 1, wc = wid & 1;            // 2x2 waves -> 64x64 each
  const int lrow = lane & 15;
  const int lko = (lane >> 4) << 3;                 // k offset 0/8/16/24
  f32x4 acc[4][4] = {};
  // staging: wave w, call c: lane l loads 16B from row w*32+c*8+(l>>3), ushort col (l&7)*8
  const int gr = (wid << 5) + (lane >> 3);
  const int gc = (lane & 7) << 3;
  const unsigned short* ga = A  + (size_t)(m0 + gr) * Kn + gc;
  const unsigned short* gb = Bt + (size_t)(n0 + gr) * Kn + gc;
  for (int k0 = 0; k0 < Kn; k0 += 64) {
    #pragma unroll
    for (int c = 0; c < 4; ++c) {
      GLOAD_LDS16(ga + (size_t)(c * 8) * Kn + k0, &As[(wid * 32 + c * 8) * 64]);
      GLOAD_LDS16(gb + (size_t)(c * 8) * Kn + k0, &Bs[(wid * 32 + c * 8) * 64]);
    }
    asm volatile("s_waitcnt vmcnt(0)" ::: "memory");
    __syncthreads();
    #pragma unroll
    for (int kk = 0; kk < 64; kk += 32) {
      bf16x8 af[4], bfr[4];
      #pragma unroll
      for (int i = 0; i < 4; ++i) af[i]  = *(const bf16x8*)&As[(wr * 64 + i * 16 + lrow) * 64 + kk + lko];
      #pragma unroll
      for (int j = 0; j < 4; ++j) bfr[j] = *(const bf16x8*)&Bs[(wc * 64 + j * 16 + lrow) * 64 + kk + lko];
      #pragma unroll
      for (int i = 0; i < 4; ++i)
        #pragma unroll
        for (int j = 0; j < 4; ++j)
          acc[i][j] = __builtin_amdgcn_mfma_f32_16x16x32_bf16(af[i], bfr[j], acc[i][j], 0, 0, 0);
    }
    __syncthreads();
  }
  const float alpha = (sA[0] + EPS_) * (sB[0] + EPS_) * (1.0f / 16129.0f);
  const int orow = (lane >> 4) << 2;
  float amax = 0.f;
  #pragma unroll
  for (int i = 0; i < 4; ++i) {
    #pragma unroll
    for (int j = 0; j < 4; ++j) {
      int col = n0 + wc * 64 + j * 16 + lrow;
      float bc = bias[col];
      #pragma unroll
      for (int rr = 0; rr < 4; ++rr) {
        int row = m0 + wr * 64 + i * 16 + orow + rr;
        float val = acc[i][j][rr] * alpha + bc;
        C[(size_t)row * Nn + col] = val;
        amax = fmaxf(amax, fabsf(val));
      }
    }
  }
  if (pmax) {
    #pragma unroll
    for (int off = 32; off; off >>= 1) amax = fmaxf(amax, __shfl_xor(amax, off));
    if (lane == 0) atomicMax((unsigned int*)&pmax[n0 / partDiv], __float_as_uint(amax));
  }
}

// ---------------- quantize qkv into int8 head-layouts ----------------
__global__ __launch_bounds__(256) void k_quant_heads(const float* __restrict__ qkvf, const float* __restrict__ g,
                                                     int8_t* __restrict__ qo, int8_t* __restrict__ ko,
                                                     int8_t* __restrict__ vT) {
  const unsigned total = (unsigned)M_ * TC_;
  const float s0 = g[3] + EPS_, s1 = g[4] + EPS_, s2 = g[5] + EPS_;
  for (unsigned i = blockIdx.x * blockDim.x + threadIdx.x; i < total; i += gridDim.x * blockDim.x) {
    unsigned m = i / 2304u, o = i % 2304u;
    unsigned part = o / 768u, c = o % 768u;
    unsigned h = c >> 6, d = c & 63;
    unsigned b = m >> 10, n = m & 1023;
    float s = (part == 0) ? s0 : (part == 1) ? s1 : s2;
    float v = qkvf[i];
    float y = fminf(fabsf(v) / s, 1.0f);
    int q = (int)rintf(y * 127.0f);
    if (v < 0.f) q = -q;
    unsigned bh = b * 12 + h;
    if (part == 0)      qo[((size_t)bh * 1024 + n) * 64 + d] = (int8_t)q;
    else if (part == 1) ko[((size_t)bh * 1024 + n) * 64 + d] = (int8_t)q;
    else                vT[((size_t)bh * 64 + d) * 1024 + n] = (int8_t)q;
  }
}

// ---------------- attention pass 1 (swapped-QK MFMA, 64-row blocks, prefetch) ----------------
// grid: 1536 = bh(96) x rt(16); 4 waves x 16 q-rows.
__global__ __launch_bounds__(256) void k_attn_stats_mfma(
    const int8_t* __restrict__ qi8, const int8_t* __restrict__ ki8,
    const float* __restrict__ g, float* __restrict__ rowmax, float* __restrict__ denomv,
    unsigned int* __restrict__ gminden) {
  __shared__ unsigned short Ks[64 * 64];
  __shared__ float red[4];
  const int bh = blockIdx.x >> 4, rt = blockIdx.x & 15;
  const int tid = threadIdx.x, w = tid >> 6, lane = tid & 63;
  const int lrow = lane & 15, lko = (lane >> 4) << 3;
  const int8_t* qbase = qi8 + (size_t)bh * 65536;
  const int8_t* kbase = ki8 + (size_t)bh * 65536;
  bf16x8 qf[2];
  #pragma unroll
  for (int ks = 0; ks < 2; ++ks)
    qf[ks] = expand8(*(const int2*)(qbase + (size_t)(rt*64 + w*16 + lrow) * 64 + ks*32 + lko));
  const float qkScale = (g[3] + EPS_) * (g[4] + EPS_) * (1.0f / 16129.0f) * SCALE_;
  float m = -3.0e38f, den = 0.f;
  const int srow = tid >> 2, sc = tid & 3;
  const int sx = (srow & 7) << 4;
  int4 kraw = *(const int4*)(kbase + (size_t)srow * 64 + sc * 16);
  for (int t = 0; t < 16; ++t) {
    __syncthreads();
    {
      int4 lo, hi; expand16(kraw, lo, hi);
      int bb = srow * 128 + sc * 32;
      *(int4*)((char*)Ks + ( bb       ^ sx)) = lo;
      *(int4*)((char*)Ks + ((bb + 16) ^ sx)) = hi;
    }
    if (t < 15)
      kraw = *(const int4*)(kbase + (size_t)(t + 1) * 4096 + (size_t)srow * 64 + sc * 16);
    __syncthreads();
    f32x4 acc[4] = {};
    #pragma unroll
    for (int ks = 0; ks < 2; ++ks)
      #pragma unroll
      for (int j = 0; j < 4; ++j) {
        int row = j * 16 + lrow;
        bf16x8 kf = *(const bf16x8*)((const char*)Ks + ((row * 128 + (ks*32 + lko) * 2) ^ ((row & 7) << 4)));
        acc[j] = __builtin_amdgcn_mfma_f32_16x16x32_bf16(kf, qf[ks], acc[j], 0, 0, 0);
      }
    float mnew = m;
    #pragma unroll
    for (int j = 0; j < 4; ++j)
      #pragma unroll
      for (int rr = 0; rr < 4; ++rr)
        mnew = fmaxf(mnew, acc[j][rr] * qkScale);
    float d = den * __expf(m - mnew);
    #pragma unroll
    for (int j = 0; j < 4; ++j)
      #pragma unroll
      for (int rr = 0; rr < 4; ++rr)
        d += __expf(acc[j][rr] * qkScale - mnew);
    den = d; m = mnew;
  }
  // merge the 4 hi-lane k-partitions
  #pragma unroll
  for (int off = 16; off <= 32; off <<= 1) {
    float mo = __shfl_xor(m, off);
    float doo = __shfl_xor(den, off);
    float mg = fmaxf(m, mo);
    den = den * __expf(m - mg) + doo * __expf(mo - mg);
    m = mg;
  }
  if (lane < 16) {
    size_t rg = (size_t)bh * 1024 + rt * 64 + w * 16 + lane;
    rowmax[rg] = m;
    denomv[rg] = den;
  }
  // one atomic per block
  float bm = den;
  #pragma unroll
  for (int off = 1; off < 16; off <<= 1) bm = fminf(bm, __shfl_xor(bm, off));
  if (lane == 0) red[w] = bm;
  __syncthreads();
  if (tid == 0)
    atomicMin(gminden, __float_as_uint(fminf(fminf(red[0], red[1]), fminf(red[2], red[3]))));
}

// ---------------- attention pass 2 (swapped-QK MFMA, 64-row blocks, prefetch) ----------------
__global__ __launch_bounds__(256) void k_attn_pv_mfma(
    const int8_t* __restrict__ qi8, const int8_t* __restrict__ ki8, const int8_t* __restrict__ vti8,
    const float* __restrict__ g, const unsigned int* __restrict__ gminden,
    const float* __restrict__ rowmax, const float* __restrict__ denomv,
    float* __restrict__ aof, float* __restrict__ gamax) {
  __shared__ unsigned short Ks[64 * 64];
  __shared__ unsigned short Vs[64 * 64];
  __shared__ unsigned short Ps[64 * 64];
  __shared__ float red[4];
  const int bh = blockIdx.x >> 4, rt = blockIdx.x & 15;
  const int b = bh / 12, h = bh % 12;
  const int tid = threadIdx.x, w = tid >> 6, lane = tid & 63;
  const int lrow = lane & 15, lko = (lane >> 4) << 3;
  const int8_t* qbase = qi8 + (size_t)bh * 65536;
  const int8_t* kbase = ki8 + (size_t)bh * 65536;
  const int8_t* vbase = vti8 + (size_t)bh * 65536;
  bf16x8 qf[2];
  #pragma unroll
  for (int ks = 0; ks < 2; ++ks)
    qf[ks] = expand8(*(const int2*)(qbase + (size_t)(rt*64 + w*16 + lrow) * 64 + ks*32 + lko));
  const float qkScale = (g[3] + EPS_) * (g[4] + EPS_) * (1.0f / 16129.0f) * SCALE_;
  const float minden = __uint_as_float(*gminden);
  const float sa = 1.0f / minden + EPS_;
  const float invSa = 1.0f / sa;
  const float sv = g[5] + EPS_;
  const float pvScale = sa * sv * (1.0f / 32385.0f);   // /(255*127)
  const float rm  = rowmax[(size_t)bh * 1024 + rt * 64 + w * 16 + lrow];
  const float ivd = 1.0f / denomv[(size_t)bh * 1024 + rt * 64 + w * 16 + lrow];
  f32x4 accO[4] = {};
  const int srow = tid >> 2, sc = tid & 3;
  const int sx = (srow & 7) << 4;
  int4 kraw = *(const int4*)(kbase + (size_t)srow * 64 + sc * 16);
  int4 vraw = *(const int4*)(vbase + (size_t)srow * 1024 + sc * 16);
  for (int t = 0; t < 16; ++t) {
    __syncthreads();
    {
      int4 lo, hi;
      int bb = srow * 128 + sc * 32;
      expand16(kraw, lo, hi);
      *(int4*)((char*)Ks + ( bb       ^ sx)) = lo;
      *(int4*)((char*)Ks + ((bb + 16) ^ sx)) = hi;
      expand16(vraw, lo, hi);
      *(int4*)((char*)Vs + ( bb       ^ sx)) = lo;
      *(int4*)((char*)Vs + ((bb + 16) ^ sx)) = hi;
    }
    if (t < 15) {
      kraw = *(const int4*)(kbase + (size_t)(t + 1) * 4096 + (size_t)srow * 64 + sc * 16);
      vraw = *(const int4*)(vbase + (size_t)srow * 1024 + (t + 1) * 64 + sc * 16);
    }
    __syncthreads();
    f32x4 acc[4] = {};
    #pragma unroll
    for (int ks = 0; ks < 2; ++ks)
      #pragma unroll
      for (int j = 0; j < 4; ++j) {
        int row = j * 16 + lrow;
        bf16x8 kf = *(const bf16x8*)((const char*)Ks + ((row * 128 + (ks*32 + lko) * 2) ^ ((row & 7) << 4)));
        acc[j] = __builtin_amdgcn_mfma_f32_16x16x32_bf16(kf, qf[ks], acc[j], 0, 0, 0);
      }
    // softmax -> unsigned 8-bit levels (exact bf16) -> Ps (in-lane)
    const int q = w * 16 + lrow;
    const int kb = (lane >> 4) << 2;
    #pragma unroll
    for (int j = 0; j < 4; ++j) {
      float a0 = rintf(fminf(__expf(acc[j][0] * qkScale - rm) * ivd * invSa, 1.0f) * 255.0f);
      float a1 = rintf(fminf(__expf(acc[j][1] * qkScale - rm) * ivd * invSa, 1.0f) * 255.0f);
      float a2 = rintf(fminf(__expf(acc[j][2] * qkScale - rm) * ivd * invSa, 1.0f) * 255.0f);
      float a3 = rintf(fminf(__expf(acc[j][3] * qkScale - rm) * ivd * invSa, 1.0f) * 255.0f);
      uint2 pk;
      pk.x = (__float_as_uint(a0) >> 16) | ((__float_as_uint(a1) >> 16) << 16);
      pk.y = (__float_as_uint(a2) >> 16) | ((__float_as_uint(a3) >> 16) << 16);
      int byteoff = (q * 128 + (j * 16 + kb) * 2) ^ ((q & 7) << 4);
      *(uint2*)((char*)Ps + byteoff) = pk;
    }
    // O += P @ V
    #pragma unroll
    for (int ks = 0; ks < 2; ++ks) {
      bf16x8 pf = *(const bf16x8*)((const char*)Ps + ((q * 128 + (ks*32 + lko) * 2) ^ ((q & 7) << 4)));
      #pragma unroll
      for (int j = 0; j < 4; ++j) {
        int row = j * 16 + lrow;
        bf16x8 vf = *(const bf16x8*)((const char*)Vs + ((row * 128 + (ks*32 + lko) * 2) ^ ((row & 7) << 4)));
        accO[j] = __builtin_amdgcn_mfma_f32_16x16x32_bf16(pf, vf, accO[j], 0, 0, 0);
      }
    }
  }
  float amax = 0.f;
  #pragma unroll
  for (int j = 0; j < 4; ++j) {
    int d = j * 16 + lrow;
    #pragma unroll
    for (int rr = 0; rr < 4; ++rr) {
      int row = rt * 64 + w * 16 + (lane >> 4) * 4 + rr;
      float val = accO[j][rr] * pvScale;
      aof[((size_t)(b * 1024 + row)) * 768 + h * 64 + d] = val;
      amax = fmaxf(amax, fabsf(val));
    }
  }
  #pragma unroll
  for (int off = 1; off < 64; off <<= 1) amax = fmaxf(amax, __shfl_xor(amax, off));
  if (lane == 0) red[w] = amax;
  __syncthreads();
  if (tid == 0)
    atomicMax((unsigned int*)gamax, __float_as_uint(fmaxf(fmaxf(red[0], red[1]), fmaxf(red[2], red[3]))));
}

extern "C" void kernel_launch(void* const* d_in, const int* in_sizes, int n_in,
                              void* d_out, int out_size, void* d_ws, size_t ws_size,
                              hipStream_t stream) {
  const float* x      = (const float*)d_in[0];   // [8,1024,768]
  const float* qkv_w  = (const float*)d_in[1];   // [2304,768]
  const float* qkv_b  = (const float*)d_in[2];   // [2304]
  const float* proj_w = (const float*)d_in[3];   // [768,768]
  const float* proj_b = (const float*)d_in[4];   // [768]
  float* out = (float*)d_out;

  char* w = (char*)d_ws;
  float*          g      = (float*)(w + 0);                 // 8 stats
  float*          rowmax = (float*)(w + 256);               // 393216 B
  float*          denomv = (float*)(w + 393472);            // 393216 B
  int8_t*         qi8    = (int8_t*)(w + 786688);           // 6291456 B
  int8_t*         ki8    = (int8_t*)(w + 7078144);          // 6291456 B
  int8_t*         vT     = (int8_t*)(w + 13369600);         // 6291456 B
  unsigned short* pw     = (unsigned short*)(w + 19661056); // 1179648 B (live to end)
  unsigned short* xq     = (unsigned short*)(w + 20840704); // 12582912 B (dead after GEMM1)
  unsigned short* wq     = (unsigned short*)(w + 33423616); //  3538944 B (dead after GEMM1)
  float*          qkvf   = (float*)(w + 36962560);          // 75497472 B (dead after quant_heads)
  float*          aof    = (float*)(w + 36962560);          // 25165824 B (aliases dead qkvf)
  unsigned short* aobf   = (unsigned short*)(w + 62128384); // 12582912 B (inside qkvf region)

  hipLaunchKernelGGL(k_init, dim3(1), dim3(64), 0, stream, g);

  hipLaunchKernelGGL(k_absmax4, dim3(512), dim3(256), 0, stream, (const float4*)x,      6291456u / 4, &g[0]);
  hipLaunchKernelGGL(k_absmax4, dim3(256), dim3(256), 0, stream, (const float4*)qkv_w,  1769472u / 4, &g[1]);
  hipLaunchKernelGGL(k_absmax4, dim3(128), dim3(256), 0, stream, (const float4*)proj_w,  589824u / 4, &g[2]);

  hipLaunchKernelGGL(k_quant_bf16, dim3(2048), dim3(256), 0, stream, x,      6291456u, &g[0], xq);
  hipLaunchKernelGGL(k_quant_bf16, dim3(1024), dim3(256), 0, stream, qkv_w,  1769472u, &g[1], wq);
  hipLaunchKernelGGL(k_quant_bf16, dim3(512),  dim3(256), 0, stream, proj_w,  589824u, &g[2], pw);

  // qkv = xq @ wq^T * (sx*sw/127^2) + b -> f32 [8192][2304]; also per-part |max| -> g[3..5]
  hipLaunchKernelGGL(k_gemm, dim3(TC_ / 128, M_ / 128), dim3(256), 0, stream,
                     xq, wq, qkv_b, qkvf, M_, TC_, C_, &g[0], &g[1], &g[3], 768);

  hipLaunchKernelGGL(k_quant_heads, dim3(2048), dim3(256), 0, stream, qkvf, g, qi8, ki8, vT);

  hipLaunchKernelGGL(k_attn_stats_mfma, dim3(1536), dim3(256), 0, stream,
                     qi8, ki8, g, rowmax, denomv, (unsigned int*)&g[6]);
  hipLaunchKernelGGL(k_attn_pv_mfma, dim3(1536), dim3(256), 0, stream,
                     qi8, ki8, vT, g, (const unsigned int*)&g[6], rowmax, denomv, aof, &g[7]);

  hipLaunchKernelGGL(k_quant_bf16, dim3(2048), dim3(256), 0, stream, aof, 6291456u, &g[7], aobf);

  // out = aobf @ pw^T * (sao*spw/127^2) + proj_b -> d_out f32 [8192][768]
  hipLaunchKernelGGL(k_gemm, dim3(C_ / 128, M_ / 128), dim3(256), 0, stream,
                     aobf, pw, proj_b, out, M_, C_, C_, &g[7], &g[2], (float*)nullptr, 1);

  (void)in_sizes; (void)n_in; (void)out_size; (void)ws_size;
}

// Round 5
// 289.875 us; speedup vs baseline: 4.8241x; 1.0505x over previous
//
#include <hip/hip_runtime.h>
#include <hip/hip_bf16.h>
#include <cstdint>
#include <cstddef>

// Problem constants
#define B_    8
#define SEQ_  1024
#define C_    768
#define H_    12
#define D_    64
#define TC_   2304          // 3*C
#define M_    8192          // B*SEQ
#define EPS_  1e-7f
#define SCALE_ 0.036084391824351615f  // 768^-0.5

typedef __attribute__((ext_vector_type(8))) short bf16x8;
typedef __attribute__((ext_vector_type(4))) float f32x4;

#define GLOAD_LDS16(gsrc, ldst) \
  __builtin_amdgcn_global_load_lds((const __attribute__((address_space(1))) unsigned int*)(gsrc), \
                                   (__attribute__((address_space(3))) unsigned int*)(ldst), 16, 0, 0)

// int8 -> bf16 integer levels (exact for |v|<=255)
__device__ __forceinline__ bf16x8 expand8(int2 raw) {
  union { int2 v; signed char c[8]; } u; u.v = raw;
  bf16x8 r;
  #pragma unroll
  for (int j = 0; j < 8; ++j) {
    float f = (float)(int)u.c[j];
    r[j] = (short)(__float_as_uint(f) >> 16);
  }
  return r;
}
__device__ __forceinline__ void expand16(int4 raw, int4& lo, int4& hi) {
  union { int4 v; signed char c[16]; } u; u.v = raw;
  unsigned short s[16];
  #pragma unroll
  for (int j = 0; j < 16; ++j) {
    float f = (float)(int)u.c[j];
    s[j] = (unsigned short)(__float_as_uint(f) >> 16);
  }
  lo = *(const int4*)&s[0]; hi = *(const int4*)&s[8];
}

// ---------------- init global stats ----------------
// g[0]=max|x| g[1]=max|qkv_w| g[2]=max|proj_w| g[3]=max|q| g[4]=max|k| g[5]=max|v|
// g[6]=min softmax-denom  g[7]=max|attn_out|
__global__ void k_init(float* g) {
  if (threadIdx.x == 0) {
    g[0]=0.f; g[1]=0.f; g[2]=0.f; g[3]=0.f; g[4]=0.f; g[5]=0.f;
    g[6]=3.402823466e+38f;
    g[7]=0.f;
  }
}

// ---------------- abs-max reduction (float4), 1 atomic per block ----------------
__global__ __launch_bounds__(256) void k_absmax4(const float4* __restrict__ p, unsigned n4, float* gout) {
  __shared__ float red[4];
  float m = 0.f;
  for (unsigned i = blockIdx.x * blockDim.x + threadIdx.x; i < n4; i += gridDim.x * blockDim.x) {
    float4 v = p[i];
    m = fmaxf(m, fmaxf(fmaxf(fabsf(v.x), fabsf(v.y)), fmaxf(fabsf(v.z), fabsf(v.w))));
  }
  #pragma unroll
  for (int off = 32; off; off >>= 1) m = fmaxf(m, __shfl_xor(m, off));
  if ((threadIdx.x & 63) == 0) red[threadIdx.x >> 6] = m;
  __syncthreads();
  if (threadIdx.x == 0) {
    m = fmaxf(fmaxf(red[0], red[1]), fmaxf(red[2], red[3]));
    atomicMax((unsigned int*)gout, __float_as_uint(m));
  }
}

// ---------------- signed fake-quant -> bf16 integer levels ----------------
__global__ __launch_bounds__(256) void k_quant_bf16(const float* __restrict__ in, unsigned n,
                                                    const float* __restrict__ gmax,
                                                    unsigned short* __restrict__ out) {
  const float s = *gmax + EPS_;
  for (unsigned i = blockIdx.x * blockDim.x + threadIdx.x; i < n; i += gridDim.x * blockDim.x) {
    float v = in[i];
    float y = fminf(fabsf(v) / s, 1.0f);
    float q = rintf(y * 127.0f);          // half-to-even, matches jnp.round
    if (v < 0.f) q = -q;
    out[i] = (unsigned short)(__float_as_uint(q) >> 16);  // exact: integer <= 127
  }
}

// ---------------- bf16-integer MFMA GEMM (m97 structure + pre-swizzled-source T2) ----------------
// A: [Mn][Kn], Bt: [Nn][Kn] bf16 int-levels; global_load_lds w16 with permuted global col;
// LDS physically holds logical ^ ((row&7)<<4); reads apply the same XOR. XCD swizzle.
__global__ __launch_bounds__(256) void k_gemm(const unsigned short* __restrict__ A,
                                              const unsigned short* __restrict__ Bt,
                                              const float* __restrict__ bias,
                                              float* __restrict__ C,
                                              int Mn, int Nn, int Kn,
                                              const float* __restrict__ sA, const float* __restrict__ sB,
                                              float* pmax, int partDiv) {
  __shared__ unsigned short As[128 * 64];
  __shared__ unsigned short Bs[128 * 64];
  const int tid = threadIdx.x;
  // bijective XCD swizzle (nwg % 8 == 0 for both GEMMs)
  int flat = blockIdx.y * gridDim.x + blockIdx.x;
  int chunk = (gridDim.x * gridDim.y) >> 3;
  int nf = (flat & 7) * chunk + (flat >> 3);
  const int n0 = (nf % gridDim.x) * 128, m0 = (nf / gridDim.x) * 128;
  const int wid = tid >> 6, lane = tid & 63;
  const int wr = wid >> 1, wc = wid & 1;            // 2x2 waves -> 64x64 each
  const int lrow = lane & 15;
  const int lko = (lane >> 4) << 3;                 // k offset 0/8/16/24
  f32x4 acc[4][4] = {};
  // staging: wave w, call c: lane l fills LDS row w*32+c*8+(l>>3), phys 16B-slot (l&7).
  // source col permuted so that LDS phys = logical ^ ((row&7)<<4):
  const int gr = (wid << 5) + (lane >> 3);
  const int gc = (((lane & 7) ^ ((lane >> 3) & 7)) << 3);   // pre-swizzled global ushort col
  const unsigned short* ga = A  + (size_t)(m0 + gr) * Kn + gc;
  const unsigned short* gb = Bt + (size_t)(n0 + gr) * Kn + gc;
  for (int k0 = 0; k0 < Kn; k0 += 64) {
    #pragma unroll
    for (int c = 0; c < 4; ++c) {
      GLOAD_LDS16(ga + (size_t)(c * 8) * Kn + k0, &As[(wid * 32 + c * 8) * 64]);
      GLOAD_LDS16(gb + (size_t)(c * 8) * Kn + k0, &Bs[(wid * 32 + c * 8) * 64]);
    }
    asm volatile("s_waitcnt vmcnt(0)" ::: "memory");
    __syncthreads();
    #pragma unroll
    for (int kk = 0; kk < 64; kk += 32) {
      bf16x8 af[4], bfr[4];
      #pragma unroll
      for (int i = 0; i < 4; ++i) {
        int row = wr * 64 + i * 16 + lrow;
        af[i] = *(const bf16x8*)((const char*)As + ((row * 128 + (kk + lko) * 2) ^ ((row & 7) << 4)));
      }
      #pragma unroll
      for (int j = 0; j < 4; ++j) {
        int row = wc * 64 + j * 16 + lrow;
        bfr[j] = *(const bf16x8*)((const char*)Bs + ((row * 128 + (kk + lko) * 2) ^ ((row & 7) << 4)));
      }
      #pragma unroll
      for (int i = 0; i < 4; ++i)
        #pragma unroll
        for (int j = 0; j < 4; ++j)
          acc[i][j] = __builtin_amdgcn_mfma_f32_16x16x32_bf16(af[i], bfr[j], acc[i][j], 0, 0, 0);
    }
    __syncthreads();
  }
  const float alpha = (sA[0] + EPS_) * (sB[0] + EPS_) * (1.0f / 16129.0f);
  const int orow = (lane >> 4) << 2;
  float amax = 0.f;
  #pragma unroll
  for (int i = 0; i < 4; ++i) {
    #pragma unroll
    for (int j = 0; j < 4; ++j) {
      int col = n0 + wc * 64 + j * 16 + lrow;
      float bc = bias[col];
      #pragma unroll
      for (int rr = 0; rr < 4; ++rr) {
        int row = m0 + wr * 64 + i * 16 + orow + rr;
        float val = acc[i][j][rr] * alpha + bc;
        C[(size_t)row * Nn + col] = val;
        amax = fmaxf(amax, fabsf(val));
      }
    }
  }
  if (pmax) {
    #pragma unroll
    for (int off = 32; off; off >>= 1) amax = fmaxf(amax, __shfl_xor(amax, off));
    if (lane == 0) atomicMax((unsigned int*)&pmax[n0 / partDiv], __float_as_uint(amax));
  }
}

// ---------------- quantize qkv into int8 head-layouts ----------------
__global__ __launch_bounds__(256) void k_quant_heads(const float* __restrict__ qkvf, const float* __restrict__ g,
                                                     int8_t* __restrict__ qo, int8_t* __restrict__ ko,
                                                     int8_t* __restrict__ vT) {
  const unsigned total = (unsigned)M_ * TC_;
  const float s0 = g[3] + EPS_, s1 = g[4] + EPS_, s2 = g[5] + EPS_;
  for (unsigned i = blockIdx.x * blockDim.x + threadIdx.x; i < total; i += gridDim.x * blockDim.x) {
    unsigned m = i / 2304u, o = i % 2304u;
    unsigned part = o / 768u, c = o % 768u;
    unsigned h = c >> 6, d = c & 63;
    unsigned b = m >> 10, n = m & 1023;
    float s = (part == 0) ? s0 : (part == 1) ? s1 : s2;
    float v = qkvf[i];
    float y = fminf(fabsf(v) / s, 1.0f);
    int q = (int)rintf(y * 127.0f);
    if (v < 0.f) q = -q;
    unsigned bh = b * 12 + h;
    if (part == 0)      qo[((size_t)bh * 1024 + n) * 64 + d] = (int8_t)q;
    else if (part == 1) ko[((size_t)bh * 1024 + n) * 64 + d] = (int8_t)q;
    else                vT[((size_t)bh * 64 + d) * 1024 + n] = (int8_t)q;
  }
}

// ---------------- attention pass 1 (swapped-QK MFMA, 64-row blocks, prefetch) ----------------
// grid: 1536 = bh(96) x rt(16); 4 waves x 16 q-rows.
__global__ __launch_bounds__(256) void k_attn_stats_mfma(
    const int8_t* __restrict__ qi8, const int8_t* __restrict__ ki8,
    const float* __restrict__ g, float* __restrict__ rowmax, float* __restrict__ denomv,
    unsigned int* __restrict__ gminden) {
  __shared__ unsigned short Ks[64 * 64];
  __shared__ float red[4];
  const int bh = blockIdx.x >> 4, rt = blockIdx.x & 15;
  const int tid = threadIdx.x, w = tid >> 6, lane = tid & 63;
  const int lrow = lane & 15, lko = (lane >> 4) << 3;
  const int8_t* qbase = qi8 + (size_t)bh * 65536;
  const int8_t* kbase = ki8 + (size_t)bh * 65536;
  bf16x8 qf[2];
  #pragma unroll
  for (int ks = 0; ks < 2; ++ks)
    qf[ks] = expand8(*(const int2*)(qbase + (size_t)(rt*64 + w*16 + lrow) * 64 + ks*32 + lko));
  const float qkScale = (g[3] + EPS_) * (g[4] + EPS_) * (1.0f / 16129.0f) * SCALE_;
  float m = -3.0e38f, den = 0.f;
  const int srow = tid >> 2, sc = tid & 3;
  const int sx = (srow & 7) << 4;
  int4 kraw = *(const int4*)(kbase + (size_t)srow * 64 + sc * 16);
  for (int t = 0; t < 16; ++t) {
    __syncthreads();
    {
      int4 lo, hi; expand16(kraw, lo, hi);
      int bb = srow * 128 + sc * 32;
      *(int4*)((char*)Ks + ( bb       ^ sx)) = lo;
      *(int4*)((char*)Ks + ((bb + 16) ^ sx)) = hi;
    }
    if (t < 15)
      kraw = *(const int4*)(kbase + (size_t)(t + 1) * 4096 + (size_t)srow * 64 + sc * 16);
    __syncthreads();
    f32x4 acc[4] = {};
    #pragma unroll
    for (int ks = 0; ks < 2; ++ks)
      #pragma unroll
      for (int j = 0; j < 4; ++j) {
        int row = j * 16 + lrow;
        bf16x8 kf = *(const bf16x8*)((const char*)Ks + ((row * 128 + (ks*32 + lko) * 2) ^ ((row & 7) << 4)));
        acc[j] = __builtin_amdgcn_mfma_f32_16x16x32_bf16(kf, qf[ks], acc[j], 0, 0, 0);
      }
    float mnew = m;
    #pragma unroll
    for (int j = 0; j < 4; ++j)
      #pragma unroll
      for (int rr = 0; rr < 4; ++rr)
        mnew = fmaxf(mnew, acc[j][rr] * qkScale);
    float d = den * __expf(m - mnew);
    #pragma unroll
    for (int j = 0; j < 4; ++j)
      #pragma unroll
      for (int rr = 0; rr < 4; ++rr)
        d += __expf(acc[j][rr] * qkScale - mnew);
    den = d; m = mnew;
  }
  // merge the 4 hi-lane k-partitions
  #pragma unroll
  for (int off = 16; off <= 32; off <<= 1) {
    float mo = __shfl_xor(m, off);
    float doo = __shfl_xor(den, off);
    float mg = fmaxf(m, mo);
    den = den * __expf(m - mg) + doo * __expf(mo - mg);
    m = mg;
  }
  if (lane < 16) {
    size_t rg = (size_t)bh * 1024 + rt * 64 + w * 16 + lane;
    rowmax[rg] = m;
    denomv[rg] = den;
  }
  // one atomic per block
  float bm = den;
  #pragma unroll
  for (int off = 1; off < 16; off <<= 1) bm = fminf(bm, __shfl_xor(bm, off));
  if (lane == 0) red[w] = bm;
  __syncthreads();
  if (tid == 0)
    atomicMin(gminden, __float_as_uint(fminf(fminf(red[0], red[1]), fminf(red[2], red[3]))));
}

// ---------------- attention pass 2 (swapped-QK MFMA, 64-row blocks, prefetch) ----------------
__global__ __launch_bounds__(256) void k_attn_pv_mfma(
    const int8_t* __restrict__ qi8, const int8_t* __restrict__ ki8, const int8_t* __restrict__ vti8,
    const float* __restrict__ g, const unsigned int* __restrict__ gminden,
    const float* __restrict__ rowmax, const float* __restrict__ denomv,
    float* __restrict__ aof, float* __restrict__ gamax) {
  __shared__ unsigned short Ks[64 * 64];
  __shared__ unsigned short Vs[64 * 64];
  __shared__ unsigned short Ps[64 * 64];
  __shared__ float red[4];
  const int bh = blockIdx.x >> 4, rt = blockIdx.x & 15;
  const int b = bh / 12, h = bh % 12;
  const int tid = threadIdx.x, w = tid >> 6, lane = tid & 63;
  const int lrow = lane & 15, lko = (lane >> 4) << 3;
  const int8_t* qbase = qi8 + (size_t)bh * 65536;
  const int8_t* kbase = ki8 + (size_t)bh * 65536;
  const int8_t* vbase = vti8 + (size_t)bh * 65536;
  bf16x8 qf[2];
  #pragma unroll
  for (int ks = 0; ks < 2; ++ks)
    qf[ks] = expand8(*(const int2*)(qbase + (size_t)(rt*64 + w*16 + lrow) * 64 + ks*32 + lko));
  const float qkScale = (g[3] + EPS_) * (g[4] + EPS_) * (1.0f / 16129.0f) * SCALE_;
  const float minden = __uint_as_float(*gminden);
  const float sa = 1.0f / minden + EPS_;
  const float invSa = 1.0f / sa;
  const float sv = g[5] + EPS_;
  const float pvScale = sa * sv * (1.0f / 32385.0f);   // /(255*127)
  const float rm  = rowmax[(size_t)bh * 1024 + rt * 64 + w * 16 + lrow];
  const float ivd = 1.0f / denomv[(size_t)bh * 1024 + rt * 64 + w * 16 + lrow];
  f32x4 accO[4] = {};
  const int srow = tid >> 2, sc = tid & 3;
  const int sx = (srow & 7) << 4;
  int4 kraw = *(const int4*)(kbase + (size_t)srow * 64 + sc * 16);
  int4 vraw = *(const int4*)(vbase + (size_t)srow * 1024 + sc * 16);
  for (int t = 0; t < 16; ++t) {
    __syncthreads();
    {
      int4 lo, hi;
      int bb = srow * 128 + sc * 32;
      expand16(kraw, lo, hi);
      *(int4*)((char*)Ks + ( bb       ^ sx)) = lo;
      *(int4*)((char*)Ks + ((bb + 16) ^ sx)) = hi;
      expand16(vraw, lo, hi);
      *(int4*)((char*)Vs + ( bb       ^ sx)) = lo;
      *(int4*)((char*)Vs + ((bb + 16) ^ sx)) = hi;
    }
    if (t < 15) {
      kraw = *(const int4*)(kbase + (size_t)(t + 1) * 4096 + (size_t)srow * 64 + sc * 16);
      vraw = *(const int4*)(vbase + (size_t)srow * 1024 + (t + 1) * 64 + sc * 16);
    }
    __syncthreads();
    f32x4 acc[4] = {};
    #pragma unroll
    for (int ks = 0; ks < 2; ++ks)
      #pragma unroll
      for (int j = 0; j < 4; ++j) {
        int row = j * 16 + lrow;
        bf16x8 kf = *(const bf16x8*)((const char*)Ks + ((row * 128 + (ks*32 + lko) * 2) ^ ((row & 7) << 4)));
        acc[j] = __builtin_amdgcn_mfma_f32_16x16x32_bf16(kf, qf[ks], acc[j], 0, 0, 0);
      }
    // softmax -> unsigned 8-bit levels (exact bf16) -> Ps (in-lane)
    const int q = w * 16 + lrow;
    const int kb = (lane >> 4) << 2;
    #pragma unroll
    for (int j = 0; j < 4; ++j) {
      float a0 = rintf(fminf(__expf(acc[j][0] * qkScale - rm) * ivd * invSa, 1.0f) * 255.0f);
      float a1 = rintf(fminf(__expf(acc[j][1] * qkScale - rm) * ivd * invSa, 1.0f) * 255.0f);
      float a2 = rintf(fminf(__expf(acc[j][2] * qkScale - rm) * ivd * invSa, 1.0f) * 255.0f);
      float a3 = rintf(fminf(__expf(acc[j][3] * qkScale - rm) * ivd * invSa, 1.0f) * 255.0f);
      uint2 pk;
      pk.x = (__float_as_uint(a0) >> 16) | ((__float_as_uint(a1) >> 16) << 16);
      pk.y = (__float_as_uint(a2) >> 16) | ((__float_as_uint(a3) >> 16) << 16);
      int byteoff = (q * 128 + (j * 16 + kb) * 2) ^ ((q & 7) << 4);
      *(uint2*)((char*)Ps + byteoff) = pk;
    }
    // O += P @ V
    #pragma unroll
    for (int ks = 0; ks < 2; ++ks) {
      bf16x8 pf = *(const bf16x8*)((const char*)Ps + ((q * 128 + (ks*32 + lko) * 2) ^ ((q & 7) << 4)));
      #pragma unroll
      for (int j = 0; j < 4; ++j) {
        int row = j * 16 + lrow;
        bf16x8 vf = *(const bf16x8*)((const char*)Vs + ((row * 128 + (ks*32 + lko) * 2) ^ ((row & 7) << 4)));
        accO[j] = __builtin_amdgcn_mfma_f32_16x16x32_bf16(pf, vf, accO[j], 0, 0, 0);
      }
    }
  }
  float amax = 0.f;
  #pragma unroll
  for (int j = 0; j < 4; ++j) {
    int d = j * 16 + lrow;
    #pragma unroll
    for (int rr = 0; rr < 4; ++rr) {
      int row = rt * 64 + w * 16 + (lane >> 4) * 4 + rr;
      float val = accO[j][rr] * pvScale;
      aof[((size_t)(b * 1024 + row)) * 768 + h * 64 + d] = val;
      amax = fmaxf(amax, fabsf(val));
    }
  }
  #pragma unroll
  for (int off = 1; off < 64; off <<= 1) amax = fmaxf(amax, __shfl_xor(amax, off));
  if (lane == 0) red[w] = amax;
  __syncthreads();
  if (tid == 0)
    atomicMax((unsigned int*)gamax, __float_as_uint(fmaxf(fmaxf(red[0], red[1]), fmaxf(red[2], red[3]))));
}

extern "C" void kernel_launch(void* const* d_in, const int* in_sizes, int n_in,
                              void* d_out, int out_size, void* d_ws, size_t ws_size,
                              hipStream_t stream) {
  const float* x      = (const float*)d_in[0];   // [8,1024,768]
  const float* qkv_w  = (const float*)d_in[1];   // [2304,768]
  const float* qkv_b  = (const float*)d_in[2];   // [2304]
  const float* proj_w = (const float*)d_in[3];   // [768,768]
  const float* proj_b = (const float*)d_in[4];   // [768]
  float* out = (float*)d_out;

  char* w = (char*)d_ws;
  float*          g      = (float*)(w + 0);                 // 8 stats
  float*          rowmax = (float*)(w + 256);               // 393216 B
  float*          denomv = (float*)(w + 393472);            // 393216 B
  int8_t*         qi8    = (int8_t*)(w + 786688);           // 6291456 B
  int8_t*         ki8    = (int8_t*)(w + 7078144);          // 6291456 B
  int8_t*         vT     = (int8_t*)(w + 13369600);         // 6291456 B
  unsigned short* pw     = (unsigned short*)(w + 19661056); // 1179648 B (live to end)
  unsigned short* xq     = (unsigned short*)(w + 20840704); // 12582912 B (dead after GEMM1)
  unsigned short* wq     = (unsigned short*)(w + 33423616); //  3538944 B (dead after GEMM1)
  float*          qkvf   = (float*)(w + 36962560);          // 75497472 B (dead after quant_heads)
  float*          aof    = (float*)(w + 36962560);          // 25165824 B (aliases dead qkvf)
  unsigned short* aobf   = (unsigned short*)(w + 62128384); // 12582912 B (inside qkvf region)

  hipLaunchKernelGGL(k_init, dim3(1), dim3(64), 0, stream, g);

  hipLaunchKernelGGL(k_absmax4, dim3(512), dim3(256), 0, stream, (const float4*)x,      6291456u / 4, &g[0]);
  hipLaunchKernelGGL(k_absmax4, dim3(256), dim3(256), 0, stream, (const float4*)qkv_w,  1769472u / 4, &g[1]);
  hipLaunchKernelGGL(k_absmax4, dim3(128), dim3(256), 0, stream, (const float4*)proj_w,  589824u / 4, &g[2]);

  hipLaunchKernelGGL(k_quant_bf16, dim3(2048), dim3(256), 0, stream, x,      6291456u, &g[0], xq);
  hipLaunchKernelGGL(k_quant_bf16, dim3(1024), dim3(256), 0, stream, qkv_w,  1769472u, &g[1], wq);
  hipLaunchKernelGGL(k_quant_bf16, dim3(512),  dim3(256), 0, stream, proj_w,  589824u, &g[2], pw);

  // qkv = xq @ wq^T * (sx*sw/127^2) + b -> f32 [8192][2304]; also per-part |max| -> g[3..5]
  hipLaunchKernelGGL(k_gemm, dim3(TC_ / 128, M_ / 128), dim3(256), 0, stream,
                     xq, wq, qkv_b, qkvf, M_, TC_, C_, &g[0], &g[1], &g[3], 768);

  hipLaunchKernelGGL(k_quant_heads, dim3(2048), dim3(256), 0, stream, qkvf, g, qi8, ki8, vT);

  hipLaunchKernelGGL(k_attn_stats_mfma, dim3(1536), dim3(256), 0, stream,
                     qi8, ki8, g, rowmax, denomv, (unsigned int*)&g[6]);
  hipLaunchKernelGGL(k_attn_pv_mfma, dim3(1536), dim3(256), 0, stream,
                     qi8, ki8, vT, g, (const unsigned int*)&g[6], rowmax, denomv, aof, &g[7]);

  hipLaunchKernelGGL(k_quant_bf16, dim3(2048), dim3(256), 0, stream, aof, 6291456u, &g[7], aobf);

  // out = aobf @ pw^T * (sao*spw/127^2) + proj_b -> d_out f32 [8192][768]
  hipLaunchKernelGGL(k_gemm, dim3(C_ / 128, M_ / 128), dim3(256), 0, stream,
                     aobf, pw, proj_b, out, M_, C_, C_, &g[7], &g[2], (float*)nullptr, 1);

  (void)in_sizes; (void)n_in; (void)out_size; (void)ws_size;
}

// Round 6
// 277.106 us; speedup vs baseline: 5.0464x; 1.0461x over previous
//
#include <hip/hip_runtime.h>
#include <hip/hip_bf16.h>
#include <cstdint>
#include <cstddef>

// Problem constants
#define B_    8
#define SEQ_  1024
#define C_    768
#define H_    12
#define D_    64
#define TC_   2304          // 3*C
#define M_    8192          // B*SEQ
#define EPS_  1e-7f
#define SCALE_ 0.036084391824351615f  // 768^-0.5

typedef __attribute__((ext_vector_type(8))) short bf16x8;
typedef __attribute__((ext_vector_type(4))) float f32x4;

#define GLOAD_LDS16(gsrc, ldst) \
  __builtin_amdgcn_global_load_lds((const __attribute__((address_space(1))) unsigned int*)(gsrc), \
                                   (__attribute__((address_space(3))) unsigned int*)(ldst), 16, 0, 0)

// int8 -> bf16 integer levels (exact for |v|<=255)
__device__ __forceinline__ bf16x8 expand8(int2 raw) {
  union { int2 v; signed char c[8]; } u; u.v = raw;
  bf16x8 r;
  #pragma unroll
  for (int j = 0; j < 8; ++j) {
    float f = (float)(int)u.c[j];
    r[j] = (short)(__float_as_uint(f) >> 16);
  }
  return r;
}
__device__ __forceinline__ void expand16(int4 raw, int4& lo, int4& hi) {
  union { int4 v; signed char c[16]; } u; u.v = raw;
  unsigned short s[16];
  #pragma unroll
  for (int j = 0; j < 16; ++j) {
    float f = (float)(int)u.c[j];
    s[j] = (unsigned short)(__float_as_uint(f) >> 16);
  }
  lo = *(const int4*)&s[0]; hi = *(const int4*)&s[8];
}

// ---------------- init global stats ----------------
// g[0]=max|x| g[1]=max|qkv_w| g[2]=max|proj_w| g[3]=max|q| g[4]=max|k| g[5]=max|v|
// g[6]=min softmax-denom  g[7]=max|attn_out|
__global__ void k_init(float* g) {
  if (threadIdx.x == 0) {
    g[0]=0.f; g[1]=0.f; g[2]=0.f; g[3]=0.f; g[4]=0.f; g[5]=0.f;
    g[6]=3.402823466e+38f;
    g[7]=0.f;
  }
}

// ---------------- fused abs-max over x / qkv_w / proj_w, 1 atomic per block ----------------
__global__ __launch_bounds__(256) void k_absmax_fused(const float4* __restrict__ x,
                                                      const float4* __restrict__ w1,
                                                      const float4* __restrict__ w2,
                                                      float* g) {
  __shared__ float red[4];
  const int blk = blockIdx.x;
  const float4* p; unsigned n4; float* gout; int b0, nb;
  if (blk < 384)      { p = x;  n4 = 1572864u; gout = &g[0]; b0 = 0;   nb = 384; }
  else if (blk < 480) { p = w1; n4 = 442368u;  gout = &g[1]; b0 = 384; nb = 96;  }
  else                { p = w2; n4 = 147456u;  gout = &g[2]; b0 = 480; nb = 48;  }
  float m = 0.f;
  for (unsigned i = (unsigned)(blk - b0) * 256u + threadIdx.x; i < n4; i += (unsigned)nb * 256u) {
    float4 v = p[i];
    m = fmaxf(m, fmaxf(fmaxf(fabsf(v.x), fabsf(v.y)), fmaxf(fabsf(v.z), fabsf(v.w))));
  }
  #pragma unroll
  for (int off = 32; off; off >>= 1) m = fmaxf(m, __shfl_xor(m, off));
  if ((threadIdx.x & 63) == 0) red[threadIdx.x >> 6] = m;
  __syncthreads();
  if (threadIdx.x == 0) {
    m = fmaxf(fmaxf(red[0], red[1]), fmaxf(red[2], red[3]));
    atomicMax((unsigned int*)gout, __float_as_uint(m));
  }
}

// ---------------- signed fake-quant -> bf16 integer levels ----------------
__device__ __forceinline__ void quant_seg(const float* __restrict__ in, unsigned n, float s,
                                          unsigned short* __restrict__ out, unsigned i0, unsigned stride) {
  for (unsigned i = i0; i < n; i += stride) {
    float v = in[i];
    float y = fminf(fabsf(v) / s, 1.0f);
    float q = rintf(y * 127.0f);          // half-to-even, matches jnp.round
    if (v < 0.f) q = -q;
    out[i] = (unsigned short)(__float_as_uint(q) >> 16);  // exact: integer <= 127
  }
}
__global__ __launch_bounds__(256) void k_quant_fused(const float* __restrict__ x,
                                                     const float* __restrict__ w1,
                                                     const float* __restrict__ w2,
                                                     const float* __restrict__ g,
                                                     unsigned short* __restrict__ xq,
                                                     unsigned short* __restrict__ wq,
                                                     unsigned short* __restrict__ pw) {
  const int blk = blockIdx.x;
  if (blk < 1536)      quant_seg(x,  6291456u, g[0] + EPS_, xq, (unsigned)blk * 256u + threadIdx.x, 1536u * 256u);
  else if (blk < 1968) quant_seg(w1, 1769472u, g[1] + EPS_, wq, (unsigned)(blk - 1536) * 256u + threadIdx.x, 432u * 256u);
  else                 quant_seg(w2,  589824u, g[2] + EPS_, pw, (unsigned)(blk - 1968) * 256u + threadIdx.x, 144u * 256u);
}

__global__ __launch_bounds__(256) void k_quant_bf16(const float* __restrict__ in, unsigned n,
                                                    const float* __restrict__ gmax,
                                                    unsigned short* __restrict__ out) {
  const float s = *gmax + EPS_;
  quant_seg(in, n, s, out, blockIdx.x * blockDim.x + threadIdx.x, gridDim.x * blockDim.x);
}

// ---------------- bf16-integer MFMA GEMM (T3 2-phase double-buffered + pre-swizzled-source T2) ----
// A: [Mn][Kn], Bt: [Nn][Kn] bf16 int-levels; global_load_lds w16 with permuted global col;
// LDS physically holds logical ^ ((row&7)<<4); reads apply the same XOR. XCD swizzle.
__global__ __launch_bounds__(256) void k_gemm(const unsigned short* __restrict__ A,
                                              const unsigned short* __restrict__ Bt,
                                              const float* __restrict__ bias,
                                              float* __restrict__ C,
                                              int Mn, int Nn, int Kn,
                                              const float* __restrict__ sA, const float* __restrict__ sB,
                                              float* pmax, int partDiv) {
  __shared__ unsigned short As[2][128 * 64];
  __shared__ unsigned short Bs[2][128 * 64];
  const int tid = threadIdx.x;
  // bijective XCD swizzle (nwg % 8 == 0 for both GEMMs)
  int flat = blockIdx.y * gridDim.x + blockIdx.x;
  int chunk = (gridDim.x * gridDim.y) >> 3;
  int nf = (flat & 7) * chunk + (flat >> 3);
  const int n0 = (nf % gridDim.x) * 128, m0 = (nf / gridDim.x) * 128;
  const int wid = tid >> 6, lane = tid & 63;
  const int wr = wid >> 1, wc = wid & 1;            // 2x2 waves -> 64x64 each
  const int lrow = lane & 15;
  const int lko = (lane >> 4) << 3;                 // k offset 0/8/16/24
  f32x4 acc[4][4] = {};
  // staging: wave w, call c: lane l fills LDS row w*32+c*8+(l>>3), phys 16B-slot (l&7).
  // source col permuted so that LDS phys = logical ^ ((row&7)<<4):
  const int gr = (wid << 5) + (lane >> 3);
  const int gc = (((lane & 7) ^ ((lane >> 3) & 7)) << 3);   // pre-swizzled global ushort col
  const unsigned short* ga = A  + (size_t)(m0 + gr) * Kn + gc;
  const unsigned short* gb = Bt + (size_t)(n0 + gr) * Kn + gc;
  const int nt = Kn >> 6;
  // prologue: stage tile 0 into buffer 0
  #pragma unroll
  for (int c = 0; c < 4; ++c) {
    GLOAD_LDS16(ga + (size_t)(c * 8) * Kn, &As[0][(wid * 32 + c * 8) * 64]);
    GLOAD_LDS16(gb + (size_t)(c * 8) * Kn, &Bs[0][(wid * 32 + c * 8) * 64]);
  }
  asm volatile("s_waitcnt vmcnt(0)" ::: "memory");
  __syncthreads();
  int cur = 0;
  for (int t = 0; t < nt; ++t) {
    // issue next tile's stage BEFORE compute (loads fly under the MFMAs)
    if (t + 1 < nt) {
      #pragma unroll
      for (int c = 0; c < 4; ++c) {
        GLOAD_LDS16(ga + (size_t)(c * 8) * Kn + (t + 1) * 64, &As[cur ^ 1][(wid * 32 + c * 8) * 64]);
        GLOAD_LDS16(gb + (size_t)(c * 8) * Kn + (t + 1) * 64, &Bs[cur ^ 1][(wid * 32 + c * 8) * 64]);
      }
    }
    const char* Ab = (const char*)As[cur];
    const char* Bb = (const char*)Bs[cur];
    #pragma unroll
    for (int kk = 0; kk < 64; kk += 32) {
      bf16x8 af[4], bfr[4];
      #pragma unroll
      for (int i = 0; i < 4; ++i) {
        int row = wr * 64 + i * 16 + lrow;
        af[i] = *(const bf16x8*)(Ab + ((row * 128 + (kk + lko) * 2) ^ ((row & 7) << 4)));
      }
      #pragma unroll
      for (int j = 0; j < 4; ++j) {
        int row = wc * 64 + j * 16 + lrow;
        bfr[j] = *(const bf16x8*)(Bb + ((row * 128 + (kk + lko) * 2) ^ ((row & 7) << 4)));
      }
      #pragma unroll
      for (int i = 0; i < 4; ++i)
        #pragma unroll
        for (int j = 0; j < 4; ++j)
          acc[i][j] = __builtin_amdgcn_mfma_f32_16x16x32_bf16(af[i], bfr[j], acc[i][j], 0, 0, 0);
    }
    // next tile staged + all LDS reads drained (compiler adds lgkmcnt(0) at barrier)
    asm volatile("s_waitcnt vmcnt(0)" ::: "memory");
    __syncthreads();
    cur ^= 1;
  }
  const float alpha = (sA[0] + EPS_) * (sB[0] + EPS_) * (1.0f / 16129.0f);
  const int orow = (lane >> 4) << 2;
  float amax = 0.f;
  #pragma unroll
  for (int i = 0; i < 4; ++i) {
    #pragma unroll
    for (int j = 0; j < 4; ++j) {
      int col = n0 + wc * 64 + j * 16 + lrow;
      float bc = bias[col];
      #pragma unroll
      for (int rr = 0; rr < 4; ++rr) {
        int row = m0 + wr * 64 + i * 16 + orow + rr;
        float val = acc[i][j][rr] * alpha + bc;
        C[(size_t)row * Nn + col] = val;
        amax = fmaxf(amax, fabsf(val));
      }
    }
  }
  if (pmax) {
    #pragma unroll
    for (int off = 32; off; off >>= 1) amax = fmaxf(amax, __shfl_xor(amax, off));
    if (lane == 0) atomicMax((unsigned int*)&pmax[n0 / partDiv], __float_as_uint(amax));
  }
}

// ---------------- quantize qkv into int8 head-layouts ----------------
__global__ __launch_bounds__(256) void k_quant_heads(const float* __restrict__ qkvf, const float* __restrict__ g,
                                                     int8_t* __restrict__ qo, int8_t* __restrict__ ko,
                                                     int8_t* __restrict__ vT) {
  const unsigned total = (unsigned)M_ * TC_;
  const float s0 = g[3] + EPS_, s1 = g[4] + EPS_, s2 = g[5] + EPS_;
  for (unsigned i = blockIdx.x * blockDim.x + threadIdx.x; i < total; i += gridDim.x * blockDim.x) {
    unsigned m = i / 2304u, o = i % 2304u;
    unsigned part = o / 768u, c = o % 768u;
    unsigned h = c >> 6, d = c & 63;
    unsigned b = m >> 10, n = m & 1023;
    float s = (part == 0) ? s0 : (part == 1) ? s1 : s2;
    float v = qkvf[i];
    float y = fminf(fabsf(v) / s, 1.0f);
    int q = (int)rintf(y * 127.0f);
    if (v < 0.f) q = -q;
    unsigned bh = b * 12 + h;
    if (part == 0)      qo[((size_t)bh * 1024 + n) * 64 + d] = (int8_t)q;
    else if (part == 1) ko[((size_t)bh * 1024 + n) * 64 + d] = (int8_t)q;
    else                vT[((size_t)bh * 64 + d) * 1024 + n] = (int8_t)q;
  }
}

// ---------------- attention pass 1 (swapped-QK MFMA, 64-row blocks, prefetch) ----------------
// grid: 1536 = bh(96) x rt(16); 4 waves x 16 q-rows.
__global__ __launch_bounds__(256) void k_attn_stats_mfma(
    const int8_t* __restrict__ qi8, const int8_t* __restrict__ ki8,
    const float* __restrict__ g, float* __restrict__ rowmax, float* __restrict__ denomv,
    unsigned int* __restrict__ gminden) {
  __shared__ unsigned short Ks[64 * 64];
  __shared__ float red[4];
  const int bh = blockIdx.x >> 4, rt = blockIdx.x & 15;
  const int tid = threadIdx.x, w = tid >> 6, lane = tid & 63;
  const int lrow = lane & 15, lko = (lane >> 4) << 3;
  const int8_t* qbase = qi8 + (size_t)bh * 65536;
  const int8_t* kbase = ki8 + (size_t)bh * 65536;
  bf16x8 qf[2];
  #pragma unroll
  for (int ks = 0; ks < 2; ++ks)
    qf[ks] = expand8(*(const int2*)(qbase + (size_t)(rt*64 + w*16 + lrow) * 64 + ks*32 + lko));
  const float qkScale = (g[3] + EPS_) * (g[4] + EPS_) * (1.0f / 16129.0f) * SCALE_;
  float m = -3.0e38f, den = 0.f;
  const int srow = tid >> 2, sc = tid & 3;
  const int sx = (srow & 7) << 4;
  int4 kraw = *(const int4*)(kbase + (size_t)srow * 64 + sc * 16);
  for (int t = 0; t < 16; ++t) {
    __syncthreads();
    {
      int4 lo, hi; expand16(kraw, lo, hi);
      int bb = srow * 128 + sc * 32;
      *(int4*)((char*)Ks + ( bb       ^ sx)) = lo;
      *(int4*)((char*)Ks + ((bb + 16) ^ sx)) = hi;
    }
    if (t < 15)
      kraw = *(const int4*)(kbase + (size_t)(t + 1) * 4096 + (size_t)srow * 64 + sc * 16);
    __syncthreads();
    f32x4 acc[4] = {};
    #pragma unroll
    for (int ks = 0; ks < 2; ++ks)
      #pragma unroll
      for (int j = 0; j < 4; ++j) {
        int row = j * 16 + lrow;
        bf16x8 kf = *(const bf16x8*)((const char*)Ks + ((row * 128 + (ks*32 + lko) * 2) ^ ((row & 7) << 4)));
        acc[j] = __builtin_amdgcn_mfma_f32_16x16x32_bf16(kf, qf[ks], acc[j], 0, 0, 0);
      }
    float mnew = m;
    #pragma unroll
    for (int j = 0; j < 4; ++j)
      #pragma unroll
      for (int rr = 0; rr < 4; ++rr)
        mnew = fmaxf(mnew, acc[j][rr] * qkScale);
    float d = den * __expf(m - mnew);
    #pragma unroll
    for (int j = 0; j < 4; ++j)
      #pragma unroll
      for (int rr = 0; rr < 4; ++rr)
        d += __expf(acc[j][rr] * qkScale - mnew);
    den = d; m = mnew;
  }
  // merge the 4 hi-lane k-partitions
  #pragma unroll
  for (int off = 16; off <= 32; off <<= 1) {
    float mo = __shfl_xor(m, off);
    float doo = __shfl_xor(den, off);
    float mg = fmaxf(m, mo);
    den = den * __expf(m - mg) + doo * __expf(mo - mg);
    m = mg;
  }
  if (lane < 16) {
    size_t rg = (size_t)bh * 1024 + rt * 64 + w * 16 + lane;
    rowmax[rg] = m;
    denomv[rg] = den;
  }
  // one atomic per block
  float bm = den;
  #pragma unroll
  for (int off = 1; off < 16; off <<= 1) bm = fminf(bm, __shfl_xor(bm, off));
  if (lane == 0) red[w] = bm;
  __syncthreads();
  if (tid == 0)
    atomicMin(gminden, __float_as_uint(fminf(fminf(red[0], red[1]), fminf(red[2], red[3]))));
}

// ---------------- attention pass 2 (swapped-QK MFMA, 64-row blocks, prefetch) ----------------
__global__ __launch_bounds__(256) void k_attn_pv_mfma(
    const int8_t* __restrict__ qi8, const int8_t* __restrict__ ki8, const int8_t* __restrict__ vti8,
    const float* __restrict__ g, const unsigned int* __restrict__ gminden,
    const float* __restrict__ rowmax, const float* __restrict__ denomv,
    float* __restrict__ aof, float* __restrict__ gamax) {
  __shared__ unsigned short Ks[64 * 64];
  __shared__ unsigned short Vs[64 * 64];
  __shared__ unsigned short Ps[64 * 64];
  __shared__ float red[4];
  const int bh = blockIdx.x >> 4, rt = blockIdx.x & 15;
  const int b = bh / 12, h = bh % 12;
  const int tid = threadIdx.x, w = tid >> 6, lane = tid & 63;
  const int lrow = lane & 15, lko = (lane >> 4) << 3;
  const int8_t* qbase = qi8 + (size_t)bh * 65536;
  const int8_t* kbase = ki8 + (size_t)bh * 65536;
  const int8_t* vbase = vti8 + (size_t)bh * 65536;
  bf16x8 qf[2];
  #pragma unroll
  for (int ks = 0; ks < 2; ++ks)
    qf[ks] = expand8(*(const int2*)(qbase + (size_t)(rt*64 + w*16 + lrow) * 64 + ks*32 + lko));
  const float qkScale = (g[3] + EPS_) * (g[4] + EPS_) * (1.0f / 16129.0f) * SCALE_;
  const float minden = __uint_as_float(*gminden);
  const float sa = 1.0f / minden + EPS_;
  const float invSa = 1.0f / sa;
  const float sv = g[5] + EPS_;
  const float pvScale = sa * sv * (1.0f / 32385.0f);   // /(255*127)
  const float rm  = rowmax[(size_t)bh * 1024 + rt * 64 + w * 16 + lrow];
  const float ivd = 1.0f / denomv[(size_t)bh * 1024 + rt * 64 + w * 16 + lrow];
  f32x4 accO[4] = {};
  const int srow = tid >> 2, sc = tid & 3;
  const int sx = (srow & 7) << 4;
  int4 kraw = *(const int4*)(kbase + (size_t)srow * 64 + sc * 16);
  int4 vraw = *(const int4*)(vbase + (size_t)srow * 1024 + sc * 16);
  for (int t = 0; t < 16; ++t) {
    __syncthreads();
    {
      int4 lo, hi;
      int bb = srow * 128 + sc * 32;
      expand16(kraw, lo, hi);
      *(int4*)((char*)Ks + ( bb       ^ sx)) = lo;
      *(int4*)((char*)Ks + ((bb + 16) ^ sx)) = hi;
      expand16(vraw, lo, hi);
      *(int4*)((char*)Vs + ( bb       ^ sx)) = lo;
      *(int4*)((char*)Vs + ((bb + 16) ^ sx)) = hi;
    }
    if (t < 15) {
      kraw = *(const int4*)(kbase + (size_t)(t + 1) * 4096 + (size_t)srow * 64 + sc * 16);
      vraw = *(const int4*)(vbase + (size_t)srow * 1024 + (t + 1) * 64 + sc * 16);
    }
    __syncthreads();
    f32x4 acc[4] = {};
    #pragma unroll
    for (int ks = 0; ks < 2; ++ks)
      #pragma unroll
      for (int j = 0; j < 4; ++j) {
        int row = j * 16 + lrow;
        bf16x8 kf = *(const bf16x8*)((const char*)Ks + ((row * 128 + (ks*32 + lko) * 2) ^ ((row & 7) << 4)));
        acc[j] = __builtin_amdgcn_mfma_f32_16x16x32_bf16(kf, qf[ks], acc[j], 0, 0, 0);
      }
    // softmax -> unsigned 8-bit levels (exact bf16) -> Ps (in-lane)
    const int q = w * 16 + lrow;
    const int kb = (lane >> 4) << 2;
    #pragma unroll
    for (int j = 0; j < 4; ++j) {
      float a0 = rintf(fminf(__expf(acc[j][0] * qkScale - rm) * ivd * invSa, 1.0f) * 255.0f);
      float a1 = rintf(fminf(__expf(acc[j][1] * qkScale - rm) * ivd * invSa, 1.0f) * 255.0f);
      float a2 = rintf(fminf(__expf(acc[j][2] * qkScale - rm) * ivd * invSa, 1.0f) * 255.0f);
      float a3 = rintf(fminf(__expf(acc[j][3] * qkScale - rm) * ivd * invSa, 1.0f) * 255.0f);
      uint2 pk;
      pk.x = (__float_as_uint(a0) >> 16) | ((__float_as_uint(a1) >> 16) << 16);
      pk.y = (__float_as_uint(a2) >> 16) | ((__float_as_uint(a3) >> 16) << 16);
      int byteoff = (q * 128 + (j * 16 + kb) * 2) ^ ((q & 7) << 4);
      *(uint2*)((char*)Ps + byteoff) = pk;
    }
    // O += P @ V
    #pragma unroll
    for (int ks = 0; ks < 2; ++ks) {
      bf16x8 pf = *(const bf16x8*)((const char*)Ps + ((q * 128 + (ks*32 + lko) * 2) ^ ((q & 7) << 4)));
      #pragma unroll
      for (int j = 0; j < 4; ++j) {
        int row = j * 16 + lrow;
        bf16x8 vf = *(const bf16x8*)((const char*)Vs + ((row * 128 + (ks*32 + lko) * 2) ^ ((row & 7) << 4)));
        accO[j] = __builtin_amdgcn_mfma_f32_16x16x32_bf16(pf, vf, accO[j], 0, 0, 0);
      }
    }
  }
  float amax = 0.f;
  #pragma unroll
  for (int j = 0; j < 4; ++j) {
    int d = j * 16 + lrow;
    #pragma unroll
    for (int rr = 0; rr < 4; ++rr) {
      int row = rt * 64 + w * 16 + (lane >> 4) * 4 + rr;
      float val = accO[j][rr] * pvScale;
      aof[((size_t)(b * 1024 + row)) * 768 + h * 64 + d] = val;
      amax = fmaxf(amax, fabsf(val));
    }
  }
  #pragma unroll
  for (int off = 1; off < 64; off <<= 1) amax = fmaxf(amax, __shfl_xor(amax, off));
  if (lane == 0) red[w] = amax;
  __syncthreads();
  if (tid == 0)
    atomicMax((unsigned int*)gamax, __float_as_uint(fmaxf(fmaxf(red[0], red[1]), fmaxf(red[2], red[3]))));
}

extern "C" void kernel_launch(void* const* d_in, const int* in_sizes, int n_in,
                              void* d_out, int out_size, void* d_ws, size_t ws_size,
                              hipStream_t stream) {
  const float* x      = (const float*)d_in[0];   // [8,1024,768]
  const float* qkv_w  = (const float*)d_in[1];   // [2304,768]
  const float* qkv_b  = (const float*)d_in[2];   // [2304]
  const float* proj_w = (const float*)d_in[3];   // [768,768]
  const float* proj_b = (const float*)d_in[4];   // [768]
  float* out = (float*)d_out;

  char* w = (char*)d_ws;
  float*          g      = (float*)(w + 0);                 // 8 stats
  float*          rowmax = (float*)(w + 256);               // 393216 B
  float*          denomv = (float*)(w + 393472);            // 393216 B
  int8_t*         qi8    = (int8_t*)(w + 786688);           // 6291456 B
  int8_t*         ki8    = (int8_t*)(w + 7078144);          // 6291456 B
  int8_t*         vT     = (int8_t*)(w + 13369600);         // 6291456 B
  unsigned short* pw     = (unsigned short*)(w + 19661056); // 1179648 B (live to end)
  unsigned short* xq     = (unsigned short*)(w + 20840704); // 12582912 B (dead after GEMM1)
  unsigned short* wq     = (unsigned short*)(w + 33423616); //  3538944 B (dead after GEMM1)
  float*          qkvf   = (float*)(w + 36962560);          // 75497472 B (dead after quant_heads)
  float*          aof    = (float*)(w + 36962560);          // 25165824 B (aliases dead qkvf)
  unsigned short* aobf   = (unsigned short*)(w + 62128384); // 12582912 B (inside qkvf region)

  hipLaunchKernelGGL(k_init, dim3(1), dim3(64), 0, stream, g);

  hipLaunchKernelGGL(k_absmax_fused, dim3(528), dim3(256), 0, stream,
                     (const float4*)x, (const float4*)qkv_w, (const float4*)proj_w, g);

  hipLaunchKernelGGL(k_quant_fused, dim3(2112), dim3(256), 0, stream,
                     x, qkv_w, proj_w, g, xq, wq, pw);

  // qkv = xq @ wq^T * (sx*sw/127^2) + b -> f32 [8192][2304]; also per-part |max| -> g[3..5]
  hipLaunchKernelGGL(k_gemm, dim3(TC_ / 128, M_ / 128), dim3(256), 0, stream,
                     xq, wq, qkv_b, qkvf, M_, TC_, C_, &g[0], &g[1], &g[3], 768);

  hipLaunchKernelGGL(k_quant_heads, dim3(2048), dim3(256), 0, stream, qkvf, g, qi8, ki8, vT);

  hipLaunchKernelGGL(k_attn_stats_mfma, dim3(1536), dim3(256), 0, stream,
                     qi8, ki8, g, rowmax, denomv, (unsigned int*)&g[6]);
  hipLaunchKernelGGL(k_attn_pv_mfma, dim3(1536), dim3(256), 0, stream,
                     qi8, ki8, vT, g, (const unsigned int*)&g[6], rowmax, denomv, aof, &g[7]);

  hipLaunchKernelGGL(k_quant_bf16, dim3(2048), dim3(256), 0, stream, aof, 6291456u, &g[7], aobf);

  // out = aobf @ pw^T * (sao*spw/127^2) + proj_b -> d_out f32 [8192][768]
  hipLaunchKernelGGL(k_gemm, dim3(C_ / 128, M_ / 128), dim3(256), 0, stream,
                     aobf, pw, proj_b, out, M_, C_, C_, &g[7], &g[2], (float*)nullptr, 1);

  (void)in_sizes; (void)n_in; (void)out_size; (void)ws_size;
}

// Round 7
// 275.677 us; speedup vs baseline: 5.0725x; 1.0052x over previous
//
#include <hip/hip_runtime.h>
#include <hip/hip_bf16.h>
#include <cstdint>
#include <cstddef>

// Problem constants
#define B_    8
#define SEQ_  1024
#define C_    768
#define H_    12
#define D_    64
#define TC_   2304          // 3*C
#define M_    8192          // B*SEQ
#define EPS_  1e-7f
#define SCALE_ 0.036084391824351615f  // 768^-0.5

typedef __attribute__((ext_vector_type(8))) short bf16x8;
typedef __attribute__((ext_vector_type(4))) float f32x4;

#define GLOAD_LDS16(gsrc, ldst) \
  __builtin_amdgcn_global_load_lds((const __attribute__((address_space(1))) unsigned int*)(gsrc), \
                                   (__attribute__((address_space(3))) unsigned int*)(ldst), 16, 0, 0)

// int8 -> bf16 integer levels (exact for |v|<=255)
__device__ __forceinline__ bf16x8 expand8(int2 raw) {
  union { int2 v; signed char c[8]; } u; u.v = raw;
  bf16x8 r;
  #pragma unroll
  for (int j = 0; j < 8; ++j) {
    float f = (float)(int)u.c[j];
    r[j] = (short)(__float_as_uint(f) >> 16);
  }
  return r;
}
__device__ __forceinline__ void expand16(int4 raw, int4& lo, int4& hi) {
  union { int4 v; signed char c[16]; } u; u.v = raw;
  unsigned short s[16];
  #pragma unroll
  for (int j = 0; j < 16; ++j) {
    float f = (float)(int)u.c[j];
    s[j] = (unsigned short)(__float_as_uint(f) >> 16);
  }
  lo = *(const int4*)&s[0]; hi = *(const int4*)&s[8];
}

// ---------------- init global stats ----------------
// g[0]=max|x| g[1]=max|qkv_w| g[2]=max|proj_w| g[3]=max|q| g[4]=max|k| g[5]=max|v|
// g[6]=min softmax-denom  g[7]=max|attn_out|
__global__ void k_init(float* g) {
  if (threadIdx.x == 0) {
    g[0]=0.f; g[1]=0.f; g[2]=0.f; g[3]=0.f; g[4]=0.f; g[5]=0.f;
    g[6]=3.402823466e+38f;
    g[7]=0.f;
  }
}

// ---------------- fused abs-max over x / qkv_w / proj_w, 1 atomic per block ----------------
__global__ __launch_bounds__(256) void k_absmax_fused(const float4* __restrict__ x,
                                                      const float4* __restrict__ w1,
                                                      const float4* __restrict__ w2,
                                                      float* g) {
  __shared__ float red[4];
  const int blk = blockIdx.x;
  const float4* p; unsigned n4; float* gout; int b0, nb;
  if (blk < 384)      { p = x;  n4 = 1572864u; gout = &g[0]; b0 = 0;   nb = 384; }
  else if (blk < 480) { p = w1; n4 = 442368u;  gout = &g[1]; b0 = 384; nb = 96;  }
  else                { p = w2; n4 = 147456u;  gout = &g[2]; b0 = 480; nb = 48;  }
  float m = 0.f;
  for (unsigned i = (unsigned)(blk - b0) * 256u + threadIdx.x; i < n4; i += (unsigned)nb * 256u) {
    float4 v = p[i];
    m = fmaxf(m, fmaxf(fmaxf(fabsf(v.x), fabsf(v.y)), fmaxf(fabsf(v.z), fabsf(v.w))));
  }
  #pragma unroll
  for (int off = 32; off; off >>= 1) m = fmaxf(m, __shfl_xor(m, off));
  if ((threadIdx.x & 63) == 0) red[threadIdx.x >> 6] = m;
  __syncthreads();
  if (threadIdx.x == 0) {
    m = fmaxf(fmaxf(red[0], red[1]), fmaxf(red[2], red[3]));
    atomicMax((unsigned int*)gout, __float_as_uint(m));
  }
}

// ---------------- signed fake-quant -> bf16 integer levels ----------------
__device__ __forceinline__ void quant_seg(const float* __restrict__ in, unsigned n, float s,
                                          unsigned short* __restrict__ out, unsigned i0, unsigned stride) {
  for (unsigned i = i0; i < n; i += stride) {
    float v = in[i];
    float y = fminf(fabsf(v) / s, 1.0f);
    float q = rintf(y * 127.0f);          // half-to-even, matches jnp.round
    if (v < 0.f) q = -q;
    out[i] = (unsigned short)(__float_as_uint(q) >> 16);  // exact: integer <= 127
  }
}
__global__ __launch_bounds__(256) void k_quant_fused(const float* __restrict__ x,
                                                     const float* __restrict__ w1,
                                                     const float* __restrict__ w2,
                                                     const float* __restrict__ g,
                                                     unsigned short* __restrict__ xq,
                                                     unsigned short* __restrict__ wq,
                                                     unsigned short* __restrict__ pw) {
  const int blk = blockIdx.x;
  if (blk < 1536)      quant_seg(x,  6291456u, g[0] + EPS_, xq, (unsigned)blk * 256u + threadIdx.x, 1536u * 256u);
  else if (blk < 1968) quant_seg(w1, 1769472u, g[1] + EPS_, wq, (unsigned)(blk - 1536) * 256u + threadIdx.x, 432u * 256u);
  else                 quant_seg(w2,  589824u, g[2] + EPS_, pw, (unsigned)(blk - 1968) * 256u + threadIdx.x, 144u * 256u);
}

__global__ __launch_bounds__(256) void k_quant_bf16(const float* __restrict__ in, unsigned n,
                                                    const float* __restrict__ gmax,
                                                    unsigned short* __restrict__ out) {
  const float s = *gmax + EPS_;
  quant_seg(in, n, s, out, blockIdx.x * blockDim.x + threadIdx.x, gridDim.x * blockDim.x);
}

// ---------------- bf16-integer MFMA GEMM (2-phase dbuf + counted vmcnt T4 + T2 src-swizzle) -----
// A: [Mn][Kn], Bt: [Nn][Kn] bf16 int-levels; global_load_lds w16 with permuted global col;
// LDS physically holds logical ^ ((row&7)<<4); reads apply the same XOR. XCD swizzle.
// Per K-step: issue 8 next-tile loads -> vmcnt(8) (keep them in flight) -> barrier -> MFMA -> barrier.
__global__ __launch_bounds__(256) void k_gemm(const unsigned short* __restrict__ A,
                                              const unsigned short* __restrict__ Bt,
                                              const float* __restrict__ bias,
                                              float* __restrict__ C,
                                              int Mn, int Nn, int Kn,
                                              const float* __restrict__ sA, const float* __restrict__ sB,
                                              float* pmax, int partDiv) {
  __shared__ unsigned short As[2][128 * 64];
  __shared__ unsigned short Bs[2][128 * 64];
  const int tid = threadIdx.x;
  // bijective XCD swizzle (nwg % 8 == 0 for both GEMMs)
  int flat = blockIdx.y * gridDim.x + blockIdx.x;
  int chunk = (gridDim.x * gridDim.y) >> 3;
  int nf = (flat & 7) * chunk + (flat >> 3);
  const int n0 = (nf % gridDim.x) * 128, m0 = (nf / gridDim.x) * 128;
  const int wid = tid >> 6, lane = tid & 63;
  const int wr = wid >> 1, wc = wid & 1;            // 2x2 waves -> 64x64 each
  const int lrow = lane & 15;
  const int lko = (lane >> 4) << 3;                 // k offset 0/8/16/24
  f32x4 acc[4][4] = {};
  // staging: wave w, call c: lane l fills LDS row w*32+c*8+(l>>3), phys 16B-slot (l&7).
  // source col permuted so that LDS phys = logical ^ ((row&7)<<4):
  const int gr = (wid << 5) + (lane >> 3);
  const int gc = (((lane & 7) ^ ((lane >> 3) & 7)) << 3);   // pre-swizzled global ushort col
  const unsigned short* ga = A  + (size_t)(m0 + gr) * Kn + gc;
  const unsigned short* gb = Bt + (size_t)(n0 + gr) * Kn + gc;
  const int nt = Kn >> 6;
  // prologue: stage tile 0 into buffer 0 (no wait here; folded into iter 0)
  #pragma unroll
  for (int c = 0; c < 4; ++c) {
    GLOAD_LDS16(ga + (size_t)(c * 8) * Kn, &As[0][(wid * 32 + c * 8) * 64]);
    GLOAD_LDS16(gb + (size_t)(c * 8) * Kn, &Bs[0][(wid * 32 + c * 8) * 64]);
  }
  int cur = 0;
  for (int t = 0; t < nt; ++t) {
    // issue next tile's stage; its 8 loads stay in flight across the barrier
    if (t + 1 < nt) {
      #pragma unroll
      for (int c = 0; c < 4; ++c) {
        GLOAD_LDS16(ga + (size_t)(c * 8) * Kn + (t + 1) * 64, &As[cur ^ 1][(wid * 32 + c * 8) * 64]);
        GLOAD_LDS16(gb + (size_t)(c * 8) * Kn + (t + 1) * 64, &Bs[cur ^ 1][(wid * 32 + c * 8) * 64]);
      }
      asm volatile("s_waitcnt vmcnt(8)" ::: "memory");   // my current-tile loads landed
    } else {
      asm volatile("s_waitcnt vmcnt(0)" ::: "memory");   // last tile: drain
    }
    __builtin_amdgcn_s_barrier();                        // everyone's current-tile loads landed
    __builtin_amdgcn_sched_barrier(0);
    const char* Ab = (const char*)As[cur];
    const char* Bb = (const char*)Bs[cur];
    #pragma unroll
    for (int kk = 0; kk < 64; kk += 32) {
      bf16x8 af[4], bfr[4];
      #pragma unroll
      for (int i = 0; i < 4; ++i) {
        int row = wr * 64 + i * 16 + lrow;
        af[i] = *(const bf16x8*)(Ab + ((row * 128 + (kk + lko) * 2) ^ ((row & 7) << 4)));
      }
      #pragma unroll
      for (int j = 0; j < 4; ++j) {
        int row = wc * 64 + j * 16 + lrow;
        bfr[j] = *(const bf16x8*)(Bb + ((row * 128 + (kk + lko) * 2) ^ ((row & 7) << 4)));
      }
      #pragma unroll
      for (int i = 0; i < 4; ++i)
        #pragma unroll
        for (int j = 0; j < 4; ++j)
          acc[i][j] = __builtin_amdgcn_mfma_f32_16x16x32_bf16(af[i], bfr[j], acc[i][j], 0, 0, 0);
    }
    __builtin_amdgcn_s_barrier();                        // all reads of buf[cur] done
    cur ^= 1;
  }
  const float alpha = (sA[0] + EPS_) * (sB[0] + EPS_) * (1.0f / 16129.0f);
  const int orow = (lane >> 4) << 2;
  float amax = 0.f;
  #pragma unroll
  for (int i = 0; i < 4; ++i) {
    #pragma unroll
    for (int j = 0; j < 4; ++j) {
      int col = n0 + wc * 64 + j * 16 + lrow;
      float bc = bias[col];
      #pragma unroll
      for (int rr = 0; rr < 4; ++rr) {
        int row = m0 + wr * 64 + i * 16 + orow + rr;
        float val = acc[i][j][rr] * alpha + bc;
        C[(size_t)row * Nn + col] = val;
        amax = fmaxf(amax, fabsf(val));
      }
    }
  }
  if (pmax) {
    #pragma unroll
    for (int off = 32; off; off >>= 1) amax = fmaxf(amax, __shfl_xor(amax, off));
    if (lane == 0) atomicMax((unsigned int*)&pmax[n0 / partDiv], __float_as_uint(amax));
  }
}

// ---------------- quantize qkv into int8 head-layouts ----------------
__global__ __launch_bounds__(256) void k_quant_heads(const float* __restrict__ qkvf, const float* __restrict__ g,
                                                     int8_t* __restrict__ qo, int8_t* __restrict__ ko,
                                                     int8_t* __restrict__ vT) {
  const unsigned total = (unsigned)M_ * TC_;
  const float s0 = g[3] + EPS_, s1 = g[4] + EPS_, s2 = g[5] + EPS_;
  for (unsigned i = blockIdx.x * blockDim.x + threadIdx.x; i < total; i += gridDim.x * blockDim.x) {
    unsigned m = i / 2304u, o = i % 2304u;
    unsigned part = o / 768u, c = o % 768u;
    unsigned h = c >> 6, d = c & 63;
    unsigned b = m >> 10, n = m & 1023;
    float s = (part == 0) ? s0 : (part == 1) ? s1 : s2;
    float v = qkvf[i];
    float y = fminf(fabsf(v) / s, 1.0f);
    int q = (int)rintf(y * 127.0f);
    if (v < 0.f) q = -q;
    unsigned bh = b * 12 + h;
    if (part == 0)      qo[((size_t)bh * 1024 + n) * 64 + d] = (int8_t)q;
    else if (part == 1) ko[((size_t)bh * 1024 + n) * 64 + d] = (int8_t)q;
    else                vT[((size_t)bh * 64 + d) * 1024 + n] = (int8_t)q;
  }
}

// ---------------- attention pass 1 (swapped-QK MFMA, 64-row blocks, prefetch) ----------------
// grid: 1536 = bh(96) x rt(16); 4 waves x 16 q-rows.
__global__ __launch_bounds__(256) void k_attn_stats_mfma(
    const int8_t* __restrict__ qi8, const int8_t* __restrict__ ki8,
    const float* __restrict__ g, float* __restrict__ rowmax, float* __restrict__ denomv,
    unsigned int* __restrict__ gminden) {
  __shared__ unsigned short Ks[64 * 64];
  __shared__ float red[4];
  const int bh = blockIdx.x >> 4, rt = blockIdx.x & 15;
  const int tid = threadIdx.x, w = tid >> 6, lane = tid & 63;
  const int lrow = lane & 15, lko = (lane >> 4) << 3;
  const int8_t* qbase = qi8 + (size_t)bh * 65536;
  const int8_t* kbase = ki8 + (size_t)bh * 65536;
  bf16x8 qf[2];
  #pragma unroll
  for (int ks = 0; ks < 2; ++ks)
    qf[ks] = expand8(*(const int2*)(qbase + (size_t)(rt*64 + w*16 + lrow) * 64 + ks*32 + lko));
  const float qkScale = (g[3] + EPS_) * (g[4] + EPS_) * (1.0f / 16129.0f) * SCALE_;
  float m = -3.0e38f, den = 0.f;
  const int srow = tid >> 2, sc = tid & 3;
  const int sx = (srow & 7) << 4;
  int4 kraw = *(const int4*)(kbase + (size_t)srow * 64 + sc * 16);
  for (int t = 0; t < 16; ++t) {
    __syncthreads();
    {
      int4 lo, hi; expand16(kraw, lo, hi);
      int bb = srow * 128 + sc * 32;
      *(int4*)((char*)Ks + ( bb       ^ sx)) = lo;
      *(int4*)((char*)Ks + ((bb + 16) ^ sx)) = hi;
    }
    if (t < 15)
      kraw = *(const int4*)(kbase + (size_t)(t + 1) * 4096 + (size_t)srow * 64 + sc * 16);
    __syncthreads();
    f32x4 acc[4] = {};
    #pragma unroll
    for (int ks = 0; ks < 2; ++ks)
      #pragma unroll
      for (int j = 0; j < 4; ++j) {
        int row = j * 16 + lrow;
        bf16x8 kf = *(const bf16x8*)((const char*)Ks + ((row * 128 + (ks*32 + lko) * 2) ^ ((row & 7) << 4)));
        acc[j] = __builtin_amdgcn_mfma_f32_16x16x32_bf16(kf, qf[ks], acc[j], 0, 0, 0);
      }
    float mnew = m;
    #pragma unroll
    for (int j = 0; j < 4; ++j)
      #pragma unroll
      for (int rr = 0; rr < 4; ++rr)
        mnew = fmaxf(mnew, acc[j][rr] * qkScale);
    float d = den * __expf(m - mnew);
    #pragma unroll
    for (int j = 0; j < 4; ++j)
      #pragma unroll
      for (int rr = 0; rr < 4; ++rr)
        d += __expf(acc[j][rr] * qkScale - mnew);
    den = d; m = mnew;
  }
  // merge the 4 hi-lane k-partitions
  #pragma unroll
  for (int off = 16; off <= 32; off <<= 1) {
    float mo = __shfl_xor(m, off);
    float doo = __shfl_xor(den, off);
    float mg = fmaxf(m, mo);
    den = den * __expf(m - mg) + doo * __expf(mo - mg);
    m = mg;
  }
  if (lane < 16) {
    size_t rg = (size_t)bh * 1024 + rt * 64 + w * 16 + lane;
    rowmax[rg] = m;
    denomv[rg] = den;
  }
  // one atomic per block
  float bm = den;
  #pragma unroll
  for (int off = 1; off < 16; off <<= 1) bm = fminf(bm, __shfl_xor(bm, off));
  if (lane == 0) red[w] = bm;
  __syncthreads();
  if (tid == 0)
    atomicMin(gminden, __float_as_uint(fminf(fminf(red[0], red[1]), fminf(red[2], red[3]))));
}

// ---------------- attention pass 2 (swapped-QK MFMA, 64-row blocks, prefetch) ----------------
__global__ __launch_bounds__(256) void k_attn_pv_mfma(
    const int8_t* __restrict__ qi8, const int8_t* __restrict__ ki8, const int8_t* __restrict__ vti8,
    const float* __restrict__ g, const unsigned int* __restrict__ gminden,
    const float* __restrict__ rowmax, const float* __restrict__ denomv,
    float* __restrict__ aof, float* __restrict__ gamax) {
  __shared__ unsigned short Ks[64 * 64];
  __shared__ unsigned short Vs[64 * 64];
  __shared__ unsigned short Ps[64 * 64];
  __shared__ float red[4];
  const int bh = blockIdx.x >> 4, rt = blockIdx.x & 15;
  const int b = bh / 12, h = bh % 12;
  const int tid = threadIdx.x, w = tid >> 6, lane = tid & 63;
  const int lrow = lane & 15, lko = (lane >> 4) << 3;
  const int8_t* qbase = qi8 + (size_t)bh * 65536;
  const int8_t* kbase = ki8 + (size_t)bh * 65536;
  const int8_t* vbase = vti8 + (size_t)bh * 65536;
  bf16x8 qf[2];
  #pragma unroll
  for (int ks = 0; ks < 2; ++ks)
    qf[ks] = expand8(*(const int2*)(qbase + (size_t)(rt*64 + w*16 + lrow) * 64 + ks*32 + lko));
  const float qkScale = (g[3] + EPS_) * (g[4] + EPS_) * (1.0f / 16129.0f) * SCALE_;
  const float minden = __uint_as_float(*gminden);
  const float sa = 1.0f / minden + EPS_;
  const float invSa = 1.0f / sa;
  const float sv = g[5] + EPS_;
  const float pvScale = sa * sv * (1.0f / 32385.0f);   // /(255*127)
  const float rm  = rowmax[(size_t)bh * 1024 + rt * 64 + w * 16 + lrow];
  const float ivd = 1.0f / denomv[(size_t)bh * 1024 + rt * 64 + w * 16 + lrow];
  f32x4 accO[4] = {};
  const int srow = tid >> 2, sc = tid & 3;
  const int sx = (srow & 7) << 4;
  int4 kraw = *(const int4*)(kbase + (size_t)srow * 64 + sc * 16);
  int4 vraw = *(const int4*)(vbase + (size_t)srow * 1024 + sc * 16);
  for (int t = 0; t < 16; ++t) {
    __syncthreads();
    {
      int4 lo, hi;
      int bb = srow * 128 + sc * 32;
      expand16(kraw, lo, hi);
      *(int4*)((char*)Ks + ( bb       ^ sx)) = lo;
      *(int4*)((char*)Ks + ((bb + 16) ^ sx)) = hi;
      expand16(vraw, lo, hi);
      *(int4*)((char*)Vs + ( bb       ^ sx)) = lo;
      *(int4*)((char*)Vs + ((bb + 16) ^ sx)) = hi;
    }
    if (t < 15) {
      kraw = *(const int4*)(kbase + (size_t)(t + 1) * 4096 + (size_t)srow * 64 + sc * 16);
      vraw = *(const int4*)(vbase + (size_t)srow * 1024 + (t + 1) * 64 + sc * 16);
    }
    __syncthreads();
    f32x4 acc[4] = {};
    #pragma unroll
    for (int ks = 0; ks < 2; ++ks)
      #pragma unroll
      for (int j = 0; j < 4; ++j) {
        int row = j * 16 + lrow;
        bf16x8 kf = *(const bf16x8*)((const char*)Ks + ((row * 128 + (ks*32 + lko) * 2) ^ ((row & 7) << 4)));
        acc[j] = __builtin_amdgcn_mfma_f32_16x16x32_bf16(kf, qf[ks], acc[j], 0, 0, 0);
      }
    // softmax -> unsigned 8-bit levels (exact bf16) -> Ps (in-lane)
    const int q = w * 16 + lrow;
    const int kb = (lane >> 4) << 2;
    #pragma unroll
    for (int j = 0; j < 4; ++j) {
      float a0 = rintf(fminf(__expf(acc[j][0] * qkScale - rm) * ivd * invSa, 1.0f) * 255.0f);
      float a1 = rintf(fminf(__expf(acc[j][1] * qkScale - rm) * ivd * invSa, 1.0f) * 255.0f);
      float a2 = rintf(fminf(__expf(acc[j][2] * qkScale - rm) * ivd * invSa, 1.0f) * 255.0f);
      float a3 = rintf(fminf(__expf(acc[j][3] * qkScale - rm) * ivd * invSa, 1.0f) * 255.0f);
      uint2 pk;
      pk.x = (__float_as_uint(a0) >> 16) | ((__float_as_uint(a1) >> 16) << 16);
      pk.y = (__float_as_uint(a2) >> 16) | ((__float_as_uint(a3) >> 16) << 16);
      int byteoff = (q * 128 + (j * 16 + kb) * 2) ^ ((q & 7) << 4);
      *(uint2*)((char*)Ps + byteoff) = pk;
    }
    // O += P @ V
    #pragma unroll
    for (int ks = 0; ks < 2; ++ks) {
      bf16x8 pf = *(const bf16x8*)((const char*)Ps + ((q * 128 + (ks*32 + lko) * 2) ^ ((q & 7) << 4)));
      #pragma unroll
      for (int j = 0; j < 4; ++j) {
        int row = j * 16 + lrow;
        bf16x8 vf = *(const bf16x8*)((const char*)Vs + ((row * 128 + (ks*32 + lko) * 2) ^ ((row & 7) << 4)));
        accO[j] = __builtin_amdgcn_mfma_f32_16x16x32_bf16(pf, vf, accO[j], 0, 0, 0);
      }
    }
  }
  float amax = 0.f;
  #pragma unroll
  for (int j = 0; j < 4; ++j) {
    int d = j * 16 + lrow;
    #pragma unroll
    for (int rr = 0; rr < 4; ++rr) {
      int row = rt * 64 + w * 16 + (lane >> 4) * 4 + rr;
      float val = accO[j][rr] * pvScale;
      aof[((size_t)(b * 1024 + row)) * 768 + h * 64 + d] = val;
      amax = fmaxf(amax, fabsf(val));
    }
  }
  #pragma unroll
  for (int off = 1; off < 64; off <<= 1) amax = fmaxf(amax, __shfl_xor(amax, off));
  if (lane == 0) red[w] = amax;
  __syncthreads();
  if (tid == 0)
    atomicMax((unsigned int*)gamax, __float_as_uint(fmaxf(fmaxf(red[0], red[1]), fmaxf(red[2], red[3]))));
}

extern "C" void kernel_launch(void* const* d_in, const int* in_sizes, int n_in,
                              void* d_out, int out_size, void* d_ws, size_t ws_size,
                              hipStream_t stream) {
  const float* x      = (const float*)d_in[0];   // [8,1024,768]
  const float* qkv_w  = (const float*)d_in[1];   // [2304,768]
  const float* qkv_b  = (const float*)d_in[2];   // [2304]
  const float* proj_w = (const float*)d_in[3];   // [768,768]
  const float* proj_b = (const float*)d_in[4];   // [768]
  float* out = (float*)d_out;

  char* w = (char*)d_ws;
  float*          g      = (float*)(w + 0);                 // 8 stats
  float*          rowmax = (float*)(w + 256);               // 393216 B
  float*          denomv = (float*)(w + 393472);            // 393216 B
  int8_t*         qi8    = (int8_t*)(w + 786688);           // 6291456 B
  int8_t*         ki8    = (int8_t*)(w + 7078144);          // 6291456 B
  int8_t*         vT     = (int8_t*)(w + 13369600);         // 6291456 B
  unsigned short* pw     = (unsigned short*)(w + 19661056); // 1179648 B (live to end)
  unsigned short* xq     = (unsigned short*)(w + 20840704); // 12582912 B (dead after GEMM1)
  unsigned short* wq     = (unsigned short*)(w + 33423616); //  3538944 B (dead after GEMM1)
  float*          qkvf   = (float*)(w + 36962560);          // 75497472 B (dead after quant_heads)
  float*          aof    = (float*)(w + 36962560);          // 25165824 B (aliases dead qkvf)
  unsigned short* aobf   = (unsigned short*)(w + 62128384); // 12582912 B (inside qkvf region)

  hipLaunchKernelGGL(k_init, dim3(1), dim3(64), 0, stream, g);

  hipLaunchKernelGGL(k_absmax_fused, dim3(528), dim3(256), 0, stream,
                     (const float4*)x, (const float4*)qkv_w, (const float4*)proj_w, g);

  hipLaunchKernelGGL(k_quant_fused, dim3(2112), dim3(256), 0, stream,
                     x, qkv_w, proj_w, g, xq, wq, pw);

  // qkv = xq @ wq^T * (sx*sw/127^2) + b -> f32 [8192][2304]; also per-part |max| -> g[3..5]
  hipLaunchKernelGGL(k_gemm, dim3(TC_ / 128, M_ / 128), dim3(256), 0, stream,
                     xq, wq, qkv_b, qkvf, M_, TC_, C_, &g[0], &g[1], &g[3], 768);

  hipLaunchKernelGGL(k_quant_heads, dim3(2048), dim3(256), 0, stream, qkvf, g, qi8, ki8, vT);

  hipLaunchKernelGGL(k_attn_stats_mfma, dim3(1536), dim3(256), 0, stream,
                     qi8, ki8, g, rowmax, denomv, (unsigned int*)&g[6]);
  hipLaunchKernelGGL(k_attn_pv_mfma, dim3(1536), dim3(256), 0, stream,
                     qi8, ki8, vT, g, (const unsigned int*)&g[6], rowmax, denomv, aof, &g[7]);

  hipLaunchKernelGGL(k_quant_bf16, dim3(2048), dim3(256), 0, stream, aof, 6291456u, &g[7], aobf);

  // out = aobf @ pw^T * (sao*spw/127^2) + proj_b -> d_out f32 [8192][768]
  hipLaunchKernelGGL(k_gemm, dim3(C_ / 128, M_ / 128), dim3(256), 0, stream,
                     aobf, pw, proj_b, out, M_, C_, C_, &g[7], &g[2], (float*)nullptr, 1);

  (void)in_sizes; (void)n_in; (void)out_size; (void)ws_size;
}

// Round 8
// 269.354 us; speedup vs baseline: 5.1916x; 1.0235x over previous
//
#include <hip/hip_runtime.h>
#include <hip/hip_bf16.h>
#include <cstdint>
#include <cstddef>

// Problem constants
#define B_    8
#define SEQ_  1024
#define C_    768
#define H_    12
#define D_    64
#define TC_   2304          // 3*C
#define M_    8192          // B*SEQ
#define EPS_  1e-7f
#define SCALE_ 0.036084391824351615f  // 768^-0.5

typedef __attribute__((ext_vector_type(8))) short bf16x8;
typedef __attribute__((ext_vector_type(4))) float f32x4;

// int8 -> bf16 integer levels (exact for |v|<=255)
__device__ __forceinline__ bf16x8 expand8(int2 raw) {
  union { int2 v; signed char c[8]; } u; u.v = raw;
  bf16x8 r;
  #pragma unroll
  for (int j = 0; j < 8; ++j) {
    float f = (float)(int)u.c[j];
    r[j] = (short)(__float_as_uint(f) >> 16);
  }
  return r;
}
__device__ __forceinline__ void expand16(int4 raw, int4& lo, int4& hi) {
  union { int4 v; signed char c[16]; } u; u.v = raw;
  unsigned short s[16];
  #pragma unroll
  for (int j = 0; j < 16; ++j) {
    float f = (float)(int)u.c[j];
    s[j] = (unsigned short)(__float_as_uint(f) >> 16);
  }
  lo = *(const int4*)&s[0]; hi = *(const int4*)&s[8];
}

// ---------------- init global stats ----------------
// g[0]=max|x| g[1]=max|qkv_w| g[2]=max|proj_w| g[3]=max|q| g[4]=max|k| g[5]=max|v|
// g[6]=min softmax-denom  g[7]=max|attn_out|
__global__ void k_init(float* g) {
  if (threadIdx.x == 0) {
    g[0]=0.f; g[1]=0.f; g[2]=0.f; g[3]=0.f; g[4]=0.f; g[5]=0.f;
    g[6]=3.402823466e+38f;
    g[7]=0.f;
  }
}

// ---------------- fused abs-max over x / qkv_w / proj_w, 1 atomic per block ----------------
__global__ __launch_bounds__(256) void k_absmax_fused(const float4* __restrict__ x,
                                                      const float4* __restrict__ w1,
                                                      const float4* __restrict__ w2,
                                                      float* g) {
  __shared__ float red[4];
  const int blk = blockIdx.x;
  const float4* p; unsigned n4; float* gout; int b0, nb;
  if (blk < 384)      { p = x;  n4 = 1572864u; gout = &g[0]; b0 = 0;   nb = 384; }
  else if (blk < 480) { p = w1; n4 = 442368u;  gout = &g[1]; b0 = 384; nb = 96;  }
  else                { p = w2; n4 = 147456u;  gout = &g[2]; b0 = 480; nb = 48;  }
  float m = 0.f;
  for (unsigned i = (unsigned)(blk - b0) * 256u + threadIdx.x; i < n4; i += (unsigned)nb * 256u) {
    float4 v = p[i];
    m = fmaxf(m, fmaxf(fmaxf(fabsf(v.x), fabsf(v.y)), fmaxf(fabsf(v.z), fabsf(v.w))));
  }
  #pragma unroll
  for (int off = 32; off; off >>= 1) m = fmaxf(m, __shfl_xor(m, off));
  if ((threadIdx.x & 63) == 0) red[threadIdx.x >> 6] = m;
  __syncthreads();
  if (threadIdx.x == 0) {
    m = fmaxf(fmaxf(red[0], red[1]), fmaxf(red[2], red[3]));
    atomicMax((unsigned int*)gout, __float_as_uint(m));
  }
}

// ---------------- signed fake-quant -> int8 integer levels ----------------
__device__ __forceinline__ void quant_seg8(const float* __restrict__ in, unsigned n, float s,
                                           int8_t* __restrict__ out, unsigned i0, unsigned stride) {
  for (unsigned i = i0; i < n; i += stride) {
    float v = in[i];
    float y = fminf(fabsf(v) / s, 1.0f);
    int q = (int)rintf(y * 127.0f);       // half-to-even, matches jnp.round
    if (v < 0.f) q = -q;
    out[i] = (int8_t)q;
  }
}
__global__ __launch_bounds__(256) void k_quant_fused(const float* __restrict__ x,
                                                     const float* __restrict__ w1,
                                                     const float* __restrict__ w2,
                                                     const float* __restrict__ g,
                                                     int8_t* __restrict__ xq,
                                                     int8_t* __restrict__ wq,
                                                     int8_t* __restrict__ pw) {
  const int blk = blockIdx.x;
  if (blk < 1536)      quant_seg8(x,  6291456u, g[0] + EPS_, xq, (unsigned)blk * 256u + threadIdx.x, 1536u * 256u);
  else if (blk < 1968) quant_seg8(w1, 1769472u, g[1] + EPS_, wq, (unsigned)(blk - 1536) * 256u + threadIdx.x, 432u * 256u);
  else                 quant_seg8(w2,  589824u, g[2] + EPS_, pw, (unsigned)(blk - 1968) * 256u + threadIdx.x, 144u * 256u);
}

__global__ __launch_bounds__(256) void k_quant_i8(const float* __restrict__ in, unsigned n,
                                                  const float* __restrict__ gmax,
                                                  int8_t* __restrict__ out) {
  const float s = *gmax + EPS_;
  quant_seg8(in, n, s, out, blockIdx.x * blockDim.x + threadIdx.x, gridDim.x * blockDim.x);
}

// ---------------- int8-input MFMA GEMM: C = alpha*(A.Bt^T) + bias ----------------
// A: [Mn][Kn] int8, Bt: [Nn][Kn] int8 levels. Reg-staged (T14 split: prefetch next tile to
// regs before compute barrier), in-register expand to bf16, XOR-swizzled LDS writes/reads.
// Halves HBM fetch vs bf16 inputs; B (<=1.8MB) becomes per-XCD-L2 resident. XCD swizzle.
__global__ __launch_bounds__(256) void k_gemm8(const int8_t* __restrict__ A,
                                               const int8_t* __restrict__ Bt,
                                               const float* __restrict__ bias,
                                               float* __restrict__ C,
                                               int Mn, int Nn, int Kn,
                                               const float* __restrict__ sA, const float* __restrict__ sB,
                                               float* pmax, int partDiv) {
  __shared__ unsigned short As[128 * 64];
  __shared__ unsigned short Bs[128 * 64];
  const int tid = threadIdx.x;
  // bijective XCD swizzle (nwg % 8 == 0 for both GEMMs)
  int flat = blockIdx.y * gridDim.x + blockIdx.x;
  int chunk = (gridDim.x * gridDim.y) >> 3;
  int nf = (flat & 7) * chunk + (flat >> 3);
  const int n0 = (nf % gridDim.x) * 128, m0 = (nf / gridDim.x) * 128;
  const int wid = tid >> 6, lane = tid & 63;
  const int wr = wid >> 1, wc = wid & 1;            // 2x2 waves -> 64x64 each
  const int lrow = lane & 15;
  const int lko = (lane >> 4) << 3;                 // k offset 0/8/16/24
  f32x4 acc[4][4] = {};
  // staging: slot s*256+tid (s=0,1): row = slot>>2 (0..127), 16B-chunk = slot&3
  const int r0 = tid >> 2;            // rows 0..63 (slot 0) ; slot 1 covers 64..127
  const int c0 = tid & 3;             // 16-byte chunk within the 64-int8 row
  const int8_t* ga = A  + (size_t)m0 * Kn;
  const int8_t* gb = Bt + (size_t)n0 * Kn;
  const int nt = Kn >> 6;
  int4 ra0 = *(const int4*)(ga + (size_t)r0 * Kn + c0 * 16);
  int4 ra1 = *(const int4*)(ga + (size_t)(64 + r0) * Kn + c0 * 16);
  int4 rb0 = *(const int4*)(gb + (size_t)r0 * Kn + c0 * 16);
  int4 rb1 = *(const int4*)(gb + (size_t)(64 + r0) * Kn + c0 * 16);
  for (int t = 0; t < nt; ++t) {
    if (t) __syncthreads();           // all waves done reading LDS from prev step
    {
      int4 lo, hi;
      const int sx0 = (r0 & 7) << 4;
      const int bb0 = r0 * 128 + c0 * 32;
      const int bb1 = (64 + r0) * 128 + c0 * 32;   // (64+r0)&7 == r0&7
      expand16(ra0, lo, hi);
      *(int4*)((char*)As + ( bb0       ^ sx0)) = lo;
      *(int4*)((char*)As + ((bb0 + 16) ^ sx0)) = hi;
      expand16(ra1, lo, hi);
      *(int4*)((char*)As + ( bb1       ^ sx0)) = lo;
      *(int4*)((char*)As + ((bb1 + 16) ^ sx0)) = hi;
      expand16(rb0, lo, hi);
      *(int4*)((char*)Bs + ( bb0       ^ sx0)) = lo;
      *(int4*)((char*)Bs + ((bb0 + 16) ^ sx0)) = hi;
      expand16(rb1, lo, hi);
      *(int4*)((char*)Bs + ( bb1       ^ sx0)) = lo;
      *(int4*)((char*)Bs + ((bb1 + 16) ^ sx0)) = hi;
    }
    // prefetch next K-tile to regs; loads fly under the MFMA phase (T14)
    if (t + 1 < nt) {
      const int ko = (t + 1) * 64;
      ra0 = *(const int4*)(ga + (size_t)r0 * Kn + ko + c0 * 16);
      ra1 = *(const int4*)(ga + (size_t)(64 + r0) * Kn + ko + c0 * 16);
      rb0 = *(const int4*)(gb + (size_t)r0 * Kn + ko + c0 * 16);
      rb1 = *(const int4*)(gb + (size_t)(64 + r0) * Kn + ko + c0 * 16);
    }
    __syncthreads();                  // LDS tile ready
    #pragma unroll
    for (int kk = 0; kk < 64; kk += 32) {
      bf16x8 af[4], bfr[4];
      #pragma unroll
      for (int i = 0; i < 4; ++i) {
        int row = wr * 64 + i * 16 + lrow;
        af[i] = *(const bf16x8*)((const char*)As + ((row * 128 + (kk + lko) * 2) ^ ((row & 7) << 4)));
      }
      #pragma unroll
      for (int j = 0; j < 4; ++j) {
        int row = wc * 64 + j * 16 + lrow;
        bfr[j] = *(const bf16x8*)((const char*)Bs + ((row * 128 + (kk + lko) * 2) ^ ((row & 7) << 4)));
      }
      #pragma unroll
      for (int i = 0; i < 4; ++i)
        #pragma unroll
        for (int j = 0; j < 4; ++j)
          acc[i][j] = __builtin_amdgcn_mfma_f32_16x16x32_bf16(af[i], bfr[j], acc[i][j], 0, 0, 0);
    }
  }
  const float alpha = (sA[0] + EPS_) * (sB[0] + EPS_) * (1.0f / 16129.0f);
  const int orow = (lane >> 4) << 2;
  float amax = 0.f;
  #pragma unroll
  for (int i = 0; i < 4; ++i) {
    #pragma unroll
    for (int j = 0; j < 4; ++j) {
      int col = n0 + wc * 64 + j * 16 + lrow;
      float bc = bias[col];
      #pragma unroll
      for (int rr = 0; rr < 4; ++rr) {
        int row = m0 + wr * 64 + i * 16 + orow + rr;
        float val = acc[i][j][rr] * alpha + bc;
        C[(size_t)row * Nn + col] = val;
        amax = fmaxf(amax, fabsf(val));
      }
    }
  }
  if (pmax) {
    #pragma unroll
    for (int off = 32; off; off >>= 1) amax = fmaxf(amax, __shfl_xor(amax, off));
    if (lane == 0) atomicMax((unsigned int*)&pmax[n0 / partDiv], __float_as_uint(amax));
  }
}

// ---------------- quantize qkv into int8 head-layouts ----------------
__global__ __launch_bounds__(256) void k_quant_heads(const float* __restrict__ qkvf, const float* __restrict__ g,
                                                     int8_t* __restrict__ qo, int8_t* __restrict__ ko,
                                                     int8_t* __restrict__ vT) {
  const unsigned total = (unsigned)M_ * TC_;
  const float s0 = g[3] + EPS_, s1 = g[4] + EPS_, s2 = g[5] + EPS_;
  for (unsigned i = blockIdx.x * blockDim.x + threadIdx.x; i < total; i += gridDim.x * blockDim.x) {
    unsigned m = i / 2304u, o = i % 2304u;
    unsigned part = o / 768u, c = o % 768u;
    unsigned h = c >> 6, d = c & 63;
    unsigned b = m >> 10, n = m & 1023;
    float s = (part == 0) ? s0 : (part == 1) ? s1 : s2;
    float v = qkvf[i];
    float y = fminf(fabsf(v) / s, 1.0f);
    int q = (int)rintf(y * 127.0f);
    if (v < 0.f) q = -q;
    unsigned bh = b * 12 + h;
    if (part == 0)      qo[((size_t)bh * 1024 + n) * 64 + d] = (int8_t)q;
    else if (part == 1) ko[((size_t)bh * 1024 + n) * 64 + d] = (int8_t)q;
    else                vT[((size_t)bh * 64 + d) * 1024 + n] = (int8_t)q;
  }
}

// ---------------- attention pass 1 (swapped-QK MFMA, 64-row blocks, prefetch) ----------------
// grid: 1536 = bh(96) x rt(16); 4 waves x 16 q-rows.
__global__ __launch_bounds__(256) void k_attn_stats_mfma(
    const int8_t* __restrict__ qi8, const int8_t* __restrict__ ki8,
    const float* __restrict__ g, float* __restrict__ rowmax, float* __restrict__ denomv,
    unsigned int* __restrict__ gminden) {
  __shared__ unsigned short Ks[64 * 64];
  __shared__ float red[4];
  const int bh = blockIdx.x >> 4, rt = blockIdx.x & 15;
  const int tid = threadIdx.x, w = tid >> 6, lane = tid & 63;
  const int lrow = lane & 15, lko = (lane >> 4) << 3;
  const int8_t* qbase = qi8 + (size_t)bh * 65536;
  const int8_t* kbase = ki8 + (size_t)bh * 65536;
  bf16x8 qf[2];
  #pragma unroll
  for (int ks = 0; ks < 2; ++ks)
    qf[ks] = expand8(*(const int2*)(qbase + (size_t)(rt*64 + w*16 + lrow) * 64 + ks*32 + lko));
  const float qkScale = (g[3] + EPS_) * (g[4] + EPS_) * (1.0f / 16129.0f) * SCALE_;
  float m = -3.0e38f, den = 0.f;
  const int srow = tid >> 2, sc = tid & 3;
  const int sx = (srow & 7) << 4;
  int4 kraw = *(const int4*)(kbase + (size_t)srow * 64 + sc * 16);
  for (int t = 0; t < 16; ++t) {
    __syncthreads();
    {
      int4 lo, hi; expand16(kraw, lo, hi);
      int bb = srow * 128 + sc * 32;
      *(int4*)((char*)Ks + ( bb       ^ sx)) = lo;
      *(int4*)((char*)Ks + ((bb + 16) ^ sx)) = hi;
    }
    if (t < 15)
      kraw = *(const int4*)(kbase + (size_t)(t + 1) * 4096 + (size_t)srow * 64 + sc * 16);
    __syncthreads();
    f32x4 acc[4] = {};
    #pragma unroll
    for (int ks = 0; ks < 2; ++ks)
      #pragma unroll
      for (int j = 0; j < 4; ++j) {
        int row = j * 16 + lrow;
        bf16x8 kf = *(const bf16x8*)((const char*)Ks + ((row * 128 + (ks*32 + lko) * 2) ^ ((row & 7) << 4)));
        acc[j] = __builtin_amdgcn_mfma_f32_16x16x32_bf16(kf, qf[ks], acc[j], 0, 0, 0);
      }
    float mnew = m;
    #pragma unroll
    for (int j = 0; j < 4; ++j)
      #pragma unroll
      for (int rr = 0; rr < 4; ++rr)
        mnew = fmaxf(mnew, acc[j][rr] * qkScale);
    float d = den * __expf(m - mnew);
    #pragma unroll
    for (int j = 0; j < 4; ++j)
      #pragma unroll
      for (int rr = 0; rr < 4; ++rr)
        d += __expf(acc[j][rr] * qkScale - mnew);
    den = d; m = mnew;
  }
  // merge the 4 hi-lane k-partitions
  #pragma unroll
  for (int off = 16; off <= 32; off <<= 1) {
    float mo = __shfl_xor(m, off);
    float doo = __shfl_xor(den, off);
    float mg = fmaxf(m, mo);
    den = den * __expf(m - mg) + doo * __expf(mo - mg);
    m = mg;
  }
  if (lane < 16) {
    size_t rg = (size_t)bh * 1024 + rt * 64 + w * 16 + lane;
    rowmax[rg] = m;
    denomv[rg] = den;
  }
  // one atomic per block
  float bm = den;
  #pragma unroll
  for (int off = 1; off < 16; off <<= 1) bm = fminf(bm, __shfl_xor(bm, off));
  if (lane == 0) red[w] = bm;
  __syncthreads();
  if (tid == 0)
    atomicMin(gminden, __float_as_uint(fminf(fminf(red[0], red[1]), fminf(red[2], red[3]))));
}

// ---------------- attention pass 2 (swapped-QK MFMA, 64-row blocks, prefetch) ----------------
__global__ __launch_bounds__(256) void k_attn_pv_mfma(
    const int8_t* __restrict__ qi8, const int8_t* __restrict__ ki8, const int8_t* __restrict__ vti8,
    const float* __restrict__ g, const unsigned int* __restrict__ gminden,
    const float* __restrict__ rowmax, const float* __restrict__ denomv,
    float* __restrict__ aof, float* __restrict__ gamax) {
  __shared__ unsigned short Ks[64 * 64];
  __shared__ unsigned short Vs[64 * 64];
  __shared__ unsigned short Ps[64 * 64];
  __shared__ float red[4];
  const int bh = blockIdx.x >> 4, rt = blockIdx.x & 15;
  const int b = bh / 12, h = bh % 12;
  const int tid = threadIdx.x, w = tid >> 6, lane = tid & 63;
  const int lrow = lane & 15, lko = (lane >> 4) << 3;
  const int8_t* qbase = qi8 + (size_t)bh * 65536;
  const int8_t* kbase = ki8 + (size_t)bh * 65536;
  const int8_t* vbase = vti8 + (size_t)bh * 65536;
  bf16x8 qf[2];
  #pragma unroll
  for (int ks = 0; ks < 2; ++ks)
    qf[ks] = expand8(*(const int2*)(qbase + (size_t)(rt*64 + w*16 + lrow) * 64 + ks*32 + lko));
  const float qkScale = (g[3] + EPS_) * (g[4] + EPS_) * (1.0f / 16129.0f) * SCALE_;
  const float minden = __uint_as_float(*gminden);
  const float sa = 1.0f / minden + EPS_;
  const float invSa = 1.0f / sa;
  const float sv = g[5] + EPS_;
  const float pvScale = sa * sv * (1.0f / 32385.0f);   // /(255*127)
  const float rm  = rowmax[(size_t)bh * 1024 + rt * 64 + w * 16 + lrow];
  const float ivd = 1.0f / denomv[(size_t)bh * 1024 + rt * 64 + w * 16 + lrow];
  f32x4 accO[4] = {};
  const int srow = tid >> 2, sc = tid & 3;
  const int sx = (srow & 7) << 4;
  int4 kraw = *(const int4*)(kbase + (size_t)srow * 64 + sc * 16);
  int4 vraw = *(const int4*)(vbase + (size_t)srow * 1024 + sc * 16);
  for (int t = 0; t < 16; ++t) {
    __syncthreads();
    {
      int4 lo, hi;
      int bb = srow * 128 + sc * 32;
      expand16(kraw, lo, hi);
      *(int4*)((char*)Ks + ( bb       ^ sx)) = lo;
      *(int4*)((char*)Ks + ((bb + 16) ^ sx)) = hi;
      expand16(vraw, lo, hi);
      *(int4*)((char*)Vs + ( bb       ^ sx)) = lo;
      *(int4*)((char*)Vs + ((bb + 16) ^ sx)) = hi;
    }
    if (t < 15) {
      kraw = *(const int4*)(kbase + (size_t)(t + 1) * 4096 + (size_t)srow * 64 + sc * 16);
      vraw = *(const int4*)(vbase + (size_t)srow * 1024 + (t + 1) * 64 + sc * 16);
    }
    __syncthreads();
    f32x4 acc[4] = {};
    #pragma unroll
    for (int ks = 0; ks < 2; ++ks)
      #pragma unroll
      for (int j = 0; j < 4; ++j) {
        int row = j * 16 + lrow;
        bf16x8 kf = *(const bf16x8*)((const char*)Ks + ((row * 128 + (ks*32 + lko) * 2) ^ ((row & 7) << 4)));
        acc[j] = __builtin_amdgcn_mfma_f32_16x16x32_bf16(kf, qf[ks], acc[j], 0, 0, 0);
      }
    // softmax -> unsigned 8-bit levels (exact bf16) -> Ps (in-lane)
    const int q = w * 16 + lrow;
    const int kb = (lane >> 4) << 2;
    #pragma unroll
    for (int j = 0; j < 4; ++j) {
      float a0 = rintf(fminf(__expf(acc[j][0] * qkScale - rm) * ivd * invSa, 1.0f) * 255.0f);
      float a1 = rintf(fminf(__expf(acc[j][1] * qkScale - rm) * ivd * invSa, 1.0f) * 255.0f);
      float a2 = rintf(fminf(__expf(acc[j][2] * qkScale - rm) * ivd * invSa, 1.0f) * 255.0f);
      float a3 = rintf(fminf(__expf(acc[j][3] * qkScale - rm) * ivd * invSa, 1.0f) * 255.0f);
      uint2 pk;
      pk.x = (__float_as_uint(a0) >> 16) | ((__float_as_uint(a1) >> 16) << 16);
      pk.y = (__float_as_uint(a2) >> 16) | ((__float_as_uint(a3) >> 16) << 16);
      int byteoff = (q * 128 + (j * 16 + kb) * 2) ^ ((q & 7) << 4);
      *(uint2*)((char*)Ps + byteoff) = pk;
    }
    // O += P @ V
    #pragma unroll
    for (int ks = 0; ks < 2; ++ks) {
      bf16x8 pf = *(const bf16x8*)((const char*)Ps + ((q * 128 + (ks*32 + lko) * 2) ^ ((q & 7) << 4)));
      #pragma unroll
      for (int j = 0; j < 4; ++j) {
        int row = j * 16 + lrow;
        bf16x8 vf = *(const bf16x8*)((const char*)Vs + ((row * 128 + (ks*32 + lko) * 2) ^ ((row & 7) << 4)));
        accO[j] = __builtin_amdgcn_mfma_f32_16x16x32_bf16(pf, vf, accO[j], 0, 0, 0);
      }
    }
  }
  float amax = 0.f;
  #pragma unroll
  for (int j = 0; j < 4; ++j) {
    int d = j * 16 + lrow;
    #pragma unroll
    for (int rr = 0; rr < 4; ++rr) {
      int row = rt * 64 + w * 16 + (lane >> 4) * 4 + rr;
      float val = accO[j][rr] * pvScale;
      aof[((size_t)(b * 1024 + row)) * 768 + h * 64 + d] = val;
      amax = fmaxf(amax, fabsf(val));
    }
  }
  #pragma unroll
  for (int off = 1; off < 64; off <<= 1) amax = fmaxf(amax, __shfl_xor(amax, off));
  if (lane == 0) red[w] = amax;
  __syncthreads();
  if (tid == 0)
    atomicMax((unsigned int*)gamax, __float_as_uint(fmaxf(fmaxf(red[0], red[1]), fmaxf(red[2], red[3]))));
}

extern "C" void kernel_launch(void* const* d_in, const int* in_sizes, int n_in,
                              void* d_out, int out_size, void* d_ws, size_t ws_size,
                              hipStream_t stream) {
  const float* x      = (const float*)d_in[0];   // [8,1024,768]
  const float* qkv_w  = (const float*)d_in[1];   // [2304,768]
  const float* qkv_b  = (const float*)d_in[2];   // [2304]
  const float* proj_w = (const float*)d_in[3];   // [768,768]
  const float* proj_b = (const float*)d_in[4];   // [768]
  float* out = (float*)d_out;

  char* w = (char*)d_ws;
  float*          g      = (float*)(w + 0);                 // 8 stats
  float*          rowmax = (float*)(w + 256);               // 393216 B
  float*          denomv = (float*)(w + 393472);            // 393216 B
  int8_t*         qi8    = (int8_t*)(w + 786688);           // 6291456 B
  int8_t*         ki8    = (int8_t*)(w + 7078144);          // 6291456 B
  int8_t*         vT     = (int8_t*)(w + 13369600);         // 6291456 B
  int8_t*         pw8    = (int8_t*)(w + 19661056);         //  589824 B (live to end)
  int8_t*         xq8    = (int8_t*)(w + 20840704);         // 6291456 B (dead after GEMM1)
  int8_t*         wq8    = (int8_t*)(w + 33423616);         // 1769472 B (dead after GEMM1)
  float*          qkvf   = (float*)(w + 36962560);          // 75497472 B (dead after quant_heads)
  float*          aof    = (float*)(w + 36962560);          // 25165824 B (aliases dead qkvf)
  int8_t*         aob8   = (int8_t*)(w + 62128384);         // 6291456 B (inside qkvf region)

  hipLaunchKernelGGL(k_init, dim3(1), dim3(64), 0, stream, g);

  hipLaunchKernelGGL(k_absmax_fused, dim3(528), dim3(256), 0, stream,
                     (const float4*)x, (const float4*)qkv_w, (const float4*)proj_w, g);

  hipLaunchKernelGGL(k_quant_fused, dim3(2112), dim3(256), 0, stream,
                     x, qkv_w, proj_w, g, xq8, wq8, pw8);

  // qkv = xq @ wq^T * (sx*sw/127^2) + b -> f32 [8192][2304]; also per-part |max| -> g[3..5]
  hipLaunchKernelGGL(k_gemm8, dim3(TC_ / 128, M_ / 128), dim3(256), 0, stream,
                     xq8, wq8, qkv_b, qkvf, M_, TC_, C_, &g[0], &g[1], &g[3], 768);

  hipLaunchKernelGGL(k_quant_heads, dim3(2048), dim3(256), 0, stream, qkvf, g, qi8, ki8, vT);

  hipLaunchKernelGGL(k_attn_stats_mfma, dim3(1536), dim3(256), 0, stream,
                     qi8, ki8, g, rowmax, denomv, (unsigned int*)&g[6]);
  hipLaunchKernelGGL(k_attn_pv_mfma, dim3(1536), dim3(256), 0, stream,
                     qi8, ki8, vT, g, (const unsigned int*)&g[6], rowmax, denomv, aof, &g[7]);

  hipLaunchKernelGGL(k_quant_i8, dim3(2048), dim3(256), 0, stream, aof, 6291456u, &g[7], aob8);

  // out = aob8 @ pw8^T * (sao*spw/127^2) + proj_b -> d_out f32 [8192][768]
  hipLaunchKernelGGL(k_gemm8, dim3(C_ / 128, M_ / 128), dim3(256), 0, stream,
                     aob8, pw8, proj_b, out, M_, C_, C_, &g[7], &g[2], (float*)nullptr, 1);

  (void)in_sizes; (void)n_in; (void)out_size; (void)ws_size;
}

// Round 9
// 236.395 us; speedup vs baseline: 5.9154x; 1.1394x over previous
//
#include <hip/hip_runtime.h>
#include <hip/hip_bf16.h>
#include <cstdint>
#include <cstddef>

// Problem constants
#define B_    8
#define SEQ_  1024
#define C_    768
#define H_    12
#define D_    64
#define TC_   2304          // 3*C
#define M_    8192          // B*SEQ
#define EPS_  1e-7f
#define SCALE_ 0.036084391824351615f  // 768^-0.5

typedef __attribute__((ext_vector_type(8))) short bf16x8;
typedef __attribute__((ext_vector_type(4))) float f32x4;
typedef __attribute__((ext_vector_type(4))) int   i32x4;

// int8 -> bf16 integer levels (exact for |v|<=255)
__device__ __forceinline__ bf16x8 expand8(int2 raw) {
  union { int2 v; signed char c[8]; } u; u.v = raw;
  bf16x8 r;
  #pragma unroll
  for (int j = 0; j < 8; ++j) {
    float f = (float)(int)u.c[j];
    r[j] = (short)(__float_as_uint(f) >> 16);
  }
  return r;
}
__device__ __forceinline__ void expand16(int4 raw, int4& lo, int4& hi) {
  union { int4 v; signed char c[16]; } u; u.v = raw;
  unsigned short s[16];
  #pragma unroll
  for (int j = 0; j < 16; ++j) {
    float f = (float)(int)u.c[j];
    s[j] = (unsigned short)(__float_as_uint(f) >> 16);
  }
  lo = *(const int4*)&s[0]; hi = *(const int4*)&s[8];
}

__device__ __forceinline__ int8_t quant1(float v, float s) {
  float y = fminf(fabsf(v) / s, 1.0f);
  int q = (int)rintf(y * 127.0f);       // half-to-even, matches jnp.round
  return (int8_t)(v < 0.f ? -q : q);
}

// ---------------- init global stats ----------------
// g[0]=max|x| g[1]=max|qkv_w| g[2]=max|proj_w| g[3]=max|q| g[4]=max|k| g[5]=max|v|
// g[6]=min softmax-denom  g[7]=max|attn_out|
__global__ void k_init(float* g) {
  if (threadIdx.x == 0) {
    g[0]=0.f; g[1]=0.f; g[2]=0.f; g[3]=0.f; g[4]=0.f; g[5]=0.f;
    g[6]=3.402823466e+38f;
    g[7]=0.f;
  }
}

// ---------------- fused abs-max over x / qkv_w / proj_w, 1 atomic per block ----------------
__global__ __launch_bounds__(256) void k_absmax_fused(const float4* __restrict__ x,
                                                      const float4* __restrict__ w1,
                                                      const float4* __restrict__ w2,
                                                      float* g) {
  __shared__ float red[4];
  const int blk = blockIdx.x;
  const float4* p; unsigned n4; float* gout; int b0, nb;
  if (blk < 384)      { p = x;  n4 = 1572864u; gout = &g[0]; b0 = 0;   nb = 384; }
  else if (blk < 480) { p = w1; n4 = 442368u;  gout = &g[1]; b0 = 384; nb = 96;  }
  else                { p = w2; n4 = 147456u;  gout = &g[2]; b0 = 480; nb = 48;  }
  float m = 0.f;
  for (unsigned i = (unsigned)(blk - b0) * 256u + threadIdx.x; i < n4; i += (unsigned)nb * 256u) {
    float4 v = p[i];
    m = fmaxf(m, fmaxf(fmaxf(fabsf(v.x), fabsf(v.y)), fmaxf(fabsf(v.z), fabsf(v.w))));
  }
  #pragma unroll
  for (int off = 32; off; off >>= 1) m = fmaxf(m, __shfl_xor(m, off));
  if ((threadIdx.x & 63) == 0) red[threadIdx.x >> 6] = m;
  __syncthreads();
  if (threadIdx.x == 0) {
    m = fmaxf(fmaxf(red[0], red[1]), fmaxf(red[2], red[3]));
    atomicMax((unsigned int*)gout, __float_as_uint(m));
  }
}

// ---------------- signed fake-quant -> int8 integer levels ----------------
__device__ __forceinline__ void quant_seg8(const float* __restrict__ in, unsigned n, float s,
                                           int8_t* __restrict__ out, unsigned i0, unsigned stride) {
  for (unsigned i = i0; i < n; i += stride)
    out[i] = quant1(in[i], s);
}
__global__ __launch_bounds__(256) void k_quant_fused(const float* __restrict__ x,
                                                     const float* __restrict__ w1,
                                                     const float* __restrict__ w2,
                                                     const float* __restrict__ g,
                                                     int8_t* __restrict__ xq,
                                                     int8_t* __restrict__ wq,
                                                     int8_t* __restrict__ pw) {
  const int blk = blockIdx.x;
  if (blk < 1536)      quant_seg8(x,  6291456u, g[0] + EPS_, xq, (unsigned)blk * 256u + threadIdx.x, 1536u * 256u);
  else if (blk < 1968) quant_seg8(w1, 1769472u, g[1] + EPS_, wq, (unsigned)(blk - 1536) * 256u + threadIdx.x, 432u * 256u);
  else                 quant_seg8(w2,  589824u, g[2] + EPS_, pw, (unsigned)(blk - 1968) * 256u + threadIdx.x, 144u * 256u);
}

__global__ __launch_bounds__(256) void k_quant_i8(const float* __restrict__ in, unsigned n,
                                                  const float* __restrict__ gmax,
                                                  int8_t* __restrict__ out) {
  const float s = *gmax + EPS_;
  quant_seg8(in, n, s, out, blockIdx.x * blockDim.x + threadIdx.x, gridDim.x * blockDim.x);
}

// ---------------- native-i8 MFMA GEMM: C = alpha*(A.Bt^T) + bias ----------------
// A: [Mn][Kn] int8, Bt: [Nn][Kn] int8. mfma_i32_16x16x64_i8: one instruction per K-step per
// (i,j) sub-tile, exact int32 accumulation, no expand. LDS slot-major [4][128][16] is
// conflict-free for both b128 writes and frag reads. Reg prefetch (T14) + XCD swizzle.
__global__ __launch_bounds__(256) void k_gemm8i(const int8_t* __restrict__ A,
                                                const int8_t* __restrict__ Bt,
                                                const float* __restrict__ bias,
                                                float* __restrict__ C,
                                                int Mn, int Nn, int Kn,
                                                const float* __restrict__ sA, const float* __restrict__ sB,
                                                float* pmax, int partDiv) {
  __shared__ int8_t As[4][128][16];   // [k-slot][row][16B]
  __shared__ int8_t Bs[4][128][16];
  const int tid = threadIdx.x;
  // bijective XCD swizzle (nwg % 8 == 0 for both GEMMs)
  int flat = blockIdx.y * gridDim.x + blockIdx.x;
  int chunk = (gridDim.x * gridDim.y) >> 3;
  int nf = (flat & 7) * chunk + (flat >> 3);
  const int n0 = (nf % gridDim.x) * 128, m0 = (nf / gridDim.x) * 128;
  const int wid = tid >> 6, lane = tid & 63;
  const int wr = wid >> 1, wc = wid & 1;            // 2x2 waves -> 64x64 each
  const int lrow = lane & 15;
  const int lslot = lane >> 4;                      // k slot 0..3 (16 bytes each)
  i32x4 acc[4][4] = {};
  // staging: thread handles rows srow with slots slot0 and slot0+2 (2 chunks per matrix)
  const int srow = tid & 127;
  const int slot0 = tid >> 7;                       // 0 or 1
  const int8_t* ga = A  + (size_t)(m0 + srow) * Kn + slot0 * 16;
  const int8_t* gb = Bt + (size_t)(n0 + srow) * Kn + slot0 * 16;
  const int nt = Kn >> 6;
  int4 ra0 = *(const int4*)(ga);
  int4 ra1 = *(const int4*)(ga + 32);
  int4 rb0 = *(const int4*)(gb);
  int4 rb1 = *(const int4*)(gb + 32);
  for (int t = 0; t < nt; ++t) {
    if (t) __syncthreads();           // all waves done reading LDS from prev step
    *(int4*)&As[slot0][srow][0]     = ra0;
    *(int4*)&As[slot0 + 2][srow][0] = ra1;
    *(int4*)&Bs[slot0][srow][0]     = rb0;
    *(int4*)&Bs[slot0 + 2][srow][0] = rb1;
    // prefetch next K-tile to regs; loads fly under the MFMA phase (T14)
    if (t + 1 < nt) {
      const int ko = (t + 1) * 64;
      ra0 = *(const int4*)(ga + ko);
      ra1 = *(const int4*)(ga + ko + 32);
      rb0 = *(const int4*)(gb + ko);
      rb1 = *(const int4*)(gb + ko + 32);
    }
    __syncthreads();                  // LDS tile ready
    i32x4 af[4], bfr[4];
    #pragma unroll
    for (int i = 0; i < 4; ++i) af[i]  = *(const i32x4*)&As[lslot][wr * 64 + i * 16 + lrow][0];
    #pragma unroll
    for (int j = 0; j < 4; ++j) bfr[j] = *(const i32x4*)&Bs[lslot][wc * 64 + j * 16 + lrow][0];
    #pragma unroll
    for (int i = 0; i < 4; ++i)
      #pragma unroll
      for (int j = 0; j < 4; ++j)
        acc[i][j] = __builtin_amdgcn_mfma_i32_16x16x64_i8(af[i], bfr[j], acc[i][j], 0, 0, 0);
  }
  const float alpha = (sA[0] + EPS_) * (sB[0] + EPS_) * (1.0f / 16129.0f);
  const int orow = (lane >> 4) << 2;
  float amax = 0.f;
  #pragma unroll
  for (int i = 0; i < 4; ++i) {
    #pragma unroll
    for (int j = 0; j < 4; ++j) {
      int col = n0 + wc * 64 + j * 16 + lrow;
      float bc = bias[col];
      #pragma unroll
      for (int rr = 0; rr < 4; ++rr) {
        int row = m0 + wr * 64 + i * 16 + orow + rr;
        float val = (float)acc[i][j][rr] * alpha + bc;
        C[(size_t)row * Nn + col] = val;
        amax = fmaxf(amax, fabsf(val));
      }
    }
  }
  if (pmax) {
    #pragma unroll
    for (int off = 32; off; off >>= 1) amax = fmaxf(amax, __shfl_xor(amax, off));
    if (lane == 0) atomicMax((unsigned int*)&pmax[n0 / partDiv], __float_as_uint(amax));
  }
}

// ---------------- quantize qkv into int8 head-layouts (tiled, coalesced vT) ----------------
// grid: 1536 = bh(96) x ntile(16). Coalesced f32 reads; q,k written directly; v transposed
// through a padded LDS f32 tile so the vT[bh][d][n] write is 16B-coalesced.
__global__ __launch_bounds__(256) void k_quant_heads(const float* __restrict__ qkvf, const float* __restrict__ g,
                                                     int8_t* __restrict__ qo, int8_t* __restrict__ ko,
                                                     int8_t* __restrict__ vT) {
  __shared__ float vt[64][65];
  const int bh = blockIdx.x >> 4, nt = blockIdx.x & 15;
  const int b = bh / 12, h = bh % 12;
  const int n0 = nt * 64;
  const int tid = threadIdx.x;
  const float s0 = g[3] + EPS_, s1 = g[4] + EPS_, s2 = g[5] + EPS_;
  const int r = tid >> 2, dc = tid & 3;             // row in tile, 16-elem d chunk
  const size_t mrow = (size_t)(b * 1024 + n0 + r) * 2304;
  union { int4 v; int8_t c[16]; } pk;
  // q part
  {
    const float* src = qkvf + mrow + h * 64 + dc * 16;
    #pragma unroll
    for (int e = 0; e < 16; ++e) pk.c[e] = quant1(src[e], s0);
    *(int4*)&qo[((size_t)bh * 1024 + n0 + r) * 64 + dc * 16] = pk.v;
  }
  // k part
  {
    const float* src = qkvf + mrow + 768 + h * 64 + dc * 16;
    #pragma unroll
    for (int e = 0; e < 16; ++e) pk.c[e] = quant1(src[e], s1);
    *(int4*)&ko[((size_t)bh * 1024 + n0 + r) * 64 + dc * 16] = pk.v;
  }
  // v part: stash transposed in LDS (f32), quantize+pack on the way out
  {
    const float* src = qkvf + mrow + 1536 + h * 64 + dc * 16;
    #pragma unroll
    for (int e = 0; e < 16; ++e) vt[dc * 16 + e][r] = src[e];
  }
  __syncthreads();
  {
    const int d = tid >> 2, nc = tid & 3;
    #pragma unroll
    for (int e = 0; e < 16; ++e) pk.c[e] = quant1(vt[d][nc * 16 + e], s2);
    *(int4*)&vT[((size_t)bh * 64 + d) * 1024 + n0 + nc * 16] = pk.v;
  }
}

// ---------------- attention pass 1 (swapped-QK MFMA, 64-row blocks, prefetch) ----------------
// grid: 1536 = bh(96) x rt(16); 4 waves x 16 q-rows.
__global__ __launch_bounds__(256) void k_attn_stats_mfma(
    const int8_t* __restrict__ qi8, const int8_t* __restrict__ ki8,
    const float* __restrict__ g, float* __restrict__ rowmax, float* __restrict__ denomv,
    unsigned int* __restrict__ gminden) {
  __shared__ unsigned short Ks[64 * 64];
  __shared__ float red[4];
  const int bh = blockIdx.x >> 4, rt = blockIdx.x & 15;
  const int tid = threadIdx.x, w = tid >> 6, lane = tid & 63;
  const int lrow = lane & 15, lko = (lane >> 4) << 3;
  const int8_t* qbase = qi8 + (size_t)bh * 65536;
  const int8_t* kbase = ki8 + (size_t)bh * 65536;
  bf16x8 qf[2];
  #pragma unroll
  for (int ks = 0; ks < 2; ++ks)
    qf[ks] = expand8(*(const int2*)(qbase + (size_t)(rt*64 + w*16 + lrow) * 64 + ks*32 + lko));
  const float qkScale = (g[3] + EPS_) * (g[4] + EPS_) * (1.0f / 16129.0f) * SCALE_;
  float m = -3.0e38f, den = 0.f;
  const int srow = tid >> 2, sc = tid & 3;
  const int sx = (srow & 7) << 4;
  int4 kraw = *(const int4*)(kbase + (size_t)srow * 64 + sc * 16);
  for (int t = 0; t < 16; ++t) {
    __syncthreads();
    {
      int4 lo, hi; expand16(kraw, lo, hi);
      int bb = srow * 128 + sc * 32;
      *(int4*)((char*)Ks + ( bb       ^ sx)) = lo;
      *(int4*)((char*)Ks + ((bb + 16) ^ sx)) = hi;
    }
    if (t < 15)
      kraw = *(const int4*)(kbase + (size_t)(t + 1) * 4096 + (size_t)srow * 64 + sc * 16);
    __syncthreads();
    f32x4 acc[4] = {};
    #pragma unroll
    for (int ks = 0; ks < 2; ++ks)
      #pragma unroll
      for (int j = 0; j < 4; ++j) {
        int row = j * 16 + lrow;
        bf16x8 kf = *(const bf16x8*)((const char*)Ks + ((row * 128 + (ks*32 + lko) * 2) ^ ((row & 7) << 4)));
        acc[j] = __builtin_amdgcn_mfma_f32_16x16x32_bf16(kf, qf[ks], acc[j], 0, 0, 0);
      }
    float mnew = m;
    #pragma unroll
    for (int j = 0; j < 4; ++j)
      #pragma unroll
      for (int rr = 0; rr < 4; ++rr)
        mnew = fmaxf(mnew, acc[j][rr] * qkScale);
    float d = den * __expf(m - mnew);
    #pragma unroll
    for (int j = 0; j < 4; ++j)
      #pragma unroll
      for (int rr = 0; rr < 4; ++rr)
        d += __expf(acc[j][rr] * qkScale - mnew);
    den = d; m = mnew;
  }
  // merge the 4 hi-lane k-partitions
  #pragma unroll
  for (int off = 16; off <= 32; off <<= 1) {
    float mo = __shfl_xor(m, off);
    float doo = __shfl_xor(den, off);
    float mg = fmaxf(m, mo);
    den = den * __expf(m - mg) + doo * __expf(mo - mg);
    m = mg;
  }
  if (lane < 16) {
    size_t rg = (size_t)bh * 1024 + rt * 64 + w * 16 + lane;
    rowmax[rg] = m;
    denomv[rg] = den;
  }
  // one atomic per block
  float bm = den;
  #pragma unroll
  for (int off = 1; off < 16; off <<= 1) bm = fminf(bm, __shfl_xor(bm, off));
  if (lane == 0) red[w] = bm;
  __syncthreads();
  if (tid == 0)
    atomicMin(gminden, __float_as_uint(fminf(fminf(red[0], red[1]), fminf(red[2], red[3]))));
}

// ---------------- attention pass 2 (swapped-QK MFMA, 64-row blocks, prefetch) ----------------
__global__ __launch_bounds__(256) void k_attn_pv_mfma(
    const int8_t* __restrict__ qi8, const int8_t* __restrict__ ki8, const int8_t* __restrict__ vti8,
    const float* __restrict__ g, const unsigned int* __restrict__ gminden,
    const float* __restrict__ rowmax, const float* __restrict__ denomv,
    float* __restrict__ aof, float* __restrict__ gamax) {
  __shared__ unsigned short Ks[64 * 64];
  __shared__ unsigned short Vs[64 * 64];
  __shared__ unsigned short Ps[64 * 64];
  __shared__ float red[4];
  const int bh = blockIdx.x >> 4, rt = blockIdx.x & 15;
  const int b = bh / 12, h = bh % 12;
  const int tid = threadIdx.x, w = tid >> 6, lane = tid & 63;
  const int lrow = lane & 15, lko = (lane >> 4) << 3;
  const int8_t* qbase = qi8 + (size_t)bh * 65536;
  const int8_t* kbase = ki8 + (size_t)bh * 65536;
  const int8_t* vbase = vti8 + (size_t)bh * 65536;
  bf16x8 qf[2];
  #pragma unroll
  for (int ks = 0; ks < 2; ++ks)
    qf[ks] = expand8(*(const int2*)(qbase + (size_t)(rt*64 + w*16 + lrow) * 64 + ks*32 + lko));
  const float qkScale = (g[3] + EPS_) * (g[4] + EPS_) * (1.0f / 16129.0f) * SCALE_;
  const float minden = __uint_as_float(*gminden);
  const float sa = 1.0f / minden + EPS_;
  const float invSa = 1.0f / sa;
  const float sv = g[5] + EPS_;
  const float pvScale = sa * sv * (1.0f / 32385.0f);   // /(255*127)
  const float rm  = rowmax[(size_t)bh * 1024 + rt * 64 + w * 16 + lrow];
  const float ivd = 1.0f / denomv[(size_t)bh * 1024 + rt * 64 + w * 16 + lrow];
  f32x4 accO[4] = {};
  const int srow = tid >> 2, sc = tid & 3;
  const int sx = (srow & 7) << 4;
  int4 kraw = *(const int4*)(kbase + (size_t)srow * 64 + sc * 16);
  int4 vraw = *(const int4*)(vbase + (size_t)srow * 1024 + sc * 16);
  for (int t = 0; t < 16; ++t) {
    __syncthreads();
    {
      int4 lo, hi;
      int bb = srow * 128 + sc * 32;
      expand16(kraw, lo, hi);
      *(int4*)((char*)Ks + ( bb       ^ sx)) = lo;
      *(int4*)((char*)Ks + ((bb + 16) ^ sx)) = hi;
      expand16(vraw, lo, hi);
      *(int4*)((char*)Vs + ( bb       ^ sx)) = lo;
      *(int4*)((char*)Vs + ((bb + 16) ^ sx)) = hi;
    }
    if (t < 15) {
      kraw = *(const int4*)(kbase + (size_t)(t + 1) * 4096 + (size_t)srow * 64 + sc * 16);
      vraw = *(const int4*)(vbase + (size_t)srow * 1024 + (t + 1) * 64 + sc * 16);
    }
    __syncthreads();
    f32x4 acc[4] = {};
    #pragma unroll
    for (int ks = 0; ks < 2; ++ks)
      #pragma unroll
      for (int j = 0; j < 4; ++j) {
        int row = j * 16 + lrow;
        bf16x8 kf = *(const bf16x8*)((const char*)Ks + ((row * 128 + (ks*32 + lko) * 2) ^ ((row & 7) << 4)));
        acc[j] = __builtin_amdgcn_mfma_f32_16x16x32_bf16(kf, qf[ks], acc[j], 0, 0, 0);
      }
    // softmax -> unsigned 8-bit levels (exact bf16) -> Ps (in-lane)
    const int q = w * 16 + lrow;
    const int kb = (lane >> 4) << 2;
    #pragma unroll
    for (int j = 0; j < 4; ++j) {
      float a0 = rintf(fminf(__expf(acc[j][0] * qkScale - rm) * ivd * invSa, 1.0f) * 255.0f);
      float a1 = rintf(fminf(__expf(acc[j][1] * qkScale - rm) * ivd * invSa, 1.0f) * 255.0f);
      float a2 = rintf(fminf(__expf(acc[j][2] * qkScale - rm) * ivd * invSa, 1.0f) * 255.0f);
      float a3 = rintf(fminf(__expf(acc[j][3] * qkScale - rm) * ivd * invSa, 1.0f) * 255.0f);
      uint2 pk;
      pk.x = (__float_as_uint(a0) >> 16) | ((__float_as_uint(a1) >> 16) << 16);
      pk.y = (__float_as_uint(a2) >> 16) | ((__float_as_uint(a3) >> 16) << 16);
      int byteoff = (q * 128 + (j * 16 + kb) * 2) ^ ((q & 7) << 4);
      *(uint2*)((char*)Ps + byteoff) = pk;
    }
    // O += P @ V
    #pragma unroll
    for (int ks = 0; ks < 2; ++ks) {
      bf16x8 pf = *(const bf16x8*)((const char*)Ps + ((q * 128 + (ks*32 + lko) * 2) ^ ((q & 7) << 4)));
      #pragma unroll
      for (int j = 0; j < 4; ++j) {
        int row = j * 16 + lrow;
        bf16x8 vf = *(const bf16x8*)((const char*)Vs + ((row * 128 + (ks*32 + lko) * 2) ^ ((row & 7) << 4)));
        accO[j] = __builtin_amdgcn_mfma_f32_16x16x32_bf16(pf, vf, accO[j], 0, 0, 0);
      }
    }
  }
  float amax = 0.f;
  #pragma unroll
  for (int j = 0; j < 4; ++j) {
    int d = j * 16 + lrow;
    #pragma unroll
    for (int rr = 0; rr < 4; ++rr) {
      int row = rt * 64 + w * 16 + (lane >> 4) * 4 + rr;
      float val = accO[j][rr] * pvScale;
      aof[((size_t)(b * 1024 + row)) * 768 + h * 64 + d] = val;
      amax = fmaxf(amax, fabsf(val));
    }
  }
  #pragma unroll
  for (int off = 1; off < 64; off <<= 1) amax = fmaxf(amax, __shfl_xor(amax, off));
  if (lane == 0) red[w] = amax;
  __syncthreads();
  if (tid == 0)
    atomicMax((unsigned int*)gamax, __float_as_uint(fmaxf(fmaxf(red[0], red[1]), fmaxf(red[2], red[3]))));
}

extern "C" void kernel_launch(void* const* d_in, const int* in_sizes, int n_in,
                              void* d_out, int out_size, void* d_ws, size_t ws_size,
                              hipStream_t stream) {
  const float* x      = (const float*)d_in[0];   // [8,1024,768]
  const float* qkv_w  = (const float*)d_in[1];   // [2304,768]
  const float* qkv_b  = (const float*)d_in[2];   // [2304]
  const float* proj_w = (const float*)d_in[3];   // [768,768]
  const float* proj_b = (const float*)d_in[4];   // [768]
  float* out = (float*)d_out;

  char* w = (char*)d_ws;
  float*          g      = (float*)(w + 0);                 // 8 stats
  float*          rowmax = (float*)(w + 256);               // 393216 B
  float*          denomv = (float*)(w + 393472);            // 393216 B
  int8_t*         qi8    = (int8_t*)(w + 786688);           // 6291456 B
  int8_t*         ki8    = (int8_t*)(w + 7078144);          // 6291456 B
  int8_t*         vT     = (int8_t*)(w + 13369600);         // 6291456 B
  int8_t*         pw8    = (int8_t*)(w + 19661056);         //  589824 B (live to end)
  int8_t*         xq8    = (int8_t*)(w + 20840704);         // 6291456 B (dead after GEMM1)
  int8_t*         wq8    = (int8_t*)(w + 33423616);         // 1769472 B (dead after GEMM1)
  float*          qkvf   = (float*)(w + 36962560);          // 75497472 B (dead after quant_heads)
  float*          aof    = (float*)(w + 36962560);          // 25165824 B (aliases dead qkvf)
  int8_t*         aob8   = (int8_t*)(w + 62128384);         // 6291456 B (inside qkvf region)

  hipLaunchKernelGGL(k_init, dim3(1), dim3(64), 0, stream, g);

  hipLaunchKernelGGL(k_absmax_fused, dim3(528), dim3(256), 0, stream,
                     (const float4*)x, (const float4*)qkv_w, (const float4*)proj_w, g);

  hipLaunchKernelGGL(k_quant_fused, dim3(2112), dim3(256), 0, stream,
                     x, qkv_w, proj_w, g, xq8, wq8, pw8);

  // qkv = xq @ wq^T * (sx*sw/127^2) + b -> f32 [8192][2304]; also per-part |max| -> g[3..5]
  hipLaunchKernelGGL(k_gemm8i, dim3(TC_ / 128, M_ / 128), dim3(256), 0, stream,
                     xq8, wq8, qkv_b, qkvf, M_, TC_, C_, &g[0], &g[1], &g[3], 768);

  hipLaunchKernelGGL(k_quant_heads, dim3(1536), dim3(256), 0, stream, qkvf, g, qi8, ki8, vT);

  hipLaunchKernelGGL(k_attn_stats_mfma, dim3(1536), dim3(256), 0, stream,
                     qi8, ki8, g, rowmax, denomv, (unsigned int*)&g[6]);
  hipLaunchKernelGGL(k_attn_pv_mfma, dim3(1536), dim3(256), 0, stream,
                     qi8, ki8, vT, g, (const unsigned int*)&g[6], rowmax, denomv, aof, &g[7]);

  hipLaunchKernelGGL(k_quant_i8, dim3(2048), dim3(256), 0, stream, aof, 6291456u, &g[7], aob8);

  // out = aob8 @ pw8^T * (sao*spw/127^2) + proj_b -> d_out f32 [8192][768]
  hipLaunchKernelGGL(k_gemm8i, dim3(C_ / 128, M_ / 128), dim3(256), 0, stream,
                     aob8, pw8, proj_b, out, M_, C_, C_, &g[7], &g[2], (float*)nullptr, 1);

  (void)in_sizes; (void)n_in; (void)out_size; (void)ws_size;
}